// Round 1
// baseline (294.303 us; speedup 1.0000x reference)
//
#include <hip/hip_runtime.h>
#include <cstdint>
#include <cstddef>

#define NN   2048
#define N2   (2048LL*2048LL)
#define CC   2
#define EE   5
#define WIN  512
#define WOUT 256

typedef __bf16 bf16_t;
typedef __attribute__((ext_vector_type(8))) __bf16 bf16x8;
typedef __attribute__((ext_vector_type(4))) __bf16 bf16x4;
typedef __attribute__((ext_vector_type(4))) float  f32x4;

// ---------------- small prep kernels ----------------

__global__ void k_softmax(const float* __restrict__ w0a, const float* __restrict__ w0b,
                          const float* __restrict__ w1, float* __restrict__ F) {
  int t = threadIdx.x;
  if (t < 3 * CC) {
    int which = t >> 1, c = t & 1;
    const float* w = (which == 0) ? w0a : ((which == 1) ? w0b : w1);
    float x[EE]; float m = -1e30f;
    for (int e = 0; e < EE; ++e) { x[e] = w[c * EE + e]; m = fmaxf(m, x[e]); }
    float s = 0.f;
    for (int e = 0; e < EE; ++e) { x[e] = expf(x[e] - m); s += x[e]; }
    for (int e = 0; e < EE; ++e) F[which * (CC * EE) + c * EE + e] = x[e] / s;
  }
}

__global__ void k_cast_bf16(const float* __restrict__ in, bf16_t* __restrict__ out, int n8) {
  int i = blockIdx.x * blockDim.x + threadIdx.x;
  if (i < n8) {
    float4 a = ((const float4*)in)[i * 2];
    float4 b = ((const float4*)in)[i * 2 + 1];
    bf16x8 o;
    o[0] = (bf16_t)a.x; o[1] = (bf16_t)a.y; o[2] = (bf16_t)a.z; o[3] = (bf16_t)a.w;
    o[4] = (bf16_t)b.x; o[5] = (bf16_t)b.y; o[6] = (bf16_t)b.z; o[7] = (bf16_t)b.w;
    ((bf16x8*)out)[i] = o;
  }
}

// out[n][m] = bf16(in[m][n]); M,N multiples of 64
__global__ void k_transpose_cast(const float* __restrict__ in, bf16_t* __restrict__ out,
                                 int M, int N) {
  __shared__ bf16_t tile[64][65];
  int m0 = blockIdx.x * 64, n0 = blockIdx.y * 64;
  int t = threadIdx.x, tr = t >> 4, tc = (t & 15) << 2;
#pragma unroll
  for (int v = 0; v < 4; ++v) {
    int r = tr + v * 16;
    float4 d = *(const float4*)&in[(long long)(m0 + r) * N + n0 + tc];
    tile[r][tc + 0] = (bf16_t)d.x; tile[r][tc + 1] = (bf16_t)d.y;
    tile[r][tc + 2] = (bf16_t)d.z; tile[r][tc + 3] = (bf16_t)d.w;
  }
  __syncthreads();
#pragma unroll
  for (int v = 0; v < 4; ++v) {
    int r = tr + v * 16;
    bf16x4 o;
    o[0] = tile[tc + 0][r]; o[1] = tile[tc + 1][r];
    o[2] = tile[tc + 2][r]; o[3] = tile[tc + 3][r];
    *(bf16x4*)&out[(long long)(n0 + r) * M + m0 + tc] = o;
  }
}

// ---------------- combine: A(5,N,N) fp32 -> Ha (row-major), HbT, Hb2T (transposed) bf16 ----------------

__global__ void k_combine(const float* __restrict__ A, const float* __restrict__ F,
                          bf16_t* __restrict__ Ha, bf16_t* __restrict__ HbT,
                          bf16_t* __restrict__ Hb2T) {
  __shared__ bf16_t tl[4][64][65]; // hb c0, hb c1, hb2 c0, hb2 c1
  float f[3][2][5];
#pragma unroll
  for (int w = 0; w < 3; ++w)
#pragma unroll
    for (int c = 0; c < 2; ++c)
#pragma unroll
      for (int e = 0; e < 5; ++e) f[w][c][e] = F[w * 10 + c * 5 + e];

  int i0 = blockIdx.x * 64, j0 = blockIdx.y * 64;
  int t = threadIdx.x, tr = t >> 4, tc = (t & 15) << 2;

#pragma unroll
  for (int v = 0; v < 4; ++v) {
    int lr = tr + v * 16;
    long long gi = i0 + lr;
    const float* base = A + gi * (long long)NN + j0 + tc;
    float av[5][4];
#pragma unroll
    for (int e = 0; e < 5; ++e) {
      float4 q = *(const float4*)(base + (long long)e * N2);
      av[e][0] = q.x; av[e][1] = q.y; av[e][2] = q.z; av[e][3] = q.w;
    }
    bf16x4 ha0, ha1;
#pragma unroll
    for (int x = 0; x < 4; ++x) {
      float s0 = 0.f, s1 = 0.f, s2 = 0.f, s3 = 0.f, s4 = 0.f, s5 = 0.f;
#pragma unroll
      for (int e = 0; e < 5; ++e) {
        float u = av[e][x];
        s0 += f[0][0][e] * u; s1 += f[0][1][e] * u;
        s2 += f[1][0][e] * u; s3 += f[1][1][e] * u;
        s4 += f[2][0][e] * u; s5 += f[2][1][e] * u;
      }
      ha0[x] = (bf16_t)s0; ha1[x] = (bf16_t)s1;
      tl[0][lr][tc + x] = (bf16_t)s2; tl[1][lr][tc + x] = (bf16_t)s3;
      tl[2][lr][tc + x] = (bf16_t)s4; tl[3][lr][tc + x] = (bf16_t)s5;
    }
    *(bf16x4*)&Ha[0 * N2 + gi * NN + j0 + tc] = ha0;
    *(bf16x4*)&Ha[1 * N2 + gi * NN + j0 + tc] = ha1;
  }
  __syncthreads();
#pragma unroll
  for (int v = 0; v < 4; ++v) {
    int lr = tr + v * 16; // local col index of source tile = local row of transposed out
#pragma unroll
    for (int k4 = 0; k4 < 4; ++k4) {
      bf16x4 o;
      o[0] = tl[k4][tc + 0][lr]; o[1] = tl[k4][tc + 1][lr];
      o[2] = tl[k4][tc + 2][lr]; o[3] = tl[k4][tc + 3][lr];
      bf16_t* dst = ((k4 < 2) ? HbT : Hb2T) + (long long)(k4 & 1) * N2
                    + (long long)(j0 + lr) * NN + i0 + tc;
      *(bf16x4*)dst = o;
    }
  }
}

// ---------------- bf16 GEMM: C[M,N] fp32 = A[M,K] @ B[N,K]^T (both row-major, bf16) ----------------
// 128x128 tile, 4 waves (2x2), 16x16x32 MFMA, global_load_lds width-16 staging (m97 structure).

__global__ __launch_bounds__(256)
void k_gemm(const bf16_t* __restrict__ A, const bf16_t* __restrict__ B, float* __restrict__ C,
            int N, int K, long long sA, long long sB, long long sC) {
  __shared__ __align__(16) bf16_t As[128 * 32];
  __shared__ __align__(16) bf16_t Bs[128 * 32];
  int cz = blockIdx.z;
  const bf16_t* Ab = A + cz * sA + (long long)blockIdx.x * 128 * K;
  const bf16_t* Bb = B + cz * sB + (long long)blockIdx.y * 128 * K;
  float* Cb = C + cz * sC;
  int t = threadIdx.x;
  int wid = t >> 6, lane = t & 63;
  int wr = wid >> 1, wc = wid & 1;

  f32x4 acc[4][4] = {};
  int frow = lane & 15, fk = (lane >> 4) << 3;

  for (int kk = 0; kk < K; kk += 32) {
#pragma unroll
    for (int inst = 0; inst < 2; ++inst) {
      int chunk = inst * 256 + t;
      int row = chunk >> 2, col = (chunk & 3) << 3;
      const bf16_t* ga = Ab + (long long)row * K + kk + col;
      const bf16_t* gb = Bb + (long long)row * K + kk + col;
      int lofs = (inst * 256 + wid * 64) * 16; // wave-uniform LDS base; HW adds lane*16
      __builtin_amdgcn_global_load_lds((__attribute__((address_space(1))) void*)ga,
          (__attribute__((address_space(3))) void*)((char*)As + lofs), 16, 0, 0);
      __builtin_amdgcn_global_load_lds((__attribute__((address_space(1))) void*)gb,
          (__attribute__((address_space(3))) void*)((char*)Bs + lofs), 16, 0, 0);
    }
    __syncthreads(); // compiler drains vmcnt before s_barrier -> staged data visible
    bf16x8 af[4], bfr[4];
#pragma unroll
    for (int m = 0; m < 4; ++m)
      af[m] = *(const bf16x8*)&As[(wr * 64 + m * 16 + frow) * 32 + fk];
#pragma unroll
    for (int n = 0; n < 4; ++n)
      bfr[n] = *(const bf16x8*)&Bs[(wc * 64 + n * 16 + frow) * 32 + fk];
#pragma unroll
    for (int m = 0; m < 4; ++m)
#pragma unroll
      for (int n = 0; n < 4; ++n)
        acc[m][n] = __builtin_amdgcn_mfma_f32_16x16x32_bf16(af[m], bfr[n], acc[m][n], 0, 0, 0);
    __syncthreads();
  }

  // C/D layout: col = lane&15, row = (lane>>4)*4 + reg
  int r0 = blockIdx.x * 128 + wr * 64 + ((lane >> 4) << 2);
  int c0 = blockIdx.y * 128 + wc * 64 + (lane & 15);
#pragma unroll
  for (int m = 0; m < 4; ++m)
#pragma unroll
    for (int n = 0; n < 4; ++n)
#pragma unroll
      for (int j = 0; j < 4; ++j)
        Cb[(long long)(r0 + m * 16 + j) * N + c0 + n * 16] = acc[m][n][j];
}

// ---------------- column sums (deterministic 2-stage), normalize passes ----------------

__global__ void k_colsum_partial(const float* __restrict__ H, float* __restrict__ partial) {
  int c = blockIdx.z, chunk = blockIdx.y;
  int col = blockIdx.x * 256 + threadIdx.x;
  const float* p = H + (long long)c * N2 + (long long)chunk * 128 * NN + col;
  int i0 = chunk * 128;
  float s = 0.f;
#pragma unroll 4
  for (int i = 0; i < 128; ++i) {
    float v = p[(long long)i * NN];
    s += (i0 + i == col) ? 0.f : v; // exclude diagonal
  }
  partial[((long long)c * 16 + chunk) * NN + col] = s;
}

__global__ void k_colsum_finish(const float* __restrict__ partial, float* __restrict__ dinv,
                                float* __restrict__ disv) {
  int idx = blockIdx.x * blockDim.x + threadIdx.x; // c*2048 + col
  int c = idx >> 11, col = idx & 2047;
  float d = 0.f;
#pragma unroll
  for (int k = 0; k < 16; ++k) d += partial[((long long)c * 16 + k) * NN + col];
  dinv[idx] = (d != 0.f) ? 1.f / d : 0.f;
  // GCN degree: colsum(normalized H) + 1 = (d!=0 ? 2 : 1); dis = deg^-1/2
  if (disv) disv[idx] = (d != 0.f) ? 0.70710678118654752f : 1.f;
}

__global__ void k_normalize1(const float* __restrict__ HH, const float* __restrict__ dinv,
                             bf16_t* __restrict__ Hn) {
  long long idx4 = ((long long)blockIdx.x * blockDim.x + threadIdx.x) * 4;
  int c = (int)(idx4 >> 22);
  long long rem = idx4 & (N2 - 1);
  int i = (int)(rem >> 11), j = (int)(rem & 2047);
  float4 h = *(const float4*)(HH + idx4);
  float4 dv = *(const float4*)(dinv + c * NN + j);
  bf16x4 o;
  o[0] = (bf16_t)((i == j + 0) ? 0.f : h.x * dv.x);
  o[1] = (bf16_t)((i == j + 1) ? 0.f : h.y * dv.y);
  o[2] = (bf16_t)((i == j + 2) ? 0.f : h.z * dv.z);
  o[3] = (bf16_t)((i == j + 3) ? 0.f : h.w * dv.w);
  *(bf16x4*)(Hn + idx4) = o;
}

// A3[c][n][r] = (r==n) ? 0 : H2[c][r][n] * dinv2[c][n] * disv[c][r]   (transposed, bf16)
__global__ void k_normalize2T(const float* __restrict__ H2, const float* __restrict__ dinv2,
                              const float* __restrict__ disv, bf16_t* __restrict__ A3) {
  __shared__ bf16_t tile[64][65];
  int r0 = blockIdx.x * 64, n0 = blockIdx.y * 64, c = blockIdx.z;
  int t = threadIdx.x, tr = t >> 4, tc = (t & 15) << 2;
  const float* Hc = H2 + (long long)c * N2;
  float4 dn = *(const float4*)&dinv2[c * NN + n0 + tc];
#pragma unroll
  for (int v = 0; v < 4; ++v) {
    int lr = tr + v * 16; int r = r0 + lr;
    float4 h = *(const float4*)&Hc[(long long)r * NN + n0 + tc];
    float dr = disv[c * NN + r];
    tile[lr][tc + 0] = (bf16_t)((r == n0 + tc + 0) ? 0.f : h.x * dn.x * dr);
    tile[lr][tc + 1] = (bf16_t)((r == n0 + tc + 1) ? 0.f : h.y * dn.y * dr);
    tile[lr][tc + 2] = (bf16_t)((r == n0 + tc + 2) ? 0.f : h.z * dn.z * dr);
    tile[lr][tc + 3] = (bf16_t)((r == n0 + tc + 3) ? 0.f : h.w * dn.w * dr);
  }
  __syncthreads();
#pragma unroll
  for (int v = 0; v < 4; ++v) {
    int lr = tr + v * 16; // local n
    bf16x4 o;
    o[0] = tile[tc + 0][lr]; o[1] = tile[tc + 1][lr];
    o[2] = tile[tc + 2][lr]; o[3] = tile[tc + 3][lr];
    *(bf16x4*)&A3[(long long)c * N2 + (long long)(n0 + lr) * NN + r0 + tc] = o;
  }
}

// ---------------- epilogues ----------------

// Xcat[n][c*256+f] = bf16(relu(dis_n*T + dis_n^2*XW[n][f] + gcn_b[f]))
__global__ void k_gcn_epi(const float* __restrict__ T, const float* __restrict__ XW,
                          const float* __restrict__ gcn_b, const float* __restrict__ disv,
                          bf16_t* __restrict__ Xcat) {
  long long idx4 = ((long long)blockIdx.x * 256 + threadIdx.x) * 4;
  int c = (int)(idx4 >> 19);
  int rem = (int)(idx4 & ((1 << 19) - 1));
  int n = rem >> 8, fcol = rem & 255;
  float4 tv = *(const float4*)(T + idx4);
  float4 xw = *(const float4*)(XW + rem);
  float4 b  = *(const float4*)(gcn_b + fcol);
  float dn = disv[c * NN + n], d2 = dn * dn;
  bf16x4 o;
  o[0] = (bf16_t)fmaxf(dn * tv.x + d2 * xw.x + b.x, 0.f);
  o[1] = (bf16_t)fmaxf(dn * tv.y + d2 * xw.y + b.y, 0.f);
  o[2] = (bf16_t)fmaxf(dn * tv.z + d2 * xw.z + b.z, 0.f);
  o[3] = (bf16_t)fmaxf(dn * tv.w + d2 * xw.w + b.w, 0.f);
  *(bf16x4*)&Xcat[(long long)n * (CC * WOUT) + c * WOUT + fcol] = o;
}

__global__ void k_relu_bias_bf16(const float* __restrict__ Cin, const float* __restrict__ bias,
                                 bf16_t* __restrict__ out) {
  long long idx4 = ((long long)blockIdx.x * 256 + threadIdx.x) * 4;
  int fcol = (int)(idx4 & 255);
  float4 v = *(const float4*)(Cin + idx4);
  float4 b = *(const float4*)(bias + fcol);
  bf16x4 o;
  o[0] = (bf16_t)fmaxf(v.x + b.x, 0.f);
  o[1] = (bf16_t)fmaxf(v.y + b.y, 0.f);
  o[2] = (bf16_t)fmaxf(v.z + b.z, 0.f);
  o[3] = (bf16_t)fmaxf(v.w + b.w, 0.f);
  *(bf16x4*)(out + idx4) = o;
}

__global__ void k_bias_out(const float* __restrict__ Cin, const float* __restrict__ bias,
                           float* __restrict__ out) {
  long long idx4 = ((long long)blockIdx.x * 256 + threadIdx.x) * 4;
  int fcol = (int)(idx4 & 255);
  float4 v = *(const float4*)(Cin + idx4);
  float4 b = *(const float4*)(bias + fcol);
  float4 o; o.x = v.x + b.x; o.y = v.y + b.y; o.z = v.z + b.z; o.w = v.w + b.w;
  *(float4*)(out + idx4) = o;
}

// ---------------- launch ----------------

extern "C" void kernel_launch(void* const* d_in, const int* in_sizes, int n_in,
                              void* d_out, int out_size, void* d_ws, size_t ws_size,
                              hipStream_t stream) {
  const float* A    = (const float*)d_in[0];
  const float* X    = (const float*)d_in[1];
  const float* w0a  = (const float*)d_in[2];
  const float* w0b  = (const float*)d_in[3];
  const float* w1   = (const float*)d_in[4];
  const float* gcnw = (const float*)d_in[5];
  const float* gcnb = (const float*)d_in[6];
  const float* l1w  = (const float*)d_in[7];
  const float* l1b  = (const float*)d_in[8];
  const float* l2w  = (const float*)d_in[9];
  const float* l2b  = (const float*)d_in[10];
  float* out = (float*)d_out;

  // workspace carve (~93 MB total)
  char* p = (char*)d_ws;
  auto carve = [&](size_t bytes) -> char* {
    char* r = p; p += (bytes + 255) & ~(size_t)255; return r;
  };
  float*  F     = (float*)carve(32 * 4);
  float*  dinv1 = (float*)carve((size_t)CC * NN * 4);
  float*  dinv2 = (float*)carve((size_t)CC * NN * 4);
  float*  disv  = (float*)carve((size_t)CC * NN * 4);
  float*  part  = (float*)carve((size_t)CC * 16 * NN * 4);
  bf16_t* buf1  = (bf16_t*)carve((size_t)CC * N2 * 2); // Ha, then Hn
  bf16_t* buf2  = (bf16_t*)carve((size_t)CC * N2 * 2); // HbT, then A3
  bf16_t* buf3  = (bf16_t*)carve((size_t)CC * N2 * 2); // Hb2T
  float*  buf4  = (float*)carve((size_t)CC * N2 * 4);  // HH, then H2
  bf16_t* Xb    = (bf16_t*)carve((size_t)NN * WIN * 2);
  bf16_t* gwT   = (bf16_t*)carve((size_t)WOUT * WIN * 2);
  bf16_t* l1wb  = (bf16_t*)carve((size_t)WOUT * CC * WOUT * 2);
  bf16_t* l2wb  = (bf16_t*)carve((size_t)WOUT * WOUT * 2);
  float*  XW    = (float*)carve((size_t)NN * WOUT * 4);
  bf16_t* XWT   = (bf16_t*)carve((size_t)WOUT * NN * 2);
  float*  Tb    = (float*)carve((size_t)CC * NN * WOUT * 4); // T, then lin1-pre, then lin2-pre
  bf16_t* Xcat  = (bf16_t*)carve((size_t)NN * CC * WOUT * 2);
  bf16_t* hb    = (bf16_t*)carve((size_t)NN * WOUT * 2);

  // prep
  k_softmax<<<1, 64, 0, stream>>>(w0a, w0b, w1, F);
  k_cast_bf16<<<(NN * WIN / 8 + 255) / 256, 256, 0, stream>>>(X, Xb, NN * WIN / 8);
  k_cast_bf16<<<(WOUT * CC * WOUT / 8 + 255) / 256, 256, 0, stream>>>(l1w, l1wb, WOUT * CC * WOUT / 8);
  k_cast_bf16<<<(WOUT * WOUT / 8 + 255) / 256, 256, 0, stream>>>(l2w, l2wb, WOUT * WOUT / 8);
  k_transpose_cast<<<dim3(WIN / 64, WOUT / 64), 256, 0, stream>>>(gcnw, gwT, WIN, WOUT);
  k_combine<<<dim3(32, 32), 256, 0, stream>>>(A, F, buf1, buf2, buf3);

  // layer 0: HH = Ha @ Hb, normalize
  k_gemm<<<dim3(16, 16, 2), 256, 0, stream>>>(buf1, buf2, buf4, NN, NN, N2, N2, N2);
  k_colsum_partial<<<dim3(8, 16, 2), 256, 0, stream>>>(buf4, part);
  k_colsum_finish<<<CC * NN / 256, 256, 0, stream>>>(part, dinv1, nullptr);
  k_normalize1<<<(int)((CC * N2 / 4) / 256), 256, 0, stream>>>(buf4, dinv1, buf1);

  // layer 1: H2 = Hn @ Hb2, normalize (+ GCN dis), transposed output with dis[r] folded
  k_gemm<<<dim3(16, 16, 2), 256, 0, stream>>>(buf1, buf3, buf4, NN, NN, N2, N2, N2);
  k_colsum_partial<<<dim3(8, 16, 2), 256, 0, stream>>>(buf4, part);
  k_colsum_finish<<<CC * NN / 256, 256, 0, stream>>>(part, dinv2, disv);
  k_normalize2T<<<dim3(32, 32, 2), 256, 0, stream>>>(buf4, dinv2, disv, buf2);

  // GCN: XW = X @ gcn_w; T = A3 @ XWT^T; epilogue adds diagonal + bias + relu -> Xcat
  k_gemm<<<dim3(16, 2, 1), 256, 0, stream>>>(Xb, gwT, XW, WOUT, WIN, 0, 0, 0);
  k_transpose_cast<<<dim3(NN / 64, WOUT / 64), 256, 0, stream>>>(XW, XWT, NN, WOUT);
  k_gemm<<<dim3(16, 2, 2), 256, 0, stream>>>(buf2, XWT, Tb, WOUT, NN, N2, 0, (long long)NN * WOUT);
  k_gcn_epi<<<(int)(((long long)CC * NN * WOUT / 4) / 256), 256, 0, stream>>>(Tb, XW, gcnb, disv, Xcat);

  // MLP
  k_gemm<<<dim3(16, 2, 1), 256, 0, stream>>>(Xcat, l1wb, Tb, WOUT, CC * WOUT, 0, 0, 0);
  k_relu_bias_bf16<<<(NN * WOUT / 4) / 256, 256, 0, stream>>>(Tb, l1b, hb);
  k_gemm<<<dim3(16, 2, 1), 256, 0, stream>>>(hb, l2wb, Tb, WOUT, WOUT, 0, 0, 0);
  k_bias_out<<<(NN * WOUT / 4) / 256, 256, 0, stream>>>(Tb, l2b, out);
}

// Round 2
// 233.708 us; speedup vs baseline: 1.2593x; 1.2593x over previous
//
#include <hip/hip_runtime.h>
#include <cstdint>
#include <cstddef>

#define NN   2048
#define N2   (2048LL*2048LL)
#define CC   2
#define EE   5
#define WIN  512
#define WOUT 256

typedef __bf16 bf16_t;
typedef __attribute__((ext_vector_type(8))) __bf16 bf16x8;
typedef __attribute__((ext_vector_type(4))) __bf16 bf16x4;
typedef __attribute__((ext_vector_type(4))) float  f32x4;

// ---------------- fused small-weight casts ----------------
// X (1048576 f32), l1w (131072), l2w (65536) -> bf16, 8 elems/thread
__global__ void k_prep(const float* __restrict__ X, const float* __restrict__ l1w,
                       const float* __restrict__ l2w, bf16_t* __restrict__ Xb,
                       bf16_t* __restrict__ l1wb, bf16_t* __restrict__ l2wb) {
  int i = blockIdx.x * 256 + threadIdx.x;
  const float* src; bf16_t* dst; int off;
  if (i < 131072)      { src = X;   dst = Xb;   off = i; }
  else if (i < 147456) { src = l1w; dst = l1wb; off = i - 131072; }
  else if (i < 155648) { src = l2w; dst = l2wb; off = i - 147456; }
  else return;
  float4 a = ((const float4*)src)[off * 2];
  float4 b = ((const float4*)src)[off * 2 + 1];
  bf16x8 o;
  o[0] = (bf16_t)a.x; o[1] = (bf16_t)a.y; o[2] = (bf16_t)a.z; o[3] = (bf16_t)a.w;
  o[4] = (bf16_t)b.x; o[5] = (bf16_t)b.y; o[6] = (bf16_t)b.z; o[7] = (bf16_t)b.w;
  ((bf16x8*)dst)[off] = o;
}

// out[n][m] = bf16(in[m][n]); M,N multiples of 64
__global__ void k_transpose_cast(const float* __restrict__ in, bf16_t* __restrict__ out,
                                 int M, int N) {
  __shared__ bf16_t tile[64][65];
  int m0 = blockIdx.x * 64, n0 = blockIdx.y * 64;
  int t = threadIdx.x, tr = t >> 4, tc = (t & 15) << 2;
#pragma unroll
  for (int v = 0; v < 4; ++v) {
    int r = tr + v * 16;
    float4 d = *(const float4*)&in[(long long)(m0 + r) * N + n0 + tc];
    tile[r][tc + 0] = (bf16_t)d.x; tile[r][tc + 1] = (bf16_t)d.y;
    tile[r][tc + 2] = (bf16_t)d.z; tile[r][tc + 3] = (bf16_t)d.w;
  }
  __syncthreads();
#pragma unroll
  for (int v = 0; v < 4; ++v) {
    int r = tr + v * 16;
    bf16x4 o;
    o[0] = tile[tc + 0][r]; o[1] = tile[tc + 1][r];
    o[2] = tile[tc + 2][r]; o[3] = tile[tc + 3][r];
    *(bf16x4*)&out[(long long)(n0 + r) * M + m0 + tc] = o;
  }
}

// bf16 transpose: out[c][n][r] = in[c][r][n]
__global__ void k_transpose_bf16(const bf16_t* __restrict__ in, bf16_t* __restrict__ out) {
  __shared__ bf16_t tile[64][65];
  int r0 = blockIdx.x * 64, n0 = blockIdx.y * 64, c = blockIdx.z;
  int t = threadIdx.x, tr = t >> 4, tc = (t & 15) << 2;
  const bf16_t* src = in + (long long)c * N2;
  bf16_t* dst = out + (long long)c * N2;
#pragma unroll
  for (int v = 0; v < 4; ++v) {
    int lr = tr + v * 16;
    bf16x4 d = *(const bf16x4*)&src[(long long)(r0 + lr) * NN + n0 + tc];
    tile[lr][tc + 0] = d[0]; tile[lr][tc + 1] = d[1];
    tile[lr][tc + 2] = d[2]; tile[lr][tc + 3] = d[3];
  }
  __syncthreads();
#pragma unroll
  for (int v = 0; v < 4; ++v) {
    int lr = tr + v * 16;
    bf16x4 o;
    o[0] = tile[tc + 0][lr]; o[1] = tile[tc + 1][lr];
    o[2] = tile[tc + 2][lr]; o[3] = tile[tc + 3][lr];
    *(bf16x4*)&dst[(long long)(n0 + lr) * NN + r0 + tc] = o;
  }
}

// ---------------- combine (softmax inline) + Ha column-sum partials ----------------

__global__ void k_combine(const float* __restrict__ A,
                          const float* __restrict__ w0a, const float* __restrict__ w0b,
                          const float* __restrict__ w1,
                          bf16_t* __restrict__ Ha, bf16_t* __restrict__ HbT,
                          bf16_t* __restrict__ Hb2T, float* __restrict__ part) {
  __shared__ bf16_t tl[4][64][65];
  __shared__ float cs[2][16][64];
  float f[3][2][5];
  {
    const float* wp[3] = {w0a, w0b, w1};
#pragma unroll
    for (int w = 0; w < 3; ++w)
#pragma unroll
      for (int c = 0; c < 2; ++c) {
        float x[5], m = -1e30f, s = 0.f;
#pragma unroll
        for (int e = 0; e < 5; ++e) { x[e] = wp[w][c * 5 + e]; m = fmaxf(m, x[e]); }
#pragma unroll
        for (int e = 0; e < 5; ++e) { x[e] = expf(x[e] - m); s += x[e]; }
#pragma unroll
        for (int e = 0; e < 5; ++e) f[w][c][e] = x[e] / s;
      }
  }
  int i0 = blockIdx.x * 64, j0 = blockIdx.y * 64;
  int t = threadIdx.x, tr = t >> 4, tc = (t & 15) << 2;
  float cs0[4] = {0, 0, 0, 0}, cs1[4] = {0, 0, 0, 0};

#pragma unroll
  for (int v = 0; v < 4; ++v) {
    int lr = tr + v * 16;
    long long gi = i0 + lr;
    const float* base = A + gi * (long long)NN + j0 + tc;
    float av[5][4];
#pragma unroll
    for (int e = 0; e < 5; ++e) {
      float4 q = *(const float4*)(base + (long long)e * N2);
      av[e][0] = q.x; av[e][1] = q.y; av[e][2] = q.z; av[e][3] = q.w;
    }
    bf16x4 ha0, ha1;
#pragma unroll
    for (int x = 0; x < 4; ++x) {
      float s0 = 0.f, s1 = 0.f, s2 = 0.f, s3 = 0.f, s4 = 0.f, s5 = 0.f;
#pragma unroll
      for (int e = 0; e < 5; ++e) {
        float u = av[e][x];
        s0 += f[0][0][e] * u; s1 += f[0][1][e] * u;
        s2 += f[1][0][e] * u; s3 += f[1][1][e] * u;
        s4 += f[2][0][e] * u; s5 += f[2][1][e] * u;
      }
      ha0[x] = (bf16_t)s0; cs0[x] += (float)ha0[x];
      ha1[x] = (bf16_t)s1; cs1[x] += (float)ha1[x];
      tl[0][lr][tc + x] = (bf16_t)s2; tl[1][lr][tc + x] = (bf16_t)s3;
      tl[2][lr][tc + x] = (bf16_t)s4; tl[3][lr][tc + x] = (bf16_t)s5;
    }
    *(bf16x4*)&Ha[0 * N2 + gi * NN + j0 + tc] = ha0;
    *(bf16x4*)&Ha[1 * N2 + gi * NN + j0 + tc] = ha1;
  }
#pragma unroll
  for (int x = 0; x < 4; ++x) { cs[0][tr][tc + x] = cs0[x]; cs[1][tr][tc + x] = cs1[x]; }
  __syncthreads();
#pragma unroll
  for (int v = 0; v < 4; ++v) {
    int lr = tr + v * 16;
#pragma unroll
    for (int k4 = 0; k4 < 4; ++k4) {
      bf16x4 o;
      o[0] = tl[k4][tc + 0][lr]; o[1] = tl[k4][tc + 1][lr];
      o[2] = tl[k4][tc + 2][lr]; o[3] = tl[k4][tc + 3][lr];
      bf16_t* dst = ((k4 < 2) ? HbT : Hb2T) + (long long)(k4 & 1) * N2
                    + (long long)(j0 + lr) * NN + i0 + tc;
      *(bf16x4*)dst = o;
    }
  }
  if (t < 128) {
    int ch = t >> 6, col = t & 63;
    float s = 0.f;
#pragma unroll
    for (int r = 0; r < 16; ++r) s += cs[ch][r][col];
    part[((long long)ch * 32 + blockIdx.x) * NN + j0 + col] = s;
  }
}

__global__ void k_s_finish(const float* __restrict__ part, float* __restrict__ s) {
  int idx = blockIdx.x * 256 + threadIdx.x; // 4096 = c*2048+k
  int c = idx >> 11, k = idx & 2047;
  float acc = 0.f;
#pragma unroll
  for (int ib = 0; ib < 32; ++ib) acc += part[((long long)c * 32 + ib) * NN + k];
  s[idx] = acc;
}

// deg[c][j] = sum_k (svec[c][k] - Arows[c][j][k]) * BT[c][j][k]
// EMIT_DIS=false: out1=dinv (1/deg), out2=m1 (deg!=0 ? 1:0)
// EMIT_DIS=true : out1=colscale (dis/deg), out2=disv (deg!=0 ? 1/sqrt2 : 1)
template<bool EMIT_DIS>
__global__ void k_deg(const float* __restrict__ svec, const bf16_t* __restrict__ Arows,
                      const bf16_t* __restrict__ BT,
                      float* __restrict__ out1, float* __restrict__ out2) {
  int c = blockIdx.y;
  int j = blockIdx.x * 4 + (threadIdx.x >> 6);
  int lane = threadIdx.x & 63;
  const bf16_t* a = Arows + (long long)c * N2 + (long long)j * NN;
  const bf16_t* b = BT + (long long)c * N2 + (long long)j * NN;
  const float* s = svec + c * NN;
  float acc = 0.f;
#pragma unroll
  for (int it = 0; it < 4; ++it) {
    int k0 = (lane + it * 64) * 8;
    bf16x8 av = *(const bf16x8*)(a + k0);
    bf16x8 bv = *(const bf16x8*)(b + k0);
    float4 s0 = *(const float4*)(s + k0);
    float4 s1 = *(const float4*)(s + k0 + 4);
    acc += (s0.x - (float)av[0]) * (float)bv[0];
    acc += (s0.y - (float)av[1]) * (float)bv[1];
    acc += (s0.z - (float)av[2]) * (float)bv[2];
    acc += (s0.w - (float)av[3]) * (float)bv[3];
    acc += (s1.x - (float)av[4]) * (float)bv[4];
    acc += (s1.y - (float)av[5]) * (float)bv[5];
    acc += (s1.z - (float)av[6]) * (float)bv[6];
    acc += (s1.w - (float)av[7]) * (float)bv[7];
  }
#pragma unroll
  for (int o = 32; o > 0; o >>= 1) acc += __shfl_xor(acc, o, 64);
  if (lane == 0) {
    float deg = acc;
    bool nz = (deg != 0.f);
    if (!EMIT_DIS) {
      out1[c * NN + j] = nz ? 1.f / deg : 0.f;
      out2[c * NN + j] = nz ? 1.f : 0.f;
    } else {
      float dis = nz ? 0.70710678118654752f : 1.f;
      out1[c * NN + j] = nz ? dis / deg : 0.f;
      out2[c * NN + j] = dis;
    }
  }
}

// ---------------- bf16 GEMM with fused epilogues ----------------
// C[M,N] = A[M,K] @ B[N,K]^T. 128x128 tile, 4 waves, double-buffered LDS staging.

enum { EP_F32 = 0, EP_NORM1 = 1, EP_NORM2 = 2, EP_BRELU = 3, EP_BF32 = 4 };

template<int EP>
__global__ __launch_bounds__(256)
void k_gemm(const bf16_t* __restrict__ A, const bf16_t* __restrict__ B,
            void* __restrict__ Cv,
            const float* __restrict__ aux1, const float* __restrict__ aux2,
            int N, int K, int lda, int ldb,
            long long zA, long long zB, long long zC) {
  __shared__ __align__(16) bf16_t As[2][128 * 32];
  __shared__ __align__(16) bf16_t Bs[2][128 * 32];
  int cz = blockIdx.z;
  const bf16_t* Ab = A + cz * zA + (long long)blockIdx.x * 128 * lda;
  const bf16_t* Bb = B + cz * zB + (long long)blockIdx.y * 128 * ldb;
  int t = threadIdx.x, wid = t >> 6, lane = t & 63;
  int wr = wid >> 1, wc = wid & 1;
  f32x4 acc[4][4] = {};
  int frow = lane & 15, fk = (lane >> 4) << 3;
  int srow = t >> 2, scol = (t & 3) << 3;
  int nt = K >> 5; // K multiple of 64 -> nt even

  auto STAGE = [&](int TT, int BUF) {
    long long kko = (long long)TT * 32;
    const bf16_t* ga0 = Ab + (long long)srow * lda + kko + scol;
    const bf16_t* gb0 = Bb + (long long)srow * ldb + kko + scol;
    char* la = (char*)As[BUF] + wid * 64 * 16;
    char* lb = (char*)Bs[BUF] + wid * 64 * 16;
    __builtin_amdgcn_global_load_lds((__attribute__((address_space(1))) void*)ga0,
        (__attribute__((address_space(3))) void*)la, 16, 0, 0);
    __builtin_amdgcn_global_load_lds((__attribute__((address_space(1))) void*)gb0,
        (__attribute__((address_space(3))) void*)lb, 16, 0, 0);
    __builtin_amdgcn_global_load_lds((__attribute__((address_space(1))) void*)(ga0 + 64LL * lda),
        (__attribute__((address_space(3))) void*)(la + 256 * 16), 16, 0, 0);
    __builtin_amdgcn_global_load_lds((__attribute__((address_space(1))) void*)(gb0 + 64LL * ldb),
        (__attribute__((address_space(3))) void*)(lb + 256 * 16), 16, 0, 0);
  };
  auto COMPUTE = [&](int BUF) {
    bf16x8 af[4], bfr[4];
#pragma unroll
    for (int m = 0; m < 4; ++m)
      af[m] = *(const bf16x8*)&As[BUF][(wr * 64 + m * 16 + frow) * 32 + fk];
#pragma unroll
    for (int n = 0; n < 4; ++n)
      bfr[n] = *(const bf16x8*)&Bs[BUF][(wc * 64 + n * 16 + frow) * 32 + fk];
#pragma unroll
    for (int m = 0; m < 4; ++m)
#pragma unroll
      for (int n = 0; n < 4; ++n)
        acc[m][n] = __builtin_amdgcn_mfma_f32_16x16x32_bf16(af[m], bfr[n], acc[m][n], 0, 0, 0);
  };

  STAGE(0, 0);
  __syncthreads();
  for (int tt = 0; tt < nt; tt += 2) {
    if (tt + 1 < nt) STAGE(tt + 1, 1);
    COMPUTE(0);
    __syncthreads(); // drains buf1 stage; all buf0 reads done
    if (tt + 2 < nt) STAGE(tt + 2, 0);
    COMPUTE(1);
    __syncthreads();
  }

  // C/D layout: col = lane&15, row = (lane>>4)*4 + reg
  int r0 = blockIdx.x * 128 + wr * 64 + ((lane >> 4) << 2);
  int c0 = blockIdx.y * 128 + wc * 64 + (lane & 15);

  if constexpr (EP == EP_F32) {
    float* Cb = (float*)Cv + cz * zC;
#pragma unroll
    for (int m = 0; m < 4; ++m)
#pragma unroll
      for (int n = 0; n < 4; ++n)
#pragma unroll
        for (int j = 0; j < 4; ++j)
          Cb[(long long)(r0 + m * 16 + j) * N + c0 + n * 16] = acc[m][n][j];
  } else if constexpr (EP == EP_NORM1) {
    bf16_t* Cb = (bf16_t*)Cv + cz * zC;
    float dj[4];
#pragma unroll
    for (int n = 0; n < 4; ++n) dj[n] = aux1[cz * NN + c0 + n * 16];
#pragma unroll
    for (int m = 0; m < 4; ++m)
#pragma unroll
      for (int n = 0; n < 4; ++n)
#pragma unroll
        for (int j = 0; j < 4; ++j) {
          int r = r0 + m * 16 + j, col = c0 + n * 16;
          float v = (r == col) ? 0.f : acc[m][n][j] * dj[n];
          Cb[(long long)r * N + col] = (bf16_t)v;
        }
  } else if constexpr (EP == EP_NORM2) {
    bf16_t* Cb = (bf16_t*)Cv + cz * zC;
    float dj[4];
#pragma unroll
    for (int n = 0; n < 4; ++n) dj[n] = aux1[cz * NN + c0 + n * 16];
#pragma unroll
    for (int m = 0; m < 4; ++m) {
      float dr[4];
#pragma unroll
      for (int j = 0; j < 4; ++j) dr[j] = aux2[cz * NN + r0 + m * 16 + j];
#pragma unroll
      for (int n = 0; n < 4; ++n)
#pragma unroll
        for (int j = 0; j < 4; ++j) {
          int r = r0 + m * 16 + j, col = c0 + n * 16;
          float v = (r == col) ? 0.f : acc[m][n][j] * dj[n] * dr[j];
          Cb[(long long)r * N + col] = (bf16_t)v;
        }
    }
  } else if constexpr (EP == EP_BRELU) {
    bf16_t* Cb = (bf16_t*)Cv;
    float bj[4];
#pragma unroll
    for (int n = 0; n < 4; ++n) bj[n] = aux1[c0 + n * 16];
#pragma unroll
    for (int m = 0; m < 4; ++m)
#pragma unroll
      for (int n = 0; n < 4; ++n)
#pragma unroll
        for (int j = 0; j < 4; ++j)
          Cb[(long long)(r0 + m * 16 + j) * N + c0 + n * 16] =
              (bf16_t)fmaxf(acc[m][n][j] + bj[n], 0.f);
  } else { // EP_BF32: bias add, f32 out
    float* Cb = (float*)Cv;
    float bj[4];
#pragma unroll
    for (int n = 0; n < 4; ++n) bj[n] = aux1[c0 + n * 16];
#pragma unroll
    for (int m = 0; m < 4; ++m)
#pragma unroll
      for (int n = 0; n < 4; ++n)
#pragma unroll
        for (int j = 0; j < 4; ++j)
          Cb[(long long)(r0 + m * 16 + j) * N + c0 + n * 16] = acc[m][n][j] + bj[n];
  }
}

// ---------------- GCN epilogue: sum split-K partials + diagonal + bias + relu ----------------

__global__ void k_gcn_epi(const float* __restrict__ Tp, const float* __restrict__ XW,
                          const float* __restrict__ gcn_b, const float* __restrict__ disv,
                          bf16_t* __restrict__ Xcat) {
  long long idx4 = ((long long)blockIdx.x * 256 + threadIdx.x) * 4;
  int c = (int)(idx4 >> 19);
  int rem = (int)(idx4 & ((1 << 19) - 1));
  int n = rem >> 8, fcol = rem & 255;
  float4 acc = {0.f, 0.f, 0.f, 0.f};
#pragma unroll
  for (int kp = 0; kp < 4; ++kp) {
    float4 v = *(const float4*)(Tp + (long long)(c * 4 + kp) * NN * WOUT + rem);
    acc.x += v.x; acc.y += v.y; acc.z += v.z; acc.w += v.w;
  }
  float4 xw = *(const float4*)(XW + rem);
  float4 b  = *(const float4*)(gcn_b + fcol);
  float dn = disv[c * NN + n], d2 = dn * dn;
  bf16x4 o;
  o[0] = (bf16_t)fmaxf(acc.x + d2 * xw.x + b.x, 0.f);
  o[1] = (bf16_t)fmaxf(acc.y + d2 * xw.y + b.y, 0.f);
  o[2] = (bf16_t)fmaxf(acc.z + d2 * xw.z + b.z, 0.f);
  o[3] = (bf16_t)fmaxf(acc.w + d2 * xw.w + b.w, 0.f);
  *(bf16x4*)&Xcat[(long long)n * (CC * WOUT) + c * WOUT + fcol] = o;
}

// ---------------- launch ----------------

extern "C" void kernel_launch(void* const* d_in, const int* in_sizes, int n_in,
                              void* d_out, int out_size, void* d_ws, size_t ws_size,
                              hipStream_t stream) {
  const float* A    = (const float*)d_in[0];
  const float* X    = (const float*)d_in[1];
  const float* w0a  = (const float*)d_in[2];
  const float* w0b  = (const float*)d_in[3];
  const float* w1   = (const float*)d_in[4];
  const float* gcnw = (const float*)d_in[5];
  const float* gcnb = (const float*)d_in[6];
  const float* l1w  = (const float*)d_in[7];
  const float* l1b  = (const float*)d_in[8];
  const float* l2w  = (const float*)d_in[9];
  const float* l2b  = (const float*)d_in[10];
  float* out = (float*)d_out;

  char* p = (char*)d_ws;
  auto carve = [&](size_t bytes) -> char* {
    char* r = p; p += (bytes + 255) & ~(size_t)255; return r;
  };
  float*  svec  = (float*)carve((size_t)CC * NN * 4);
  float*  dinv1 = (float*)carve((size_t)CC * NN * 4);
  float*  m1    = (float*)carve((size_t)CC * NN * 4);
  float*  cscal = (float*)carve((size_t)CC * NN * 4);
  float*  disv  = (float*)carve((size_t)CC * NN * 4);
  float*  part  = (float*)carve((size_t)CC * 32 * NN * 4);
  bf16_t* S1    = (bf16_t*)carve((size_t)CC * N2 * 2); // Ha -> A3
  bf16_t* S2    = (bf16_t*)carve((size_t)CC * N2 * 2); // HbT -> H2s
  bf16_t* S3    = (bf16_t*)carve((size_t)CC * N2 * 2); // Hb2T -> Tb (split-K f32 partials, same 16MB)
  bf16_t* Hn    = (bf16_t*)carve((size_t)CC * N2 * 2);
  bf16_t* Xb    = (bf16_t*)carve((size_t)NN * WIN * 2);
  bf16_t* gwT   = (bf16_t*)carve((size_t)WOUT * WIN * 2);
  bf16_t* l1wb  = (bf16_t*)carve((size_t)WOUT * CC * WOUT * 2);
  bf16_t* l2wb  = (bf16_t*)carve((size_t)WOUT * WOUT * 2);
  float*  XW    = (float*)carve((size_t)NN * WOUT * 4);
  bf16_t* XWT   = (bf16_t*)carve((size_t)WOUT * NN * 2);
  bf16_t* Xcat  = (bf16_t*)carve((size_t)NN * CC * WOUT * 2);
  bf16_t* hb    = (bf16_t*)carve((size_t)NN * WOUT * 2);

  bf16_t* Ha = S1;  bf16_t* A3  = S1;
  bf16_t* HbT = S2; bf16_t* H2s = S2;
  bf16_t* Hb2T = S3; float* Tb  = (float*)S3;

  // prep
  k_prep<<<608, 256, 0, stream>>>(X, l1w, l2w, Xb, l1wb, l2wb);
  k_transpose_cast<<<dim3(WIN / 64, WOUT / 64), 256, 0, stream>>>(gcnw, gwT, WIN, WOUT);
  k_combine<<<dim3(32, 32), 256, 0, stream>>>(A, w0a, w0b, w1, Ha, HbT, Hb2T, part);
  k_s_finish<<<16, 256, 0, stream>>>(part, svec);

  // layer 0: deg analytically, GEMM with fused normalize -> Hn (bf16)
  k_deg<false><<<dim3(512, 2), 256, 0, stream>>>(svec, Ha, HbT, dinv1, m1);
  k_gemm<EP_NORM1><<<dim3(16, 16, 2), 256, 0, stream>>>(
      Ha, HbT, Hn, dinv1, nullptr, NN, NN, NN, NN, N2, N2, N2);

  // layer 1: colsum(Hn)=m1 analytically; GEMM fused normalize+dis scalings -> H2s row-major
  k_deg<true><<<dim3(512, 2), 256, 0, stream>>>(m1, Hn, Hb2T, cscal, disv);
  k_gemm<EP_NORM2><<<dim3(16, 16, 2), 256, 0, stream>>>(
      Hn, Hb2T, H2s, cscal, disv, NN, NN, NN, NN, N2, N2, N2);
  k_transpose_bf16<<<dim3(32, 32, 2), 256, 0, stream>>>(H2s, A3);

  // GCN: XW = X @ gcn_w (f32); T = A3 @ XWT^T split-K x4; epilogue -> Xcat
  k_gemm<EP_F32><<<dim3(16, 2, 1), 256, 0, stream>>>(
      Xb, gwT, XW, nullptr, nullptr, WOUT, WIN, WIN, WIN, 0, 0, 0);
  k_transpose_cast<<<dim3(NN / 64, WOUT / 64), 256, 0, stream>>>(XW, XWT, NN, WOUT);
  for (int c = 0; c < 2; ++c)
    k_gemm<EP_F32><<<dim3(16, 2, 4), 256, 0, stream>>>(
        A3 + (long long)c * N2, XWT, Tb + (long long)c * 4 * NN * WOUT,
        nullptr, nullptr, WOUT, 512, NN, NN, 512, 512, (long long)NN * WOUT);
  k_gcn_epi<<<1024, 256, 0, stream>>>(Tb, XW, gcnb, disv, Xcat);

  // MLP with fused bias(+relu) epilogues
  k_gemm<EP_BRELU><<<dim3(16, 2, 1), 256, 0, stream>>>(
      Xcat, l1wb, hb, l1b, nullptr, WOUT, CC * WOUT, CC * WOUT, CC * WOUT, 0, 0, 0);
  k_gemm<EP_BF32><<<dim3(16, 2, 1), 256, 0, stream>>>(
      hb, l2wb, out, l2b, nullptr, WOUT, WOUT, WOUT, WOUT, 0, 0, 0);
}

// Round 3
// 224.824 us; speedup vs baseline: 1.3090x; 1.0395x over previous
//
#include <hip/hip_runtime.h>
#include <cstdint>
#include <cstddef>

#define NN   2048
#define N2   (2048LL*2048LL)
#define CC   2
#define EE   5
#define WIN  512
#define WOUT 256

typedef __bf16 bf16_t;
typedef __attribute__((ext_vector_type(8))) __bf16 bf16x8;
typedef __attribute__((ext_vector_type(4))) __bf16 bf16x4;
typedef __attribute__((ext_vector_type(4))) float  f32x4;

// ---------------- fused small-weight casts ----------------
__global__ void k_prep(const float* __restrict__ X, const float* __restrict__ l1w,
                       const float* __restrict__ l2w, bf16_t* __restrict__ Xb,
                       bf16_t* __restrict__ l1wb, bf16_t* __restrict__ l2wb) {
  int i = blockIdx.x * 256 + threadIdx.x;
  const float* src; bf16_t* dst; int off;
  if (i < 131072)      { src = X;   dst = Xb;   off = i; }
  else if (i < 147456) { src = l1w; dst = l1wb; off = i - 131072; }
  else if (i < 155648) { src = l2w; dst = l2wb; off = i - 147456; }
  else return;
  float4 a = ((const float4*)src)[off * 2];
  float4 b = ((const float4*)src)[off * 2 + 1];
  bf16x8 o;
  o[0] = (bf16_t)a.x; o[1] = (bf16_t)a.y; o[2] = (bf16_t)a.z; o[3] = (bf16_t)a.w;
  o[4] = (bf16_t)b.x; o[5] = (bf16_t)b.y; o[6] = (bf16_t)b.z; o[7] = (bf16_t)b.w;
  ((bf16x8*)dst)[off] = o;
}

// out[n][m] = bf16(in[m][n]); M,N multiples of 64 (used for gcn_w only)
__global__ void k_transpose_cast(const float* __restrict__ in, bf16_t* __restrict__ out,
                                 int M, int N) {
  __shared__ bf16_t tile[64][65];
  int m0 = blockIdx.x * 64, n0 = blockIdx.y * 64;
  int t = threadIdx.x, tr = t >> 4, tc = (t & 15) << 2;
#pragma unroll
  for (int v = 0; v < 4; ++v) {
    int r = tr + v * 16;
    float4 d = *(const float4*)&in[(long long)(m0 + r) * N + n0 + tc];
    tile[r][tc + 0] = (bf16_t)d.x; tile[r][tc + 1] = (bf16_t)d.y;
    tile[r][tc + 2] = (bf16_t)d.z; tile[r][tc + 3] = (bf16_t)d.w;
  }
  __syncthreads();
#pragma unroll
  for (int v = 0; v < 4; ++v) {
    int r = tr + v * 16;
    bf16x4 o;
    o[0] = tile[tc + 0][r]; o[1] = tile[tc + 1][r];
    o[2] = tile[tc + 2][r]; o[3] = tile[tc + 3][r];
    *(bf16x4*)&out[(long long)(n0 + r) * M + m0 + tc] = o;
  }
}

// ---------------- combine: 2-phase LDS (low footprint), inline Ha colsum partials ----------------

__global__ void k_combine(const float* __restrict__ A,
                          const float* __restrict__ w0a, const float* __restrict__ w0b,
                          const float* __restrict__ w1,
                          bf16_t* __restrict__ Ha, bf16_t* __restrict__ HbT,
                          bf16_t* __restrict__ Hb2T, float* __restrict__ part) {
  __shared__ bf16_t tl[2][64][65];  // 16.6 KB
  __shared__ float cs[2][16][64];   // 8 KB
  float f[3][2][5];
  {
    const float* wp[3] = {w0a, w0b, w1};
#pragma unroll
    for (int w = 0; w < 3; ++w)
#pragma unroll
      for (int c = 0; c < 2; ++c) {
        float x[5], m = -1e30f, s = 0.f;
#pragma unroll
        for (int e = 0; e < 5; ++e) { x[e] = wp[w][c * 5 + e]; m = fmaxf(m, x[e]); }
#pragma unroll
        for (int e = 0; e < 5; ++e) { x[e] = expf(x[e] - m); s += x[e]; }
#pragma unroll
        for (int e = 0; e < 5; ++e) f[w][c][e] = x[e] / s;
      }
  }
  int i0 = blockIdx.x * 64, j0 = blockIdx.y * 64;
  int t = threadIdx.x, tr = t >> 4, tc = (t & 15) << 2;
  float cs0[4] = {0, 0, 0, 0}, cs1[4] = {0, 0, 0, 0};

  // phase A: Ha (row-major out) + Hb -> tl, colsum partials in regs
#pragma unroll
  for (int v = 0; v < 4; ++v) {
    int lr = tr + v * 16;
    long long gi = i0 + lr;
    const float* base = A + gi * (long long)NN + j0 + tc;
    float av[5][4];
#pragma unroll
    for (int e = 0; e < 5; ++e) {
      float4 q = *(const float4*)(base + (long long)e * N2);
      av[e][0] = q.x; av[e][1] = q.y; av[e][2] = q.z; av[e][3] = q.w;
    }
    bf16x4 ha0, ha1;
#pragma unroll
    for (int x = 0; x < 4; ++x) {
      float s0 = 0.f, s1 = 0.f, s2 = 0.f, s3 = 0.f;
#pragma unroll
      for (int e = 0; e < 5; ++e) {
        float u = av[e][x];
        s0 += f[0][0][e] * u; s1 += f[0][1][e] * u;
        s2 += f[1][0][e] * u; s3 += f[1][1][e] * u;
      }
      ha0[x] = (bf16_t)s0; cs0[x] += (float)ha0[x];
      ha1[x] = (bf16_t)s1; cs1[x] += (float)ha1[x];
      tl[0][lr][tc + x] = (bf16_t)s2; tl[1][lr][tc + x] = (bf16_t)s3;
    }
    *(bf16x4*)&Ha[0 * N2 + gi * NN + j0 + tc] = ha0;
    *(bf16x4*)&Ha[1 * N2 + gi * NN + j0 + tc] = ha1;
  }
#pragma unroll
  for (int x = 0; x < 4; ++x) { cs[0][tr][tc + x] = cs0[x]; cs[1][tr][tc + x] = cs1[x]; }
  __syncthreads();

  // phase B: transposed write of HbT + colsum reduce
#pragma unroll
  for (int v = 0; v < 4; ++v) {
    int lr = tr + v * 16;
#pragma unroll
    for (int ch = 0; ch < 2; ++ch) {
      bf16x4 o;
      o[0] = tl[ch][tc + 0][lr]; o[1] = tl[ch][tc + 1][lr];
      o[2] = tl[ch][tc + 2][lr]; o[3] = tl[ch][tc + 3][lr];
      *(bf16x4*)&HbT[(long long)ch * N2 + (long long)(j0 + lr) * NN + i0 + tc] = o;
    }
  }
  if (t < 128) {
    int ch = t >> 6, col = t & 63;
    float s = 0.f;
#pragma unroll
    for (int r = 0; r < 16; ++r) s += cs[ch][r][col];
    part[((long long)ch * 32 + blockIdx.x) * NN + j0 + col] = s;
  }
  __syncthreads();

  // phase C: reload A tile (L2-hot), compute Hb2 -> tl
#pragma unroll
  for (int v = 0; v < 4; ++v) {
    int lr = tr + v * 16;
    long long gi = i0 + lr;
    const float* base = A + gi * (long long)NN + j0 + tc;
    float av[5][4];
#pragma unroll
    for (int e = 0; e < 5; ++e) {
      float4 q = *(const float4*)(base + (long long)e * N2);
      av[e][0] = q.x; av[e][1] = q.y; av[e][2] = q.z; av[e][3] = q.w;
    }
#pragma unroll
    for (int x = 0; x < 4; ++x) {
      float s4 = 0.f, s5 = 0.f;
#pragma unroll
      for (int e = 0; e < 5; ++e) {
        float u = av[e][x];
        s4 += f[2][0][e] * u; s5 += f[2][1][e] * u;
      }
      tl[0][lr][tc + x] = (bf16_t)s4; tl[1][lr][tc + x] = (bf16_t)s5;
    }
  }
  __syncthreads();

  // phase D: transposed write of Hb2T
#pragma unroll
  for (int v = 0; v < 4; ++v) {
    int lr = tr + v * 16;
#pragma unroll
    for (int ch = 0; ch < 2; ++ch) {
      bf16x4 o;
      o[0] = tl[ch][tc + 0][lr]; o[1] = tl[ch][tc + 1][lr];
      o[2] = tl[ch][tc + 2][lr]; o[3] = tl[ch][tc + 3][lr];
      *(bf16x4*)&Hb2T[(long long)ch * N2 + (long long)(j0 + lr) * NN + i0 + tc] = o;
    }
  }
}

__global__ void k_s_finish(const float* __restrict__ part, float* __restrict__ s) {
  int idx = blockIdx.x * 256 + threadIdx.x; // 4096 = c*2048+k
  int c = idx >> 11, k = idx & 2047;
  float acc = 0.f;
#pragma unroll
  for (int ib = 0; ib < 32; ++ib) acc += part[((long long)c * 32 + ib) * NN + k];
  s[idx] = acc;
}

// deg[c][j] = sum_k (svec[c][k] - Arows[c][j][k]) * BT[c][j][k]
template<bool EMIT_DIS>
__global__ void k_deg(const float* __restrict__ svec, const bf16_t* __restrict__ Arows,
                      const bf16_t* __restrict__ BT,
                      float* __restrict__ out1, float* __restrict__ out2) {
  int c = blockIdx.y;
  int j = blockIdx.x * 4 + (threadIdx.x >> 6);
  int lane = threadIdx.x & 63;
  const bf16_t* a = Arows + (long long)c * N2 + (long long)j * NN;
  const bf16_t* b = BT + (long long)c * N2 + (long long)j * NN;
  const float* s = svec + c * NN;
  float acc = 0.f;
#pragma unroll
  for (int it = 0; it < 4; ++it) {
    int k0 = (lane + it * 64) * 8;
    bf16x8 av = *(const bf16x8*)(a + k0);
    bf16x8 bv = *(const bf16x8*)(b + k0);
    float4 s0 = *(const float4*)(s + k0);
    float4 s1 = *(const float4*)(s + k0 + 4);
    acc += (s0.x - (float)av[0]) * (float)bv[0];
    acc += (s0.y - (float)av[1]) * (float)bv[1];
    acc += (s0.z - (float)av[2]) * (float)bv[2];
    acc += (s0.w - (float)av[3]) * (float)bv[3];
    acc += (s1.x - (float)av[4]) * (float)bv[4];
    acc += (s1.y - (float)av[5]) * (float)bv[5];
    acc += (s1.z - (float)av[6]) * (float)bv[6];
    acc += (s1.w - (float)av[7]) * (float)bv[7];
  }
#pragma unroll
  for (int o = 32; o > 0; o >>= 1) acc += __shfl_xor(acc, o, 64);
  if (lane == 0) {
    float deg = acc;
    bool nz = (deg != 0.f);
    if (!EMIT_DIS) {
      out1[c * NN + j] = nz ? 1.f / deg : 0.f;
      out2[c * NN + j] = nz ? 1.f : 0.f;
    } else {
      float dis = nz ? 0.70710678118654752f : 1.f;
      out1[c * NN + j] = nz ? dis / deg : 0.f;
      out2[c * NN + j] = dis;
    }
  }
}

// ---------------- bf16 GEMM, 128x64 tile, 4 waves (2x2), dbuf LDS, fused epilogues ----------------
// C[M,N] = A[M,K] @ B[N,K]^T. Grid (M/128, N/64, z).

enum { EP_F32 = 0, EP_NORM1 = 1, EP_NORM2T = 2, EP_BRELU = 3, EP_BF32 = 4, EP_XWT = 5, EP_GCN = 6 };

template<int EP>
__global__ __launch_bounds__(256)
void k_gemm(const bf16_t* __restrict__ A, const bf16_t* __restrict__ B,
            void* __restrict__ Cv,
            const float* __restrict__ aux1, const float* __restrict__ aux2,
            bf16_t* __restrict__ aux3,
            int N, int K, int lda, int ldb,
            long long zA, long long zB, long long zC) {
  // As: 2 bufs x 128x32 bf16 = 16 KB at offset 0; Bs: 2 bufs x 64x32 = 8 KB at 16384.
  // Epilogue transpose tile (128x65 bf16 = 16.6 KB) reuses offset 0 after final barrier.
  __shared__ __align__(16) char smem[24576];
  bf16_t* As = (bf16_t*)smem;
  bf16_t* Bs = (bf16_t*)(smem + 16384);
  bf16_t* tile = (bf16_t*)smem;

  int cz = blockIdx.z;
  const bf16_t *Ab, *Bb;
  if constexpr (EP == EP_GCN) {
    int c = cz >> 2, kc = cz & 3;
    Ab = A + (long long)c * zA + kc * 512;
    Bb = B + kc * 512;
  } else {
    Ab = A + cz * zA;
    Bb = B + cz * zB;
  }
  Ab += (long long)blockIdx.x * 128 * lda;
  Bb += (long long)blockIdx.y * 64 * ldb;

  int t = threadIdx.x, wid = t >> 6, lane = t & 63;
  int wr = wid >> 1, wc = wid & 1;
  f32x4 acc[4][2] = {};
  int frow = lane & 15, fk = (lane >> 4) << 3;
  int srow = t >> 2, scol = (t & 3) << 3;
  int nt = K >> 5; // even for all our K

  auto STAGE = [&](int TT, int BUF) {
    long long kko = (long long)TT * 32 + scol;
    const bf16_t* ga0 = Ab + (long long)srow * lda + kko;
    const bf16_t* ga1 = Ab + (long long)(64 + srow) * lda + kko;
    const bf16_t* gb0 = Bb + (long long)srow * ldb + kko;
    char* la = (char*)(As + BUF * 4096) + wid * 64 * 16;
    char* lb = (char*)(Bs + BUF * 2048) + wid * 64 * 16;
    __builtin_amdgcn_global_load_lds((__attribute__((address_space(1))) void*)ga0,
        (__attribute__((address_space(3))) void*)la, 16, 0, 0);
    __builtin_amdgcn_global_load_lds((__attribute__((address_space(1))) void*)ga1,
        (__attribute__((address_space(3))) void*)(la + 256 * 16), 16, 0, 0);
    __builtin_amdgcn_global_load_lds((__attribute__((address_space(1))) void*)gb0,
        (__attribute__((address_space(3))) void*)lb, 16, 0, 0);
  };
  auto COMPUTE = [&](int BUF) {
    bf16x8 af[4], bfr[2];
#pragma unroll
    for (int m = 0; m < 4; ++m)
      af[m] = *(const bf16x8*)&As[BUF * 4096 + (wr * 64 + m * 16 + frow) * 32 + fk];
#pragma unroll
    for (int n = 0; n < 2; ++n)
      bfr[n] = *(const bf16x8*)&Bs[BUF * 2048 + (wc * 32 + n * 16 + frow) * 32 + fk];
#pragma unroll
    for (int m = 0; m < 4; ++m)
#pragma unroll
      for (int n = 0; n < 2; ++n)
        acc[m][n] = __builtin_amdgcn_mfma_f32_16x16x32_bf16(af[m], bfr[n], acc[m][n], 0, 0, 0);
  };

  STAGE(0, 0);
  __syncthreads();
  for (int tt = 0; tt < nt; tt += 2) {
    if (tt + 1 < nt) STAGE(tt + 1, 1);
    COMPUTE(0);
    __syncthreads();
    if (tt + 2 < nt) STAGE(tt + 2, 0);
    COMPUTE(1);
    __syncthreads();
  }

  // C/D frag: col = lane&15, row = (lane>>4)*4 + reg
  int rl0 = wr * 64 + ((lane >> 4) << 2);       // local row 0..127
  int cl0 = wc * 32 + (lane & 15);              // local col 0..63
  int r0 = blockIdx.x * 128 + rl0;
  int c0 = blockIdx.y * 64 + cl0;

  if constexpr (EP == EP_F32 || EP == EP_GCN) {
    float* Cb = (float*)Cv + cz * zC;
#pragma unroll
    for (int m = 0; m < 4; ++m)
#pragma unroll
      for (int n = 0; n < 2; ++n)
#pragma unroll
        for (int j = 0; j < 4; ++j)
          Cb[(long long)(r0 + m * 16 + j) * N + c0 + n * 16] = acc[m][n][j];
  } else if constexpr (EP == EP_NORM1) {
    bf16_t* Cb = (bf16_t*)Cv + cz * zC;
    float dj[2];
#pragma unroll
    for (int n = 0; n < 2; ++n) dj[n] = aux1[cz * NN + c0 + n * 16];
#pragma unroll
    for (int m = 0; m < 4; ++m)
#pragma unroll
      for (int n = 0; n < 2; ++n)
#pragma unroll
        for (int j = 0; j < 4; ++j) {
          int r = r0 + m * 16 + j, col = c0 + n * 16;
          float v = (r == col) ? 0.f : acc[m][n][j] * dj[n];
          Cb[(long long)r * N + col] = (bf16_t)v;
        }
  } else if constexpr (EP == EP_NORM2T) {
    // scaled+transposed: A3[c][n][r] = (r==n)?0 : acc*dj[n]*dr[r], via LDS transpose
    bf16_t* Cb = (bf16_t*)Cv + cz * zC;
    float dj[2];
#pragma unroll
    for (int n = 0; n < 2; ++n) dj[n] = aux1[cz * NN + c0 + n * 16];
#pragma unroll
    for (int m = 0; m < 4; ++m) {
      float dr[4];
#pragma unroll
      for (int j = 0; j < 4; ++j) dr[j] = aux2[cz * NN + r0 + m * 16 + j];
#pragma unroll
      for (int n = 0; n < 2; ++n)
#pragma unroll
        for (int j = 0; j < 4; ++j) {
          int r = r0 + m * 16 + j, col = c0 + n * 16;
          float v = (r == col) ? 0.f : acc[m][n][j] * dj[n] * dr[j];
          tile[(rl0 + m * 16 + j) * 65 + cl0 + n * 16] = (bf16_t)v;
        }
    }
    __syncthreads();
    int nl = t >> 5, rl = (t & 31) * 4;
#pragma unroll
    for (int vv = 0; vv < 8; ++vv) {
      int n_l = nl + vv * 8;
      bf16x4 o;
      o[0] = tile[(rl + 0) * 65 + n_l]; o[1] = tile[(rl + 1) * 65 + n_l];
      o[2] = tile[(rl + 2) * 65 + n_l]; o[3] = tile[(rl + 3) * 65 + n_l];
      *(bf16x4*)&Cb[(long long)(blockIdx.y * 64 + n_l) * NN + blockIdx.x * 128 + rl] = o;
    }
  } else if constexpr (EP == EP_XWT) {
    // f32 row-major C + bf16 transposed copy (XWT[f][n]) via LDS
    float* Cb = (float*)Cv;
#pragma unroll
    for (int m = 0; m < 4; ++m)
#pragma unroll
      for (int n = 0; n < 2; ++n)
#pragma unroll
        for (int j = 0; j < 4; ++j) {
          float v = acc[m][n][j];
          Cb[(long long)(r0 + m * 16 + j) * N + c0 + n * 16] = v;
          tile[(rl0 + m * 16 + j) * 65 + cl0 + n * 16] = (bf16_t)v;
        }
    __syncthreads();
    int nl = t >> 5, rl = (t & 31) * 4;
#pragma unroll
    for (int vv = 0; vv < 8; ++vv) {
      int n_l = nl + vv * 8;
      bf16x4 o;
      o[0] = tile[(rl + 0) * 65 + n_l]; o[1] = tile[(rl + 1) * 65 + n_l];
      o[2] = tile[(rl + 2) * 65 + n_l]; o[3] = tile[(rl + 3) * 65 + n_l];
      *(bf16x4*)&aux3[(long long)(blockIdx.y * 64 + n_l) * NN + blockIdx.x * 128 + rl] = o;
    }
  } else if constexpr (EP == EP_BRELU) {
    bf16_t* Cb = (bf16_t*)Cv;
    float bj[2];
#pragma unroll
    for (int n = 0; n < 2; ++n) bj[n] = aux1[c0 + n * 16];
#pragma unroll
    for (int m = 0; m < 4; ++m)
#pragma unroll
      for (int n = 0; n < 2; ++n)
#pragma unroll
        for (int j = 0; j < 4; ++j)
          Cb[(long long)(r0 + m * 16 + j) * N + c0 + n * 16] =
              (bf16_t)fmaxf(acc[m][n][j] + bj[n], 0.f);
  } else { // EP_BF32
    float* Cb = (float*)Cv;
    float bj[2];
#pragma unroll
    for (int n = 0; n < 2; ++n) bj[n] = aux1[c0 + n * 16];
#pragma unroll
    for (int m = 0; m < 4; ++m)
#pragma unroll
      for (int n = 0; n < 2; ++n)
#pragma unroll
        for (int j = 0; j < 4; ++j)
          Cb[(long long)(r0 + m * 16 + j) * N + c0 + n * 16] = acc[m][n][j] + bj[n];
  }
}

// ---------------- GCN epilogue: sum split-K partials + diagonal + bias + relu ----------------

__global__ void k_gcn_epi(const float* __restrict__ Tp, const float* __restrict__ XW,
                          const float* __restrict__ gcn_b, const float* __restrict__ disv,
                          bf16_t* __restrict__ Xcat) {
  long long idx4 = ((long long)blockIdx.x * 256 + threadIdx.x) * 4;
  int c = (int)(idx4 >> 19);
  int rem = (int)(idx4 & ((1 << 19) - 1));
  int n = rem >> 8, fcol = rem & 255;
  float4 acc = {0.f, 0.f, 0.f, 0.f};
#pragma unroll
  for (int kp = 0; kp < 4; ++kp) {
    float4 v = *(const float4*)(Tp + (long long)(c * 4 + kp) * NN * WOUT + rem);
    acc.x += v.x; acc.y += v.y; acc.z += v.z; acc.w += v.w;
  }
  float4 xw = *(const float4*)(XW + rem);
  float4 b  = *(const float4*)(gcn_b + fcol);
  float dn = disv[c * NN + n], d2 = dn * dn;
  bf16x4 o;
  o[0] = (bf16_t)fmaxf(acc.x + d2 * xw.x + b.x, 0.f);
  o[1] = (bf16_t)fmaxf(acc.y + d2 * xw.y + b.y, 0.f);
  o[2] = (bf16_t)fmaxf(acc.z + d2 * xw.z + b.z, 0.f);
  o[3] = (bf16_t)fmaxf(acc.w + d2 * xw.w + b.w, 0.f);
  *(bf16x4*)&Xcat[(long long)n * (CC * WOUT) + c * WOUT + fcol] = o;
}

// ---------------- launch ----------------

extern "C" void kernel_launch(void* const* d_in, const int* in_sizes, int n_in,
                              void* d_out, int out_size, void* d_ws, size_t ws_size,
                              hipStream_t stream) {
  const float* A    = (const float*)d_in[0];
  const float* X    = (const float*)d_in[1];
  const float* w0a  = (const float*)d_in[2];
  const float* w0b  = (const float*)d_in[3];
  const float* w1   = (const float*)d_in[4];
  const float* gcnw = (const float*)d_in[5];
  const float* gcnb = (const float*)d_in[6];
  const float* l1w  = (const float*)d_in[7];
  const float* l1b  = (const float*)d_in[8];
  const float* l2w  = (const float*)d_in[9];
  const float* l2b  = (const float*)d_in[10];
  float* out = (float*)d_out;

  char* p = (char*)d_ws;
  auto carve = [&](size_t bytes) -> char* {
    char* r = p; p += (bytes + 255) & ~(size_t)255; return r;
  };
  float*  svec  = (float*)carve((size_t)CC * NN * 4);
  float*  dinv1 = (float*)carve((size_t)CC * NN * 4);
  float*  m1    = (float*)carve((size_t)CC * NN * 4);
  float*  cscal = (float*)carve((size_t)CC * NN * 4);
  float*  disv  = (float*)carve((size_t)CC * NN * 4);
  float*  part  = (float*)carve((size_t)CC * 32 * NN * 4);
  bf16_t* S1    = (bf16_t*)carve((size_t)CC * N2 * 2); // Ha
  bf16_t* S2    = (bf16_t*)carve((size_t)CC * N2 * 2); // HbT -> A3
  bf16_t* S3    = (bf16_t*)carve((size_t)CC * N2 * 2); // Hb2T -> Tb (f32 split-K partials)
  bf16_t* Hn    = (bf16_t*)carve((size_t)CC * N2 * 2);
  bf16_t* Xb    = (bf16_t*)carve((size_t)NN * WIN * 2);
  bf16_t* gwT   = (bf16_t*)carve((size_t)WOUT * WIN * 2);
  bf16_t* l1wb  = (bf16_t*)carve((size_t)WOUT * CC * WOUT * 2);
  bf16_t* l2wb  = (bf16_t*)carve((size_t)WOUT * WOUT * 2);
  float*  XW    = (float*)carve((size_t)NN * WOUT * 4);
  bf16_t* XWT   = (bf16_t*)carve((size_t)WOUT * NN * 2);
  bf16_t* Xcat  = (bf16_t*)carve((size_t)NN * CC * WOUT * 2);
  bf16_t* hb    = (bf16_t*)carve((size_t)NN * WOUT * 2);

  bf16_t* Ha  = S1;
  bf16_t* HbT = S2; bf16_t* A3 = S2;
  bf16_t* Hb2T = S3; float* Tb = (float*)S3;

  // prep
  k_prep<<<608, 256, 0, stream>>>(X, l1w, l2w, Xb, l1wb, l2wb);
  k_transpose_cast<<<dim3(WIN / 64, WOUT / 64), 256, 0, stream>>>(gcnw, gwT, WIN, WOUT);
  k_combine<<<dim3(32, 32), 256, 0, stream>>>(A, w0a, w0b, w1, Ha, HbT, Hb2T, part);
  k_s_finish<<<16, 256, 0, stream>>>(part, svec);

  // layer 0
  k_deg<false><<<dim3(512, 2), 256, 0, stream>>>(svec, Ha, HbT, dinv1, m1);
  k_gemm<EP_NORM1><<<dim3(16, 32, 2), 256, 0, stream>>>(
      Ha, HbT, Hn, dinv1, nullptr, nullptr, NN, NN, NN, NN, N2, N2, N2);

  // layer 1 (fused normalize + dis + transpose -> A3)
  k_deg<true><<<dim3(512, 2), 256, 0, stream>>>(m1, Hn, Hb2T, cscal, disv);
  k_gemm<EP_NORM2T><<<dim3(16, 32, 2), 256, 0, stream>>>(
      Hn, Hb2T, A3, cscal, disv, nullptr, NN, NN, NN, NN, N2, N2, N2);

  // GCN: XW (+fused XWT transpose); T = A3 @ XWT^T, split-K x4, both channels in one launch
  k_gemm<EP_XWT><<<dim3(16, 4, 1), 256, 0, stream>>>(
      Xb, gwT, XW, nullptr, nullptr, XWT, WOUT, WIN, WIN, WIN, 0, 0, 0);
  k_gemm<EP_GCN><<<dim3(16, 4, 8), 256, 0, stream>>>(
      A3, XWT, Tb, nullptr, nullptr, nullptr, WOUT, 512, NN, NN, N2, 0, (long long)NN * WOUT);
  k_gcn_epi<<<1024, 256, 0, stream>>>(Tb, XW, gcnb, disv, Xcat);

  // MLP with fused bias(+relu)
  k_gemm<EP_BRELU><<<dim3(16, 4, 1), 256, 0, stream>>>(
      Xcat, l1wb, hb, l1b, nullptr, nullptr, WOUT, CC * WOUT, CC * WOUT, CC * WOUT, 0, 0, 0);
  k_gemm<EP_BF32><<<dim3(16, 4, 1), 256, 0, stream>>>(
      hb, l2wb, out, l2b, nullptr, nullptr, WOUT, WOUT, WOUT, WOUT, 0, 0, 0);
}

// Round 4
// 198.211 us; speedup vs baseline: 1.4848x; 1.1343x over previous
//
#include <hip/hip_runtime.h>
#include <cstdint>
#include <cstddef>

#define NN   2048
#define N2   (2048LL*2048LL)
#define CC   2
#define EE   5
#define WIN  512
#define WOUT 256

typedef __bf16 bf16_t;
typedef __attribute__((ext_vector_type(8))) __bf16 bf16x8;
typedef __attribute__((ext_vector_type(4))) __bf16 bf16x4;
typedef __attribute__((ext_vector_type(4))) float  f32x4;

// ---------------- prep: bf16 casts + gcn_w transpose-cast, one launch ----------------
__global__ void k_prep(const float* __restrict__ X, const float* __restrict__ l1w,
                       const float* __restrict__ l2w, const float* __restrict__ gcnw,
                       bf16_t* __restrict__ Xb, bf16_t* __restrict__ l1wb,
                       bf16_t* __restrict__ l2wb, bf16_t* __restrict__ gwT) {
  __shared__ bf16_t tile[64][65];
  int bid = blockIdx.x;
  if (bid < 608) {
    int i = bid * 256 + threadIdx.x;
    const float* src; bf16_t* dst; int off;
    if (i < 131072)      { src = X;   dst = Xb;   off = i; }
    else if (i < 147456) { src = l1w; dst = l1wb; off = i - 131072; }
    else if (i < 155648) { src = l2w; dst = l2wb; off = i - 147456; }
    else return;
    float4 a = ((const float4*)src)[off * 2];
    float4 b = ((const float4*)src)[off * 2 + 1];
    bf16x8 o;
    o[0] = (bf16_t)a.x; o[1] = (bf16_t)a.y; o[2] = (bf16_t)a.z; o[3] = (bf16_t)a.w;
    o[4] = (bf16_t)b.x; o[5] = (bf16_t)b.y; o[6] = (bf16_t)b.z; o[7] = (bf16_t)b.w;
    ((bf16x8*)dst)[off] = o;
  } else {
    // transpose-cast gcn_w (WIN x WOUT) -> gwT (WOUT x WIN)
    int b2 = bid - 608;              // 0..31
    int m0 = (b2 & 7) * 64, n0 = (b2 >> 3) * 64;
    int t = threadIdx.x, tr = t >> 4, tc = (t & 15) << 2;
#pragma unroll
    for (int v = 0; v < 4; ++v) {
      int r = tr + v * 16;
      float4 d = *(const float4*)&gcnw[(long long)(m0 + r) * WOUT + n0 + tc];
      tile[r][tc + 0] = (bf16_t)d.x; tile[r][tc + 1] = (bf16_t)d.y;
      tile[r][tc + 2] = (bf16_t)d.z; tile[r][tc + 3] = (bf16_t)d.w;
    }
    __syncthreads();
#pragma unroll
    for (int v = 0; v < 4; ++v) {
      int r = tr + v * 16;
      bf16x4 o;
      o[0] = tile[tc + 0][r]; o[1] = tile[tc + 1][r];
      o[2] = tile[tc + 2][r]; o[3] = tile[tc + 3][r];
      *(bf16x4*)&gwT[(long long)(n0 + r) * WIN + m0 + tc] = o;
    }
  }
}

// ---------------- combine: single A pass; Hb via LDS, Hb2 carried in registers ----------------

__global__ void k_combine(const float* __restrict__ A,
                          const float* __restrict__ w0a, const float* __restrict__ w0b,
                          const float* __restrict__ w1,
                          bf16_t* __restrict__ Ha, bf16_t* __restrict__ HbT,
                          bf16_t* __restrict__ Hb2T, float* __restrict__ part) {
  __shared__ bf16_t tl[2][64][65];  // 16.6 KB
  __shared__ float cs[2][16][64];   // 8 KB
  float f[3][2][5];
  {
    const float* wp[3] = {w0a, w0b, w1};
#pragma unroll
    for (int w = 0; w < 3; ++w)
#pragma unroll
      for (int c = 0; c < 2; ++c) {
        float x[5], m = -1e30f, s = 0.f;
#pragma unroll
        for (int e = 0; e < 5; ++e) { x[e] = wp[w][c * 5 + e]; m = fmaxf(m, x[e]); }
#pragma unroll
        for (int e = 0; e < 5; ++e) { x[e] = expf(x[e] - m); s += x[e]; }
#pragma unroll
        for (int e = 0; e < 5; ++e) f[w][c][e] = x[e] / s;
      }
  }
  int i0 = blockIdx.x * 64, j0 = blockIdx.y * 64;
  int t = threadIdx.x, tr = t >> 4, tc = (t & 15) << 2;
  float cs0[4] = {0, 0, 0, 0}, cs1[4] = {0, 0, 0, 0};
  bf16x4 hb2a[4], hb2b[4];  // Hb2 ch0/ch1, kept in registers across phases

  // phase A: one read of A tile; Ha -> global, Hb -> LDS, Hb2 -> regs
#pragma unroll
  for (int v = 0; v < 4; ++v) {
    int lr = tr + v * 16;
    long long gi = i0 + lr;
    const float* base = A + gi * (long long)NN + j0 + tc;
    float av[5][4];
#pragma unroll
    for (int e = 0; e < 5; ++e) {
      float4 q = *(const float4*)(base + (long long)e * N2);
      av[e][0] = q.x; av[e][1] = q.y; av[e][2] = q.z; av[e][3] = q.w;
    }
    bf16x4 ha0, ha1;
#pragma unroll
    for (int x = 0; x < 4; ++x) {
      float s0 = 0.f, s1 = 0.f, s2 = 0.f, s3 = 0.f, s4 = 0.f, s5 = 0.f;
#pragma unroll
      for (int e = 0; e < 5; ++e) {
        float u = av[e][x];
        s0 += f[0][0][e] * u; s1 += f[0][1][e] * u;
        s2 += f[1][0][e] * u; s3 += f[1][1][e] * u;
        s4 += f[2][0][e] * u; s5 += f[2][1][e] * u;
      }
      ha0[x] = (bf16_t)s0; cs0[x] += (float)ha0[x];
      ha1[x] = (bf16_t)s1; cs1[x] += (float)ha1[x];
      tl[0][lr][tc + x] = (bf16_t)s2; tl[1][lr][tc + x] = (bf16_t)s3;
      hb2a[v][x] = (bf16_t)s4; hb2b[v][x] = (bf16_t)s5;
    }
    *(bf16x4*)&Ha[0 * N2 + gi * NN + j0 + tc] = ha0;
    *(bf16x4*)&Ha[1 * N2 + gi * NN + j0 + tc] = ha1;
  }
#pragma unroll
  for (int x = 0; x < 4; ++x) { cs[0][tr][tc + x] = cs0[x]; cs[1][tr][tc + x] = cs1[x]; }
  __syncthreads();

  // phase B: transposed store of HbT + colsum partial reduce
#pragma unroll
  for (int v = 0; v < 4; ++v) {
    int lr = tr + v * 16;
#pragma unroll
    for (int ch = 0; ch < 2; ++ch) {
      bf16x4 o;
      o[0] = tl[ch][tc + 0][lr]; o[1] = tl[ch][tc + 1][lr];
      o[2] = tl[ch][tc + 2][lr]; o[3] = tl[ch][tc + 3][lr];
      *(bf16x4*)&HbT[(long long)ch * N2 + (long long)(j0 + lr) * NN + i0 + tc] = o;
    }
  }
  if (t < 128) {
    int ch = t >> 6, col = t & 63;
    float s = 0.f;
#pragma unroll
    for (int r = 0; r < 16; ++r) s += cs[ch][r][col];
    part[((long long)ch * 32 + blockIdx.x) * NN + j0 + col] = s;
  }
  __syncthreads();

  // phase C: dump Hb2 registers into the same LDS tile
#pragma unroll
  for (int v = 0; v < 4; ++v) {
    int lr = tr + v * 16;
#pragma unroll
    for (int x = 0; x < 4; ++x) {
      tl[0][lr][tc + x] = hb2a[v][x];
      tl[1][lr][tc + x] = hb2b[v][x];
    }
  }
  __syncthreads();

  // phase D: transposed store of Hb2T
#pragma unroll
  for (int v = 0; v < 4; ++v) {
    int lr = tr + v * 16;
#pragma unroll
    for (int ch = 0; ch < 2; ++ch) {
      bf16x4 o;
      o[0] = tl[ch][tc + 0][lr]; o[1] = tl[ch][tc + 1][lr];
      o[2] = tl[ch][tc + 2][lr]; o[3] = tl[ch][tc + 3][lr];
      *(bf16x4*)&Hb2T[(long long)ch * N2 + (long long)(j0 + lr) * NN + i0 + tc] = o;
    }
  }
}

__global__ void k_s_finish(const float* __restrict__ part, float* __restrict__ s) {
  int idx = blockIdx.x * 256 + threadIdx.x; // 4096 = c*2048+k
  int c = idx >> 11, k = idx & 2047;
  float acc = 0.f;
#pragma unroll
  for (int ib = 0; ib < 32; ++ib) acc += part[((long long)c * 32 + ib) * NN + k];
  s[idx] = acc;
}

// deg[c][j] = sum_k (svec[c][k] - Arows[c][j][k]) * BT[c][j][k]
template<bool EMIT_DIS>
__global__ void k_deg(const float* __restrict__ svec, const bf16_t* __restrict__ Arows,
                      const bf16_t* __restrict__ BT,
                      float* __restrict__ out1, float* __restrict__ out2) {
  int c = blockIdx.y;
  int j = blockIdx.x * 4 + (threadIdx.x >> 6);
  int lane = threadIdx.x & 63;
  const bf16_t* a = Arows + (long long)c * N2 + (long long)j * NN;
  const bf16_t* b = BT + (long long)c * N2 + (long long)j * NN;
  const float* s = svec + c * NN;
  float acc = 0.f;
#pragma unroll
  for (int it = 0; it < 4; ++it) {
    int k0 = (lane + it * 64) * 8;
    bf16x8 av = *(const bf16x8*)(a + k0);
    bf16x8 bv = *(const bf16x8*)(b + k0);
    float4 s0 = *(const float4*)(s + k0);
    float4 s1 = *(const float4*)(s + k0 + 4);
    acc += (s0.x - (float)av[0]) * (float)bv[0];
    acc += (s0.y - (float)av[1]) * (float)bv[1];
    acc += (s0.z - (float)av[2]) * (float)bv[2];
    acc += (s0.w - (float)av[3]) * (float)bv[3];
    acc += (s1.x - (float)av[4]) * (float)bv[4];
    acc += (s1.y - (float)av[5]) * (float)bv[5];
    acc += (s1.z - (float)av[6]) * (float)bv[6];
    acc += (s1.w - (float)av[7]) * (float)bv[7];
  }
#pragma unroll
  for (int o = 32; o > 0; o >>= 1) acc += __shfl_xor(acc, o, 64);
  if (lane == 0) {
    float deg = acc;
    bool nz = (deg != 0.f);
    if (!EMIT_DIS) {
      out1[c * NN + j] = nz ? 1.f / deg : 0.f;
      out2[c * NN + j] = nz ? 1.f : 0.f;
    } else {
      float dis = nz ? 0.70710678118654752f : 1.f;
      out1[c * NN + j] = nz ? dis / deg : 0.f;
      out2[c * NN + j] = dis;
    }
  }
}

// ---------------- bf16 GEMM, 128x64 tile, 4 waves (2x2), dbuf LDS, fused epilogues ----------------
// C[M,N] = A[M,K] @ B[N,K]^T. Grid (M/128, N/64, z).

enum { EP_F32 = 0, EP_NORM1 = 1, EP_NORM2T = 2, EP_BRELU = 3, EP_BF32 = 4, EP_XWT = 5, EP_GCN = 6 };

template<int EP>
__global__ __launch_bounds__(256)
void k_gemm(const bf16_t* __restrict__ A, const bf16_t* __restrict__ B,
            void* __restrict__ Cv,
            const float* __restrict__ aux1, const float* __restrict__ aux2,
            bf16_t* __restrict__ aux3,
            int N, int K, int lda, int ldb,
            long long zA, long long zB, long long zC) {
  __shared__ __align__(16) char smem[24576];
  bf16_t* As = (bf16_t*)smem;
  bf16_t* Bs = (bf16_t*)(smem + 16384);
  bf16_t* tile = (bf16_t*)smem;

  int cz = blockIdx.z;
  const bf16_t *Ab, *Bb;
  if constexpr (EP == EP_GCN) {
    int c = cz >> 2, kc = cz & 3;
    Ab = A + (long long)c * zA + kc * 512;
    Bb = B + kc * 512;
  } else {
    Ab = A + cz * zA;
    Bb = B + cz * zB;
  }
  Ab += (long long)blockIdx.x * 128 * lda;
  Bb += (long long)blockIdx.y * 64 * ldb;

  int t = threadIdx.x, wid = t >> 6, lane = t & 63;
  int wr = wid >> 1, wc = wid & 1;
  f32x4 acc[4][2] = {};
  int frow = lane & 15, fk = (lane >> 4) << 3;
  int srow = t >> 2, scol = (t & 3) << 3;
  int nt = K >> 5;

  auto STAGE = [&](int TT, int BUF) {
    long long kko = (long long)TT * 32 + scol;
    const bf16_t* ga0 = Ab + (long long)srow * lda + kko;
    const bf16_t* ga1 = Ab + (long long)(64 + srow) * lda + kko;
    const bf16_t* gb0 = Bb + (long long)srow * ldb + kko;
    char* la = (char*)(As + BUF * 4096) + wid * 64 * 16;
    char* lb = (char*)(Bs + BUF * 2048) + wid * 64 * 16;
    __builtin_amdgcn_global_load_lds((__attribute__((address_space(1))) void*)ga0,
        (__attribute__((address_space(3))) void*)la, 16, 0, 0);
    __builtin_amdgcn_global_load_lds((__attribute__((address_space(1))) void*)ga1,
        (__attribute__((address_space(3))) void*)(la + 256 * 16), 16, 0, 0);
    __builtin_amdgcn_global_load_lds((__attribute__((address_space(1))) void*)gb0,
        (__attribute__((address_space(3))) void*)lb, 16, 0, 0);
  };
  auto COMPUTE = [&](int BUF) {
    bf16x8 af[4], bfr[2];
#pragma unroll
    for (int m = 0; m < 4; ++m)
      af[m] = *(const bf16x8*)&As[BUF * 4096 + (wr * 64 + m * 16 + frow) * 32 + fk];
#pragma unroll
    for (int n = 0; n < 2; ++n)
      bfr[n] = *(const bf16x8*)&Bs[BUF * 2048 + (wc * 32 + n * 16 + frow) * 32 + fk];
#pragma unroll
    for (int m = 0; m < 4; ++m)
#pragma unroll
      for (int n = 0; n < 2; ++n)
        acc[m][n] = __builtin_amdgcn_mfma_f32_16x16x32_bf16(af[m], bfr[n], acc[m][n], 0, 0, 0);
  };

  STAGE(0, 0);
  __syncthreads();
  for (int tt = 0; tt < nt; tt += 2) {
    if (tt + 1 < nt) STAGE(tt + 1, 1);
    COMPUTE(0);
    __syncthreads();
    if (tt + 2 < nt) STAGE(tt + 2, 0);
    COMPUTE(1);
    __syncthreads();
  }

  // C/D frag: col = lane&15, row = (lane>>4)*4 + reg
  int rl0 = wr * 64 + ((lane >> 4) << 2);
  int cl0 = wc * 32 + (lane & 15);
  int r0 = blockIdx.x * 128 + rl0;
  int c0 = blockIdx.y * 64 + cl0;

  if constexpr (EP == EP_F32 || EP == EP_GCN) {
    float* Cb = (float*)Cv + cz * zC;
#pragma unroll
    for (int m = 0; m < 4; ++m)
#pragma unroll
      for (int n = 0; n < 2; ++n)
#pragma unroll
        for (int j = 0; j < 4; ++j)
          Cb[(long long)(r0 + m * 16 + j) * N + c0 + n * 16] = acc[m][n][j];
  } else if constexpr (EP == EP_NORM1) {
    bf16_t* Cb = (bf16_t*)Cv + cz * zC;
    float dj[2];
#pragma unroll
    for (int n = 0; n < 2; ++n) dj[n] = aux1[cz * NN + c0 + n * 16];
#pragma unroll
    for (int m = 0; m < 4; ++m)
#pragma unroll
      for (int n = 0; n < 2; ++n)
#pragma unroll
        for (int j = 0; j < 4; ++j) {
          int r = r0 + m * 16 + j, col = c0 + n * 16;
          float v = (r == col) ? 0.f : acc[m][n][j] * dj[n];
          Cb[(long long)r * N + col] = (bf16_t)v;
        }
  } else if constexpr (EP == EP_NORM2T) {
    bf16_t* Cb = (bf16_t*)Cv + cz * zC;
    float dj[2];
#pragma unroll
    for (int n = 0; n < 2; ++n) dj[n] = aux1[cz * NN + c0 + n * 16];
#pragma unroll
    for (int m = 0; m < 4; ++m) {
      float dr[4];
#pragma unroll
      for (int j = 0; j < 4; ++j) dr[j] = aux2[cz * NN + r0 + m * 16 + j];
#pragma unroll
      for (int n = 0; n < 2; ++n)
#pragma unroll
        for (int j = 0; j < 4; ++j) {
          int r = r0 + m * 16 + j, col = c0 + n * 16;
          float v = (r == col) ? 0.f : acc[m][n][j] * dj[n] * dr[j];
          tile[(rl0 + m * 16 + j) * 65 + cl0 + n * 16] = (bf16_t)v;
        }
    }
    __syncthreads();
    int nl = t >> 5, rl = (t & 31) * 4;
#pragma unroll
    for (int vv = 0; vv < 8; ++vv) {
      int n_l = nl + vv * 8;
      bf16x4 o;
      o[0] = tile[(rl + 0) * 65 + n_l]; o[1] = tile[(rl + 1) * 65 + n_l];
      o[2] = tile[(rl + 2) * 65 + n_l]; o[3] = tile[(rl + 3) * 65 + n_l];
      *(bf16x4*)&Cb[(long long)(blockIdx.y * 64 + n_l) * NN + blockIdx.x * 128 + rl] = o;
    }
  } else if constexpr (EP == EP_XWT) {
    float* Cb = (float*)Cv;
#pragma unroll
    for (int m = 0; m < 4; ++m)
#pragma unroll
      for (int n = 0; n < 2; ++n)
#pragma unroll
        for (int j = 0; j < 4; ++j) {
          float v = acc[m][n][j];
          Cb[(long long)(r0 + m * 16 + j) * N + c0 + n * 16] = v;
          tile[(rl0 + m * 16 + j) * 65 + cl0 + n * 16] = (bf16_t)v;
        }
    __syncthreads();
    int nl = t >> 5, rl = (t & 31) * 4;
#pragma unroll
    for (int vv = 0; vv < 8; ++vv) {
      int n_l = nl + vv * 8;
      bf16x4 o;
      o[0] = tile[(rl + 0) * 65 + n_l]; o[1] = tile[(rl + 1) * 65 + n_l];
      o[2] = tile[(rl + 2) * 65 + n_l]; o[3] = tile[(rl + 3) * 65 + n_l];
      *(bf16x4*)&aux3[(long long)(blockIdx.y * 64 + n_l) * NN + blockIdx.x * 128 + rl] = o;
    }
  } else if constexpr (EP == EP_BRELU) {
    bf16_t* Cb = (bf16_t*)Cv;
    float bj[2];
#pragma unroll
    for (int n = 0; n < 2; ++n) bj[n] = aux1[c0 + n * 16];
#pragma unroll
    for (int m = 0; m < 4; ++m)
#pragma unroll
      for (int n = 0; n < 2; ++n)
#pragma unroll
        for (int j = 0; j < 4; ++j)
          Cb[(long long)(r0 + m * 16 + j) * N + c0 + n * 16] =
              (bf16_t)fmaxf(acc[m][n][j] + bj[n], 0.f);
  } else { // EP_BF32
    float* Cb = (float*)Cv;
    float bj[2];
#pragma unroll
    for (int n = 0; n < 2; ++n) bj[n] = aux1[c0 + n * 16];
#pragma unroll
    for (int m = 0; m < 4; ++m)
#pragma unroll
      for (int n = 0; n < 2; ++n)
#pragma unroll
        for (int j = 0; j < 4; ++j)
          Cb[(long long)(r0 + m * 16 + j) * N + c0 + n * 16] = acc[m][n][j] + bj[n];
  }
}

// ---------------- GCN epilogue: sum split-K partials + diagonal + bias + relu ----------------

__global__ void k_gcn_epi(const float* __restrict__ Tp, const float* __restrict__ XW,
                          const float* __restrict__ gcn_b, const float* __restrict__ disv,
                          bf16_t* __restrict__ Xcat) {
  long long idx4 = ((long long)blockIdx.x * 256 + threadIdx.x) * 4;
  int c = (int)(idx4 >> 19);
  int rem = (int)(idx4 & ((1 << 19) - 1));
  int n = rem >> 8, fcol = rem & 255;
  float4 acc = {0.f, 0.f, 0.f, 0.f};
#pragma unroll
  for (int kp = 0; kp < 4; ++kp) {
    float4 v = *(const float4*)(Tp + (long long)(c * 4 + kp) * NN * WOUT + rem);
    acc.x += v.x; acc.y += v.y; acc.z += v.z; acc.w += v.w;
  }
  float4 xw = *(const float4*)(XW + rem);
  float4 b  = *(const float4*)(gcn_b + fcol);
  float dn = disv[c * NN + n], d2 = dn * dn;
  bf16x4 o;
  o[0] = (bf16_t)fmaxf(acc.x + d2 * xw.x + b.x, 0.f);
  o[1] = (bf16_t)fmaxf(acc.y + d2 * xw.y + b.y, 0.f);
  o[2] = (bf16_t)fmaxf(acc.z + d2 * xw.z + b.z, 0.f);
  o[3] = (bf16_t)fmaxf(acc.w + d2 * xw.w + b.w, 0.f);
  *(bf16x4*)&Xcat[(long long)n * (CC * WOUT) + c * WOUT + fcol] = o;
}

// ---------------- launch ----------------

extern "C" void kernel_launch(void* const* d_in, const int* in_sizes, int n_in,
                              void* d_out, int out_size, void* d_ws, size_t ws_size,
                              hipStream_t stream) {
  const float* A    = (const float*)d_in[0];
  const float* X    = (const float*)d_in[1];
  const float* w0a  = (const float*)d_in[2];
  const float* w0b  = (const float*)d_in[3];
  const float* w1   = (const float*)d_in[4];
  const float* gcnw = (const float*)d_in[5];
  const float* gcnb = (const float*)d_in[6];
  const float* l1w  = (const float*)d_in[7];
  const float* l1b  = (const float*)d_in[8];
  const float* l2w  = (const float*)d_in[9];
  const float* l2b  = (const float*)d_in[10];
  float* out = (float*)d_out;

  char* p = (char*)d_ws;
  auto carve = [&](size_t bytes) -> char* {
    char* r = p; p += (bytes + 255) & ~(size_t)255; return r;
  };
  float*  svec  = (float*)carve((size_t)CC * NN * 4);
  float*  dinv1 = (float*)carve((size_t)CC * NN * 4);
  float*  m1    = (float*)carve((size_t)CC * NN * 4);
  float*  cscal = (float*)carve((size_t)CC * NN * 4);
  float*  disv  = (float*)carve((size_t)CC * NN * 4);
  float*  part  = (float*)carve((size_t)CC * 32 * NN * 4);
  bf16_t* S1    = (bf16_t*)carve((size_t)CC * N2 * 2); // Ha
  bf16_t* S2    = (bf16_t*)carve((size_t)CC * N2 * 2); // HbT -> A3
  bf16_t* S3    = (bf16_t*)carve((size_t)CC * N2 * 2); // Hb2T -> Tb (f32 split-K partials)
  bf16_t* Hn    = (bf16_t*)carve((size_t)CC * N2 * 2);
  bf16_t* Xb    = (bf16_t*)carve((size_t)NN * WIN * 2);
  bf16_t* gwT   = (bf16_t*)carve((size_t)WOUT * WIN * 2);
  bf16_t* l1wb  = (bf16_t*)carve((size_t)WOUT * CC * WOUT * 2);
  bf16_t* l2wb  = (bf16_t*)carve((size_t)WOUT * WOUT * 2);
  float*  XW    = (float*)carve((size_t)NN * WOUT * 4);
  bf16_t* XWT   = (bf16_t*)carve((size_t)WOUT * NN * 2);
  bf16_t* Xcat  = (bf16_t*)carve((size_t)NN * CC * WOUT * 2);
  bf16_t* hb    = (bf16_t*)carve((size_t)NN * WOUT * 2);

  bf16_t* Ha  = S1;
  bf16_t* HbT = S2; bf16_t* A3 = S2;
  bf16_t* Hb2T = S3; float* Tb = (float*)S3;

  // prep
  k_prep<<<640, 256, 0, stream>>>(X, l1w, l2w, gcnw, Xb, l1wb, l2wb, gwT);
  k_combine<<<dim3(32, 32), 256, 0, stream>>>(A, w0a, w0b, w1, Ha, HbT, Hb2T, part);
  k_s_finish<<<16, 256, 0, stream>>>(part, svec);

  // layer 0
  k_deg<false><<<dim3(512, 2), 256, 0, stream>>>(svec, Ha, HbT, dinv1, m1);
  k_gemm<EP_NORM1><<<dim3(16, 32, 2), 256, 0, stream>>>(
      Ha, HbT, Hn, dinv1, nullptr, nullptr, NN, NN, NN, NN, N2, N2, N2);

  // layer 1 (fused normalize + dis + transpose -> A3)
  k_deg<true><<<dim3(512, 2), 256, 0, stream>>>(m1, Hn, Hb2T, cscal, disv);
  k_gemm<EP_NORM2T><<<dim3(16, 32, 2), 256, 0, stream>>>(
      Hn, Hb2T, A3, cscal, disv, nullptr, NN, NN, NN, NN, N2, N2, N2);

  // GCN: XW (+fused XWT transpose); T = A3 @ XWT^T, split-K x4, both channels in one launch
  k_gemm<EP_XWT><<<dim3(16, 4, 1), 256, 0, stream>>>(
      Xb, gwT, XW, nullptr, nullptr, XWT, WOUT, WIN, WIN, WIN, 0, 0, 0);
  k_gemm<EP_GCN><<<dim3(16, 4, 8), 256, 0, stream>>>(
      A3, XWT, Tb, nullptr, nullptr, nullptr, WOUT, 512, NN, NN, N2, 0, (long long)NN * WOUT);
  k_gcn_epi<<<1024, 256, 0, stream>>>(Tb, XW, gcnb, disv, Xcat);

  // MLP with fused bias(+relu)
  k_gemm<EP_BRELU><<<dim3(16, 4, 1), 256, 0, stream>>>(
      Xcat, l1wb, hb, l1b, nullptr, nullptr, WOUT, CC * WOUT, CC * WOUT, CC * WOUT, 0, 0, 0);
  k_gemm<EP_BF32><<<dim3(16, 4, 1), 256, 0, stream>>>(
      hb, l2wb, out, l2b, nullptr, nullptr, WOUT, WOUT, WOUT, WOUT, 0, 0, 0);
}

// Round 5
// 185.676 us; speedup vs baseline: 1.5850x; 1.0675x over previous
//
#include <hip/hip_runtime.h>
#include <cstdint>
#include <cstddef>

#define NN   2048
#define N2   (2048LL*2048LL)
#define CC   2
#define EE   5
#define WIN  512
#define WOUT 256

typedef __bf16 bf16_t;
typedef __attribute__((ext_vector_type(8))) __bf16 bf16x8;
typedef __attribute__((ext_vector_type(4))) __bf16 bf16x4;
typedef __attribute__((ext_vector_type(4))) float  f32x4;

// ---------------- prep: bf16 casts + gcn_w transpose-cast, one launch ----------------
__global__ void k_prep(const float* __restrict__ X, const float* __restrict__ l1w,
                       const float* __restrict__ l2w, const float* __restrict__ gcnw,
                       bf16_t* __restrict__ Xb, bf16_t* __restrict__ l1wb,
                       bf16_t* __restrict__ l2wb, bf16_t* __restrict__ gwT) {
  __shared__ bf16_t tile[64][65];
  int bid = blockIdx.x;
  if (bid < 608) {
    int i = bid * 256 + threadIdx.x;
    const float* src; bf16_t* dst; int off;
    if (i < 131072)      { src = X;   dst = Xb;   off = i; }
    else if (i < 147456) { src = l1w; dst = l1wb; off = i - 131072; }
    else if (i < 155648) { src = l2w; dst = l2wb; off = i - 147456; }
    else return;
    float4 a = ((const float4*)src)[off * 2];
    float4 b = ((const float4*)src)[off * 2 + 1];
    bf16x8 o;
    o[0] = (bf16_t)a.x; o[1] = (bf16_t)a.y; o[2] = (bf16_t)a.z; o[3] = (bf16_t)a.w;
    o[4] = (bf16_t)b.x; o[5] = (bf16_t)b.y; o[6] = (bf16_t)b.z; o[7] = (bf16_t)b.w;
    ((bf16x8*)dst)[off] = o;
  } else {
    int b2 = bid - 608;              // 0..31
    int m0 = (b2 & 7) * 64, n0 = (b2 >> 3) * 64;
    int t = threadIdx.x, tr = t >> 4, tc = (t & 15) << 2;
#pragma unroll
    for (int v = 0; v < 4; ++v) {
      int r = tr + v * 16;
      float4 d = *(const float4*)&gcnw[(long long)(m0 + r) * WOUT + n0 + tc];
      tile[r][tc + 0] = (bf16_t)d.x; tile[r][tc + 1] = (bf16_t)d.y;
      tile[r][tc + 2] = (bf16_t)d.z; tile[r][tc + 3] = (bf16_t)d.w;
    }
    __syncthreads();
#pragma unroll
    for (int v = 0; v < 4; ++v) {
      int r = tr + v * 16;
      bf16x4 o;
      o[0] = tile[tc + 0][r]; o[1] = tile[tc + 1][r];
      o[2] = tile[tc + 2][r]; o[3] = tile[tc + 3][r];
      *(bf16x4*)&gwT[(long long)(n0 + r) * WIN + m0 + tc] = o;
    }
  }
}

// ---------------- combine: single A pass; Hb via LDS, Hb2 carried in registers ----------------

__global__ void k_combine(const float* __restrict__ A,
                          const float* __restrict__ w0a, const float* __restrict__ w0b,
                          const float* __restrict__ w1,
                          bf16_t* __restrict__ Ha, bf16_t* __restrict__ HbT,
                          bf16_t* __restrict__ Hb2T, float* __restrict__ part) {
  __shared__ bf16_t tl[2][64][65];
  __shared__ float cs[2][16][64];
  float f[3][2][5];
  {
    const float* wp[3] = {w0a, w0b, w1};
#pragma unroll
    for (int w = 0; w < 3; ++w)
#pragma unroll
      for (int c = 0; c < 2; ++c) {
        float x[5], m = -1e30f, s = 0.f;
#pragma unroll
        for (int e = 0; e < 5; ++e) { x[e] = wp[w][c * 5 + e]; m = fmaxf(m, x[e]); }
#pragma unroll
        for (int e = 0; e < 5; ++e) { x[e] = expf(x[e] - m); s += x[e]; }
#pragma unroll
        for (int e = 0; e < 5; ++e) f[w][c][e] = x[e] / s;
      }
  }
  int i0 = blockIdx.x * 64, j0 = blockIdx.y * 64;
  int t = threadIdx.x, tr = t >> 4, tc = (t & 15) << 2;
  float cs0[4] = {0, 0, 0, 0}, cs1[4] = {0, 0, 0, 0};
  bf16x4 hb2a[4], hb2b[4];

#pragma unroll
  for (int v = 0; v < 4; ++v) {
    int lr = tr + v * 16;
    long long gi = i0 + lr;
    const float* base = A + gi * (long long)NN + j0 + tc;
    float av[5][4];
#pragma unroll
    for (int e = 0; e < 5; ++e) {
      float4 q = *(const float4*)(base + (long long)e * N2);
      av[e][0] = q.x; av[e][1] = q.y; av[e][2] = q.z; av[e][3] = q.w;
    }
    bf16x4 ha0, ha1;
#pragma unroll
    for (int x = 0; x < 4; ++x) {
      float s0 = 0.f, s1 = 0.f, s2 = 0.f, s3 = 0.f, s4 = 0.f, s5 = 0.f;
#pragma unroll
      for (int e = 0; e < 5; ++e) {
        float u = av[e][x];
        s0 += f[0][0][e] * u; s1 += f[0][1][e] * u;
        s2 += f[1][0][e] * u; s3 += f[1][1][e] * u;
        s4 += f[2][0][e] * u; s5 += f[2][1][e] * u;
      }
      ha0[x] = (bf16_t)s0; cs0[x] += (float)ha0[x];
      ha1[x] = (bf16_t)s1; cs1[x] += (float)ha1[x];
      tl[0][lr][tc + x] = (bf16_t)s2; tl[1][lr][tc + x] = (bf16_t)s3;
      hb2a[v][x] = (bf16_t)s4; hb2b[v][x] = (bf16_t)s5;
    }
    *(bf16x4*)&Ha[0 * N2 + gi * NN + j0 + tc] = ha0;
    *(bf16x4*)&Ha[1 * N2 + gi * NN + j0 + tc] = ha1;
  }
#pragma unroll
  for (int x = 0; x < 4; ++x) { cs[0][tr][tc + x] = cs0[x]; cs[1][tr][tc + x] = cs1[x]; }
  __syncthreads();

#pragma unroll
  for (int v = 0; v < 4; ++v) {
    int lr = tr + v * 16;
#pragma unroll
    for (int ch = 0; ch < 2; ++ch) {
      bf16x4 o;
      o[0] = tl[ch][tc + 0][lr]; o[1] = tl[ch][tc + 1][lr];
      o[2] = tl[ch][tc + 2][lr]; o[3] = tl[ch][tc + 3][lr];
      *(bf16x4*)&HbT[(long long)ch * N2 + (long long)(j0 + lr) * NN + i0 + tc] = o;
    }
  }
  if (t < 128) {
    int ch = t >> 6, col = t & 63;
    float s = 0.f;
#pragma unroll
    for (int r = 0; r < 16; ++r) s += cs[ch][r][col];
    part[((long long)ch * 32 + blockIdx.x) * NN + j0 + col] = s;
  }
  __syncthreads();

#pragma unroll
  for (int v = 0; v < 4; ++v) {
    int lr = tr + v * 16;
#pragma unroll
    for (int x = 0; x < 4; ++x) {
      tl[0][lr][tc + x] = hb2a[v][x];
      tl[1][lr][tc + x] = hb2b[v][x];
    }
  }
  __syncthreads();

#pragma unroll
  for (int v = 0; v < 4; ++v) {
    int lr = tr + v * 16;
#pragma unroll
    for (int ch = 0; ch < 2; ++ch) {
      bf16x4 o;
      o[0] = tl[ch][tc + 0][lr]; o[1] = tl[ch][tc + 1][lr];
      o[2] = tl[ch][tc + 2][lr]; o[3] = tl[ch][tc + 3][lr];
      *(bf16x4*)&Hb2T[(long long)ch * N2 + (long long)(j0 + lr) * NN + i0 + tc] = o;
    }
  }
}

__global__ void k_s_finish(const float* __restrict__ part, float* __restrict__ s) {
  int idx = blockIdx.x * 256 + threadIdx.x;
  int c = idx >> 11, k = idx & 2047;
  float acc = 0.f;
#pragma unroll
  for (int ib = 0; ib < 32; ++ib) acc += part[((long long)c * 32 + ib) * NN + k];
  s[idx] = acc;
}

// deg[c][j] = sum_k (svec[k] - A[j,k])*BT[j,k];  Mdiag[c][j] = sum_k A[j,k]*BT[j,k]
template<bool EMIT_DIS>
__global__ void k_deg(const float* __restrict__ svec, const bf16_t* __restrict__ Arows,
                      const bf16_t* __restrict__ BT,
                      float* __restrict__ out1, float* __restrict__ out2,
                      float* __restrict__ out3) {
  int c = blockIdx.y;
  int j = blockIdx.x * 4 + (threadIdx.x >> 6);
  int lane = threadIdx.x & 63;
  const bf16_t* a = Arows + (long long)c * N2 + (long long)j * NN;
  const bf16_t* b = BT + (long long)c * N2 + (long long)j * NN;
  const float* s = svec + c * NN;
  float acc_s = 0.f, acc_a = 0.f;
#pragma unroll
  for (int it = 0; it < 4; ++it) {
    int k0 = (lane + it * 64) * 8;
    bf16x8 av = *(const bf16x8*)(a + k0);
    bf16x8 bv = *(const bf16x8*)(b + k0);
    float4 s0 = *(const float4*)(s + k0);
    float4 s1 = *(const float4*)(s + k0 + 4);
    float sv[8] = {s0.x, s0.y, s0.z, s0.w, s1.x, s1.y, s1.z, s1.w};
#pragma unroll
    for (int x = 0; x < 8; ++x) {
      float bx = (float)bv[x];
      acc_s += sv[x] * bx;
      acc_a += (float)av[x] * bx;
    }
  }
#pragma unroll
  for (int o = 32; o > 0; o >>= 1) {
    acc_s += __shfl_xor(acc_s, o, 64);
    acc_a += __shfl_xor(acc_a, o, 64);
  }
  if (lane == 0) {
    float deg = acc_s - acc_a;
    bool nz = (deg != 0.f);
    if (!EMIT_DIS) {
      out1[c * NN + j] = nz ? 1.f / deg : 0.f;
      out2[c * NN + j] = nz ? 1.f : 0.f;
    } else {
      float dis = nz ? 0.70710678118654752f : 1.f;
      out1[c * NN + j] = nz ? dis / deg : 0.f;     // cscal = dis/deg2
      out2[c * NN + j] = dis;                      // disv
      out3[c * NN + j] = acc_a;                    // Mdiag = diag(Hn@Hb2)
    }
  }
}

// XWdT[c][f][i] = XWT[f][i] * disv[c][i]
__global__ void k_scale_xwd(const bf16_t* __restrict__ XWT, const float* __restrict__ disv,
                            bf16_t* __restrict__ XWdT) {
  int i = blockIdx.x * 256 + threadIdx.x;      // 2 * 256*2048/8 = 131072
  int c = i >> 16, rem = i & 65535;
  bf16x8 v = ((const bf16x8*)XWT)[rem];
  int col0 = (rem & 255) * 8;
  float4 d0 = *(const float4*)(disv + c * NN + col0);
  float4 d1 = *(const float4*)(disv + c * NN + col0 + 4);
  bf16x8 o;
  o[0] = (bf16_t)((float)v[0] * d0.x); o[1] = (bf16_t)((float)v[1] * d0.y);
  o[2] = (bf16_t)((float)v[2] * d0.z); o[3] = (bf16_t)((float)v[3] * d0.w);
  o[4] = (bf16_t)((float)v[4] * d1.x); o[5] = (bf16_t)((float)v[5] * d1.y);
  o[6] = (bf16_t)((float)v[6] * d1.z); o[7] = (bf16_t)((float)v[7] * d1.w);
  ((bf16x8*)XWdT)[i] = o;
}

// ---------------- bf16 GEMM, 128x64 tile, 4 waves (2x2), dbuf LDS, fused epilogues ----------------

enum { EP_F32 = 0, EP_NORM1T = 1, EP_BRELU = 3, EP_BF32 = 4, EP_XWT = 5, EP_BF16O = 7 };

template<int EP>
__global__ __launch_bounds__(256)
void k_gemm(const bf16_t* __restrict__ A, const bf16_t* __restrict__ B,
            void* __restrict__ Cv,
            const float* __restrict__ aux1, const float* __restrict__ aux2,
            bf16_t* __restrict__ aux3,
            int N, int K, int lda, int ldb,
            long long zA, long long zB, long long zC) {
  __shared__ __align__(16) char smem[24576];
  bf16_t* As = (bf16_t*)smem;
  bf16_t* Bs = (bf16_t*)(smem + 16384);
  bf16_t* tile = (bf16_t*)smem;

  int cz = blockIdx.z;
  const bf16_t* Ab = A + cz * zA + (long long)blockIdx.x * 128 * lda;
  const bf16_t* Bb = B + cz * zB + (long long)blockIdx.y * 64 * ldb;

  int t = threadIdx.x, wid = t >> 6, lane = t & 63;
  int wr = wid >> 1, wc = wid & 1;
  f32x4 acc[4][2] = {};
  int frow = lane & 15, fk = (lane >> 4) << 3;
  int srow = t >> 2, scol = (t & 3) << 3;
  int nt = K >> 5;

  auto STAGE = [&](int TT, int BUF) {
    long long kko = (long long)TT * 32 + scol;
    const bf16_t* ga0 = Ab + (long long)srow * lda + kko;
    const bf16_t* ga1 = Ab + (long long)(64 + srow) * lda + kko;
    const bf16_t* gb0 = Bb + (long long)srow * ldb + kko;
    char* la = (char*)(As + BUF * 4096) + wid * 64 * 16;
    char* lb = (char*)(Bs + BUF * 2048) + wid * 64 * 16;
    __builtin_amdgcn_global_load_lds((__attribute__((address_space(1))) void*)ga0,
        (__attribute__((address_space(3))) void*)la, 16, 0, 0);
    __builtin_amdgcn_global_load_lds((__attribute__((address_space(1))) void*)ga1,
        (__attribute__((address_space(3))) void*)(la + 256 * 16), 16, 0, 0);
    __builtin_amdgcn_global_load_lds((__attribute__((address_space(1))) void*)gb0,
        (__attribute__((address_space(3))) void*)lb, 16, 0, 0);
  };
  auto COMPUTE = [&](int BUF) {
    bf16x8 af[4], bfr[2];
#pragma unroll
    for (int m = 0; m < 4; ++m)
      af[m] = *(const bf16x8*)&As[BUF * 4096 + (wr * 64 + m * 16 + frow) * 32 + fk];
#pragma unroll
    for (int n = 0; n < 2; ++n)
      bfr[n] = *(const bf16x8*)&Bs[BUF * 2048 + (wc * 32 + n * 16 + frow) * 32 + fk];
#pragma unroll
    for (int m = 0; m < 4; ++m)
#pragma unroll
      for (int n = 0; n < 2; ++n)
        acc[m][n] = __builtin_amdgcn_mfma_f32_16x16x32_bf16(af[m], bfr[n], acc[m][n], 0, 0, 0);
  };

  STAGE(0, 0);
  __syncthreads();
  for (int tt = 0; tt < nt; tt += 2) {
    if (tt + 1 < nt) STAGE(tt + 1, 1);
    COMPUTE(0);
    __syncthreads();
    if (tt + 2 < nt) STAGE(tt + 2, 0);
    COMPUTE(1);
    __syncthreads();
  }

  int rl0 = wr * 64 + ((lane >> 4) << 2);
  int cl0 = wc * 32 + (lane & 15);
  int r0 = blockIdx.x * 128 + rl0;
  int c0 = blockIdx.y * 64 + cl0;

  if constexpr (EP == EP_F32) {
    float* Cb = (float*)Cv + cz * zC;
#pragma unroll
    for (int m = 0; m < 4; ++m)
#pragma unroll
      for (int n = 0; n < 2; ++n)
#pragma unroll
        for (int j = 0; j < 4; ++j)
          Cb[(long long)(r0 + m * 16 + j) * N + c0 + n * 16] = acc[m][n][j];
  } else if constexpr (EP == EP_BF16O) {
    bf16_t* Cb = (bf16_t*)Cv + cz * zC;
#pragma unroll
    for (int m = 0; m < 4; ++m)
#pragma unroll
      for (int n = 0; n < 2; ++n)
#pragma unroll
        for (int j = 0; j < 4; ++j)
          Cb[(long long)(r0 + m * 16 + j) * N + c0 + n * 16] = (bf16_t)acc[m][n][j];
  } else if constexpr (EP == EP_NORM1T) {
    // Hn = (r==col)?0: acc*dinv1[col]  (row-major) ; HnT = transpose(Hn) via LDS
    bf16_t* Cb = (bf16_t*)Cv + cz * zC;
    bf16_t* Ct = aux3 + cz * zC;
    float dj[2];
#pragma unroll
    for (int n = 0; n < 2; ++n) dj[n] = aux1[cz * NN + c0 + n * 16];
#pragma unroll
    for (int m = 0; m < 4; ++m)
#pragma unroll
      for (int n = 0; n < 2; ++n)
#pragma unroll
        for (int j = 0; j < 4; ++j) {
          int r = r0 + m * 16 + j, col = c0 + n * 16;
          float v = (r == col) ? 0.f : acc[m][n][j] * dj[n];
          Cb[(long long)r * NN + col] = (bf16_t)v;
          tile[(rl0 + m * 16 + j) * 65 + cl0 + n * 16] = (bf16_t)v;
        }
    __syncthreads();
    int nl = t >> 5, rl = (t & 31) * 4;
#pragma unroll
    for (int vv = 0; vv < 8; ++vv) {
      int n_l = nl + vv * 8;
      bf16x4 o;
      o[0] = tile[(rl + 0) * 65 + n_l]; o[1] = tile[(rl + 1) * 65 + n_l];
      o[2] = tile[(rl + 2) * 65 + n_l]; o[3] = tile[(rl + 3) * 65 + n_l];
      *(bf16x4*)&Ct[(long long)(blockIdx.y * 64 + n_l) * NN + blockIdx.x * 128 + rl] = o;
    }
  } else if constexpr (EP == EP_XWT) {
    float* Cb = (float*)Cv;
#pragma unroll
    for (int m = 0; m < 4; ++m)
#pragma unroll
      for (int n = 0; n < 2; ++n)
#pragma unroll
        for (int j = 0; j < 4; ++j) {
          float v = acc[m][n][j];
          Cb[(long long)(r0 + m * 16 + j) * N + c0 + n * 16] = v;
          tile[(rl0 + m * 16 + j) * 65 + cl0 + n * 16] = (bf16_t)v;
        }
    __syncthreads();
    int nl = t >> 5, rl = (t & 31) * 4;
#pragma unroll
    for (int vv = 0; vv < 8; ++vv) {
      int n_l = nl + vv * 8;
      bf16x4 o;
      o[0] = tile[(rl + 0) * 65 + n_l]; o[1] = tile[(rl + 1) * 65 + n_l];
      o[2] = tile[(rl + 2) * 65 + n_l]; o[3] = tile[(rl + 3) * 65 + n_l];
      *(bf16x4*)&aux3[(long long)(blockIdx.y * 64 + n_l) * NN + blockIdx.x * 128 + rl] = o;
    }
  } else if constexpr (EP == EP_BRELU) {
    bf16_t* Cb = (bf16_t*)Cv;
    float bj[2];
#pragma unroll
    for (int n = 0; n < 2; ++n) bj[n] = aux1[c0 + n * 16];
#pragma unroll
    for (int m = 0; m < 4; ++m)
#pragma unroll
      for (int n = 0; n < 2; ++n)
#pragma unroll
        for (int j = 0; j < 4; ++j)
          Cb[(long long)(r0 + m * 16 + j) * N + c0 + n * 16] =
              (bf16_t)fmaxf(acc[m][n][j] + bj[n], 0.f);
  } else { // EP_BF32
    float* Cb = (float*)Cv;
    float bj[2];
#pragma unroll
    for (int n = 0; n < 2; ++n) bj[n] = aux1[c0 + n * 16];
#pragma unroll
    for (int m = 0; m < 4; ++m)
#pragma unroll
      for (int n = 0; n < 2; ++n)
#pragma unroll
        for (int j = 0; j < 4; ++j)
          Cb[(long long)(r0 + m * 16 + j) * N + c0 + n * 16] = acc[m][n][j] + bj[n];
  }
}

// ---------------- GCN epilogue: out = relu(cscal*(Z - Mdiag*dis*XW) + dis^2*XW + b) ----------------

__global__ void k_gcn_epi2(const float* __restrict__ Z, const float* __restrict__ XW,
                           const float* __restrict__ gcn_b, const float* __restrict__ cscal,
                           const float* __restrict__ disv, const float* __restrict__ Mdiag,
                           bf16_t* __restrict__ Xcat) {
  long long idx4 = ((long long)blockIdx.x * 256 + threadIdx.x) * 4;
  int c = (int)(idx4 >> 19);
  int rem = (int)(idx4 & ((1 << 19) - 1));
  int n = rem >> 8, fcol = rem & 255;
  float4 z  = *(const float4*)(Z + (long long)c * NN * WOUT + rem);
  float4 xw = *(const float4*)(XW + rem);
  float4 b  = *(const float4*)(gcn_b + fcol);
  float cs = cscal[c * NN + n], dn = disv[c * NN + n], md = Mdiag[c * NN + n];
  float d2 = dn * dn, mdd = md * dn;
  bf16x4 o;
  o[0] = (bf16_t)fmaxf(cs * (z.x - mdd * xw.x) + d2 * xw.x + b.x, 0.f);
  o[1] = (bf16_t)fmaxf(cs * (z.y - mdd * xw.y) + d2 * xw.y + b.y, 0.f);
  o[2] = (bf16_t)fmaxf(cs * (z.z - mdd * xw.z) + d2 * xw.z + b.z, 0.f);
  o[3] = (bf16_t)fmaxf(cs * (z.w - mdd * xw.w) + d2 * xw.w + b.w, 0.f);
  *(bf16x4*)&Xcat[(long long)n * (CC * WOUT) + c * WOUT + fcol] = o;
}

// ---------------- launch ----------------

extern "C" void kernel_launch(void* const* d_in, const int* in_sizes, int n_in,
                              void* d_out, int out_size, void* d_ws, size_t ws_size,
                              hipStream_t stream) {
  const float* A    = (const float*)d_in[0];
  const float* X    = (const float*)d_in[1];
  const float* w0a  = (const float*)d_in[2];
  const float* w0b  = (const float*)d_in[3];
  const float* w1   = (const float*)d_in[4];
  const float* gcnw = (const float*)d_in[5];
  const float* gcnb = (const float*)d_in[6];
  const float* l1w  = (const float*)d_in[7];
  const float* l1b  = (const float*)d_in[8];
  const float* l2w  = (const float*)d_in[9];
  const float* l2b  = (const float*)d_in[10];
  float* out = (float*)d_out;

  char* p = (char*)d_ws;
  auto carve = [&](size_t bytes) -> char* {
    char* r = p; p += (bytes + 255) & ~(size_t)255; return r;
  };
  float*  svec  = (float*)carve((size_t)CC * NN * 4);
  float*  dinv1 = (float*)carve((size_t)CC * NN * 4);
  float*  m1    = (float*)carve((size_t)CC * NN * 4);
  float*  cscal = (float*)carve((size_t)CC * NN * 4);
  float*  disv  = (float*)carve((size_t)CC * NN * 4);
  float*  Mdiag = (float*)carve((size_t)CC * NN * 4);
  float*  part  = (float*)carve((size_t)CC * 32 * NN * 4);
  bf16_t* S1    = (bf16_t*)carve((size_t)CC * N2 * 2); // Ha -> {XWdT, Yt, Z}
  bf16_t* HbT   = (bf16_t*)carve((size_t)CC * N2 * 2);
  bf16_t* Hb2T  = (bf16_t*)carve((size_t)CC * N2 * 2);
  bf16_t* Hn    = (bf16_t*)carve((size_t)CC * N2 * 2);
  bf16_t* HnT   = (bf16_t*)carve((size_t)CC * N2 * 2);
  bf16_t* Xb    = (bf16_t*)carve((size_t)NN * WIN * 2);
  bf16_t* gwT   = (bf16_t*)carve((size_t)WOUT * WIN * 2);
  bf16_t* l1wb  = (bf16_t*)carve((size_t)WOUT * CC * WOUT * 2);
  bf16_t* l2wb  = (bf16_t*)carve((size_t)WOUT * WOUT * 2);
  float*  XW    = (float*)carve((size_t)NN * WOUT * 4);
  bf16_t* XWT   = (bf16_t*)carve((size_t)WOUT * NN * 2);
  bf16_t* Xcat  = (bf16_t*)carve((size_t)NN * CC * WOUT * 2);
  bf16_t* hb    = (bf16_t*)carve((size_t)NN * WOUT * 2);

  bf16_t* Ha = S1;
  // Ha is dead after GEMM1; reuse its 16 MB for the skinny-GEMM intermediates
  bf16_t* XWdT = (bf16_t*)((char*)S1);                         // 2 MB (2ch x 256x2048 bf16)
  bf16_t* Yt   = (bf16_t*)((char*)S1 + (2LL << 20));           // 2 MB (2ch x 256x2048 bf16)
  float*  Z    = (float*) ((char*)S1 + (6LL << 20));           // 8 MB (2ch x 2048x256 f32)

  // prep
  k_prep<<<640, 256, 0, stream>>>(X, l1w, l2w, gcnw, Xb, l1wb, l2wb, gwT);
  k_combine<<<dim3(32, 32), 256, 0, stream>>>(A, w0a, w0b, w1, Ha, HbT, Hb2T, part);
  k_s_finish<<<16, 256, 0, stream>>>(part, svec);

  // layer 0: analytic degrees; GEMM1 with fused normalize, writes Hn AND HnT
  k_deg<false><<<dim3(512, 2), 256, 0, stream>>>(svec, Ha, HbT, dinv1, m1, nullptr);
  k_gemm<EP_NORM1T><<<dim3(16, 32, 2), 256, 0, stream>>>(
      Ha, HbT, Hn, dinv1, nullptr, HnT, NN, NN, NN, NN, N2, N2, N2);

  // layer 1 scalars: deg2 (-> cscal, disv) and Mdiag from one row-dot pass
  k_deg<true><<<dim3(512, 2), 256, 0, stream>>>(m1, Hn, Hb2T, cscal, disv, Mdiag);

  // GCN via associativity: XW (+XWT); XWdT = disv .* XWT;
  // Yt[f,k] = sum_i XWdT[f,i]*HnT[k,i]; Z[n,f] = sum_k Hb2T[n,k]*Yt[f,k]
  k_gemm<EP_XWT><<<dim3(16, 4, 1), 256, 0, stream>>>(
      Xb, gwT, XW, nullptr, nullptr, XWT, WOUT, WIN, WIN, WIN, 0, 0, 0);
  k_scale_xwd<<<512, 256, 0, stream>>>(XWT, disv, XWdT);
  k_gemm<EP_BF16O><<<dim3(2, 32, 2), 256, 0, stream>>>(
      XWdT, HnT, Yt, nullptr, nullptr, nullptr, NN, NN, NN, NN,
      (long long)WOUT * NN, N2, (long long)WOUT * NN);
  k_gemm<EP_F32><<<dim3(16, 4, 2), 256, 0, stream>>>(
      Hb2T, Yt, Z, nullptr, nullptr, nullptr, WOUT, NN, NN, NN,
      N2, (long long)WOUT * NN, (long long)NN * WOUT);
  k_gcn_epi2<<<1024, 256, 0, stream>>>(Z, XW, gcnb, cscal, disv, Mdiag, Xcat);

  // MLP with fused bias(+relu)
  k_gemm<EP_BRELU><<<dim3(16, 4, 1), 256, 0, stream>>>(
      Xcat, l1wb, hb, l1b, nullptr, nullptr, WOUT, CC * WOUT, CC * WOUT, CC * WOUT, 0, 0, 0);
  k_gemm<EP_BF32><<<dim3(16, 4, 1), 256, 0, stream>>>(
      hb, l2wb, out, l2b, nullptr, nullptr, WOUT, WOUT, WOUT, WOUT, 0, 0, 0);
}

// Round 6
// 165.128 us; speedup vs baseline: 1.7823x; 1.1244x over previous
//
#include <hip/hip_runtime.h>
#include <cstdint>
#include <cstddef>

#define NN   2048
#define N2   (2048LL*2048LL)
#define CC   2
#define EE   5
#define WIN  512
#define WOUT 256

typedef __bf16 bf16_t;
typedef __attribute__((ext_vector_type(8))) __bf16 bf16x8;
typedef __attribute__((ext_vector_type(4))) __bf16 bf16x4;
typedef __attribute__((ext_vector_type(4))) float  f32x4;

// ---------------- prep: bf16 casts + gcn_w transpose-cast, one launch ----------------
__global__ void k_prep(const float* __restrict__ X, const float* __restrict__ l1w,
                       const float* __restrict__ l2w, const float* __restrict__ gcnw,
                       bf16_t* __restrict__ Xb, bf16_t* __restrict__ l1wb,
                       bf16_t* __restrict__ l2wb, bf16_t* __restrict__ gwT) {
  __shared__ bf16_t tile[64][65];
  int bid = blockIdx.x;
  if (bid < 608) {
    int i = bid * 256 + threadIdx.x;
    const float* src; bf16_t* dst; int off;
    if (i < 131072)      { src = X;   dst = Xb;   off = i; }
    else if (i < 147456) { src = l1w; dst = l1wb; off = i - 131072; }
    else if (i < 155648) { src = l2w; dst = l2wb; off = i - 147456; }
    else return;
    float4 a = ((const float4*)src)[off * 2];
    float4 b = ((const float4*)src)[off * 2 + 1];
    bf16x8 o;
    o[0] = (bf16_t)a.x; o[1] = (bf16_t)a.y; o[2] = (bf16_t)a.z; o[3] = (bf16_t)a.w;
    o[4] = (bf16_t)b.x; o[5] = (bf16_t)b.y; o[6] = (bf16_t)b.z; o[7] = (bf16_t)b.w;
    ((bf16x8*)dst)[off] = o;
  } else {
    int b2 = bid - 608;              // 0..31
    int m0 = (b2 & 7) * 64, n0 = (b2 >> 3) * 64;
    int t = threadIdx.x, tr = t >> 4, tc = (t & 15) << 2;
#pragma unroll
    for (int v = 0; v < 4; ++v) {
      int r = tr + v * 16;
      float4 d = *(const float4*)&gcnw[(long long)(m0 + r) * WOUT + n0 + tc];
      tile[r][tc + 0] = (bf16_t)d.x; tile[r][tc + 1] = (bf16_t)d.y;
      tile[r][tc + 2] = (bf16_t)d.z; tile[r][tc + 3] = (bf16_t)d.w;
    }
    __syncthreads();
#pragma unroll
    for (int v = 0; v < 4; ++v) {
      int r = tr + v * 16;
      bf16x4 o;
      o[0] = tile[tc + 0][r]; o[1] = tile[tc + 1][r];
      o[2] = tile[tc + 2][r]; o[3] = tile[tc + 3][r];
      *(bf16x4*)&gwT[(long long)(n0 + r) * WIN + m0 + tc] = o;
    }
  }
}

// ---------------- combine: single A pass; Hb via LDS, Hb2 carried in registers ----------------

__global__ void k_combine(const float* __restrict__ A,
                          const float* __restrict__ w0a, const float* __restrict__ w0b,
                          const float* __restrict__ w1,
                          bf16_t* __restrict__ Ha, bf16_t* __restrict__ HbT,
                          bf16_t* __restrict__ Hb2T, float* __restrict__ part) {
  __shared__ bf16_t tl[2][64][65];
  __shared__ float cs[2][16][64];
  float f[3][2][5];
  {
    const float* wp[3] = {w0a, w0b, w1};
#pragma unroll
    for (int w = 0; w < 3; ++w)
#pragma unroll
      for (int c = 0; c < 2; ++c) {
        float x[5], m = -1e30f, s = 0.f;
#pragma unroll
        for (int e = 0; e < 5; ++e) { x[e] = wp[w][c * 5 + e]; m = fmaxf(m, x[e]); }
#pragma unroll
        for (int e = 0; e < 5; ++e) { x[e] = expf(x[e] - m); s += x[e]; }
#pragma unroll
        for (int e = 0; e < 5; ++e) f[w][c][e] = x[e] / s;
      }
  }
  int i0 = blockIdx.x * 64, j0 = blockIdx.y * 64;
  int t = threadIdx.x, tr = t >> 4, tc = (t & 15) << 2;
  float cs0[4] = {0, 0, 0, 0}, cs1[4] = {0, 0, 0, 0};
  bf16x4 hb2a[4], hb2b[4];

#pragma unroll
  for (int v = 0; v < 4; ++v) {
    int lr = tr + v * 16;
    long long gi = i0 + lr;
    const float* base = A + gi * (long long)NN + j0 + tc;
    float av[5][4];
#pragma unroll
    for (int e = 0; e < 5; ++e) {
      float4 q = *(const float4*)(base + (long long)e * N2);
      av[e][0] = q.x; av[e][1] = q.y; av[e][2] = q.z; av[e][3] = q.w;
    }
    bf16x4 ha0, ha1;
#pragma unroll
    for (int x = 0; x < 4; ++x) {
      float s0 = 0.f, s1 = 0.f, s2 = 0.f, s3 = 0.f, s4 = 0.f, s5 = 0.f;
#pragma unroll
      for (int e = 0; e < 5; ++e) {
        float u = av[e][x];
        s0 += f[0][0][e] * u; s1 += f[0][1][e] * u;
        s2 += f[1][0][e] * u; s3 += f[1][1][e] * u;
        s4 += f[2][0][e] * u; s5 += f[2][1][e] * u;
      }
      ha0[x] = (bf16_t)s0; cs0[x] += (float)ha0[x];
      ha1[x] = (bf16_t)s1; cs1[x] += (float)ha1[x];
      tl[0][lr][tc + x] = (bf16_t)s2; tl[1][lr][tc + x] = (bf16_t)s3;
      hb2a[v][x] = (bf16_t)s4; hb2b[v][x] = (bf16_t)s5;
    }
    *(bf16x4*)&Ha[0 * N2 + gi * NN + j0 + tc] = ha0;
    *(bf16x4*)&Ha[1 * N2 + gi * NN + j0 + tc] = ha1;
  }
#pragma unroll
  for (int x = 0; x < 4; ++x) { cs[0][tr][tc + x] = cs0[x]; cs[1][tr][tc + x] = cs1[x]; }
  __syncthreads();

#pragma unroll
  for (int v = 0; v < 4; ++v) {
    int lr = tr + v * 16;
#pragma unroll
    for (int ch = 0; ch < 2; ++ch) {
      bf16x4 o;
      o[0] = tl[ch][tc + 0][lr]; o[1] = tl[ch][tc + 1][lr];
      o[2] = tl[ch][tc + 2][lr]; o[3] = tl[ch][tc + 3][lr];
      *(bf16x4*)&HbT[(long long)ch * N2 + (long long)(j0 + lr) * NN + i0 + tc] = o;
    }
  }
  if (t < 128) {
    int ch = t >> 6, col = t & 63;
    float s = 0.f;
#pragma unroll
    for (int r = 0; r < 16; ++r) s += cs[ch][r][col];
    part[((long long)ch * 32 + blockIdx.x) * NN + j0 + col] = s;
  }
  __syncthreads();

#pragma unroll
  for (int v = 0; v < 4; ++v) {
    int lr = tr + v * 16;
#pragma unroll
    for (int x = 0; x < 4; ++x) {
      tl[0][lr][tc + x] = hb2a[v][x];
      tl[1][lr][tc + x] = hb2b[v][x];
    }
  }
  __syncthreads();

#pragma unroll
  for (int v = 0; v < 4; ++v) {
    int lr = tr + v * 16;
#pragma unroll
    for (int ch = 0; ch < 2; ++ch) {
      bf16x4 o;
      o[0] = tl[ch][tc + 0][lr]; o[1] = tl[ch][tc + 1][lr];
      o[2] = tl[ch][tc + 2][lr]; o[3] = tl[ch][tc + 3][lr];
      *(bf16x4*)&Hb2T[(long long)ch * N2 + (long long)(j0 + lr) * NN + i0 + tc] = o;
    }
  }
}

__global__ void k_s_finish(const float* __restrict__ part, float* __restrict__ s) {
  int idx = blockIdx.x * 256 + threadIdx.x;
  int c = idx >> 11, k = idx & 2047;
  float acc = 0.f;
#pragma unroll
  for (int ib = 0; ib < 32; ++ib) acc += part[((long long)c * 32 + ib) * NN + k];
  s[idx] = acc;
}

// deg[c][j] = sum_k (svec[k] - A[j,k])*BT[j,k];  Mdiag[c][j] = sum_k A[j,k]*BT[j,k]
template<bool EMIT_DIS>
__global__ void k_deg(const float* __restrict__ svec, const bf16_t* __restrict__ Arows,
                      const bf16_t* __restrict__ BT,
                      float* __restrict__ out1, float* __restrict__ out2,
                      float* __restrict__ out3) {
  int c = blockIdx.y;
  int j = blockIdx.x * 4 + (threadIdx.x >> 6);
  int lane = threadIdx.x & 63;
  const bf16_t* a = Arows + (long long)c * N2 + (long long)j * NN;
  const bf16_t* b = BT + (long long)c * N2 + (long long)j * NN;
  const float* s = svec + c * NN;
  float acc_s = 0.f, acc_a = 0.f;
#pragma unroll
  for (int it = 0; it < 4; ++it) {
    int k0 = (lane + it * 64) * 8;
    bf16x8 av = *(const bf16x8*)(a + k0);
    bf16x8 bv = *(const bf16x8*)(b + k0);
    float4 s0 = *(const float4*)(s + k0);
    float4 s1 = *(const float4*)(s + k0 + 4);
    float sv[8] = {s0.x, s0.y, s0.z, s0.w, s1.x, s1.y, s1.z, s1.w};
#pragma unroll
    for (int x = 0; x < 8; ++x) {
      float bx = (float)bv[x];
      acc_s += sv[x] * bx;
      acc_a += (float)av[x] * bx;
    }
  }
#pragma unroll
  for (int o = 32; o > 0; o >>= 1) {
    acc_s += __shfl_xor(acc_s, o, 64);
    acc_a += __shfl_xor(acc_a, o, 64);
  }
  if (lane == 0) {
    float deg = acc_s - acc_a;
    bool nz = (deg != 0.f);
    if (!EMIT_DIS) {
      out1[c * NN + j] = nz ? 1.f / deg : 0.f;
      out2[c * NN + j] = nz ? 1.f : 0.f;
    } else {
      float dis = nz ? 0.70710678118654752f : 1.f;
      out1[c * NN + j] = nz ? dis / deg : 0.f;     // cscal = dis/deg2
      out2[c * NN + j] = dis;                      // disv
      out3[c * NN + j] = acc_a;                    // Mdiag = diag(Hn@Hb2)
    }
  }
}

// XWdT[c][f][i] = XWT[f][i] * disv[c][i]
__global__ void k_scale_xwd(const bf16_t* __restrict__ XWT, const float* __restrict__ disv,
                            bf16_t* __restrict__ XWdT) {
  int i = blockIdx.x * 256 + threadIdx.x;
  int c = i >> 16, rem = i & 65535;
  bf16x8 v = ((const bf16x8*)XWT)[rem];
  int col0 = (rem & 255) * 8;
  float4 d0 = *(const float4*)(disv + c * NN + col0);
  float4 d1 = *(const float4*)(disv + c * NN + col0 + 4);
  bf16x8 o;
  o[0] = (bf16_t)((float)v[0] * d0.x); o[1] = (bf16_t)((float)v[1] * d0.y);
  o[2] = (bf16_t)((float)v[2] * d0.z); o[3] = (bf16_t)((float)v[3] * d0.w);
  o[4] = (bf16_t)((float)v[4] * d1.x); o[5] = (bf16_t)((float)v[5] * d1.y);
  o[6] = (bf16_t)((float)v[6] * d1.z); o[7] = (bf16_t)((float)v[7] * d1.w);
  ((bf16x8*)XWdT)[i] = o;
}

// ---------------- bf16 GEMM, 128x64 tile, 4 waves (2x2) ----------------
// 3-slot LDS ring, counted vmcnt (T4), chunk-XOR swizzle (T2), fused epilogues.

enum { EP_F32 = 0, EP_NORM1T = 1, EP_BRELU = 3, EP_BF32 = 4, EP_XWT = 5, EP_BF16O = 7 };

template<int EP>
__global__ __launch_bounds__(256)
void k_gemm(const bf16_t* __restrict__ A, const bf16_t* __restrict__ B,
            void* __restrict__ Cv,
            const float* __restrict__ aux1, const float* __restrict__ aux2,
            bf16_t* __restrict__ aux3,
            int N, int K, int lda, int ldb,
            long long zA, long long zB, long long zC) {
  // As: 3 slots x 128x32 bf16 (8 KB) at 0; Bs: 3 slots x 64x32 (4 KB) at 24576.
  // Epilogue transpose tile (128x65 bf16 = 16.6 KB) reuses offset 0 after the final barrier.
  __shared__ __align__(16) char smem[36864];
  bf16_t* As = (bf16_t*)smem;
  bf16_t* Bs = (bf16_t*)(smem + 24576);
  bf16_t* tile = (bf16_t*)smem;

  int cz = blockIdx.z;
  const bf16_t* Ab = A + cz * zA + (long long)blockIdx.x * 128 * lda;
  const bf16_t* Bb = B + cz * zB + (long long)blockIdx.y * 64 * ldb;

  int t = threadIdx.x, wid = t >> 6, lane = t & 63;
  int wr = wid >> 1, wc = wid & 1;
  f32x4 acc[4][2] = {};
  int frow = lane & 15;
  // T2 swizzle: LDS slot (row, chunk) holds global chunk (chunk ^ ((row>>1)&3)).
  // Read side: element offset for fragment chunk (lane>>4) at row ..+frow:
  int fk_sw = (((lane >> 4) ^ ((frow >> 1) & 3)) << 3);
  int srow = t >> 2;
  // Stage side: source chunk = (t&3) ^ ((srow>>1)&3) = (t&3) ^ ((t>>3)&3)
  int scol_sw = (((t & 3) ^ ((t >> 3) & 3)) << 3);
  int nt = K >> 5;  // always >= 8 here

  auto STAGE = [&](int TT, int BUF) {
    long long kko = (long long)TT * 32 + scol_sw;
    const bf16_t* ga0 = Ab + (long long)srow * lda + kko;
    const bf16_t* ga1 = Ab + (long long)(64 + srow) * lda + kko;
    const bf16_t* gb0 = Bb + (long long)srow * ldb + kko;
    char* la = smem + BUF * 8192 + wid * 1024;
    char* lb = smem + 24576 + BUF * 4096 + wid * 1024;
    __builtin_amdgcn_global_load_lds((__attribute__((address_space(1))) void*)ga0,
        (__attribute__((address_space(3))) void*)la, 16, 0, 0);
    __builtin_amdgcn_global_load_lds((__attribute__((address_space(1))) void*)ga1,
        (__attribute__((address_space(3))) void*)(la + 4096), 16, 0, 0);
    __builtin_amdgcn_global_load_lds((__attribute__((address_space(1))) void*)gb0,
        (__attribute__((address_space(3))) void*)lb, 16, 0, 0);
  };
  auto COMPUTE = [&](int BUF) {
    bf16x8 af[4], bfr[2];
#pragma unroll
    for (int m = 0; m < 4; ++m)
      af[m] = *(const bf16x8*)&As[BUF * 4096 + (wr * 64 + m * 16 + frow) * 32 + fk_sw];
#pragma unroll
    for (int n = 0; n < 2; ++n)
      bfr[n] = *(const bf16x8*)&Bs[BUF * 2048 + (wc * 32 + n * 16 + frow) * 32 + fk_sw];
#pragma unroll
    for (int m = 0; m < 4; ++m)
#pragma unroll
      for (int n = 0; n < 2; ++n)
        acc[m][n] = __builtin_amdgcn_mfma_f32_16x16x32_bf16(af[m], bfr[n], acc[m][n], 0, 0, 0);
  };

  // prologue: 3 slots in flight (9 loads/wave)
  STAGE(0, 0); STAGE(1, 1); STAGE(2, 2);
  int slot = 0;
  for (int tt = 0; tt < nt; ++tt) {
    int rem = nt - 1 - tt;  // slots staged beyond current
    if (rem >= 2)      asm volatile("s_waitcnt vmcnt(6)" ::: "memory");
    else if (rem == 1) asm volatile("s_waitcnt vmcnt(3)" ::: "memory");
    else               asm volatile("s_waitcnt vmcnt(0)" ::: "memory");
    __builtin_amdgcn_s_barrier();          // slot tt staged by ALL waves
    __builtin_amdgcn_sched_barrier(0);
    COMPUTE(slot);
    __builtin_amdgcn_s_barrier();          // all waves done reading slot tt
    if (tt + 3 < nt) STAGE(tt + 3, slot);  // safe overwrite
    slot = (slot == 2) ? 0 : slot + 1;
  }
  __builtin_amdgcn_sched_barrier(0);

  int rl0 = wr * 64 + ((lane >> 4) << 2);
  int cl0 = wc * 32 + (lane & 15);
  int r0 = blockIdx.x * 128 + rl0;
  int c0 = blockIdx.y * 64 + cl0;

  if constexpr (EP == EP_F32) {
    float* Cb = (float*)Cv + cz * zC;
#pragma unroll
    for (int m = 0; m < 4; ++m)
#pragma unroll
      for (int n = 0; n < 2; ++n)
#pragma unroll
        for (int j = 0; j < 4; ++j)
          Cb[(long long)(r0 + m * 16 + j) * N + c0 + n * 16] = acc[m][n][j];
  } else if constexpr (EP == EP_BF16O) {
    bf16_t* Cb = (bf16_t*)Cv + cz * zC;
#pragma unroll
    for (int m = 0; m < 4; ++m)
#pragma unroll
      for (int n = 0; n < 2; ++n)
#pragma unroll
        for (int j = 0; j < 4; ++j)
          Cb[(long long)(r0 + m * 16 + j) * N + c0 + n * 16] = (bf16_t)acc[m][n][j];
  } else if constexpr (EP == EP_NORM1T) {
    // Hn = (r==col)?0: acc*dinv1[col]  (row-major) ; HnT = transpose(Hn) via LDS
    bf16_t* Cb = (bf16_t*)Cv + cz * zC;
    bf16_t* Ct = aux3 + cz * zC;
    float dj[2];
#pragma unroll
    for (int n = 0; n < 2; ++n) dj[n] = aux1[cz * NN + c0 + n * 16];
#pragma unroll
    for (int m = 0; m < 4; ++m)
#pragma unroll
      for (int n = 0; n < 2; ++n)
#pragma unroll
        for (int j = 0; j < 4; ++j) {
          int r = r0 + m * 16 + j, col = c0 + n * 16;
          float v = (r == col) ? 0.f : acc[m][n][j] * dj[n];
          Cb[(long long)r * NN + col] = (bf16_t)v;
          tile[(rl0 + m * 16 + j) * 65 + cl0 + n * 16] = (bf16_t)v;
        }
    __syncthreads();
    int nl = t >> 5, rl = (t & 31) * 4;
#pragma unroll
    for (int vv = 0; vv < 8; ++vv) {
      int n_l = nl + vv * 8;
      bf16x4 o;
      o[0] = tile[(rl + 0) * 65 + n_l]; o[1] = tile[(rl + 1) * 65 + n_l];
      o[2] = tile[(rl + 2) * 65 + n_l]; o[3] = tile[(rl + 3) * 65 + n_l];
      *(bf16x4*)&Ct[(long long)(blockIdx.y * 64 + n_l) * NN + blockIdx.x * 128 + rl] = o;
    }
  } else if constexpr (EP == EP_XWT) {
    float* Cb = (float*)Cv;
#pragma unroll
    for (int m = 0; m < 4; ++m)
#pragma unroll
      for (int n = 0; n < 2; ++n)
#pragma unroll
        for (int j = 0; j < 4; ++j) {
          float v = acc[m][n][j];
          Cb[(long long)(r0 + m * 16 + j) * N + c0 + n * 16] = v;
          tile[(rl0 + m * 16 + j) * 65 + cl0 + n * 16] = (bf16_t)v;
        }
    __syncthreads();
    int nl = t >> 5, rl = (t & 31) * 4;
#pragma unroll
    for (int vv = 0; vv < 8; ++vv) {
      int n_l = nl + vv * 8;
      bf16x4 o;
      o[0] = tile[(rl + 0) * 65 + n_l]; o[1] = tile[(rl + 1) * 65 + n_l];
      o[2] = tile[(rl + 2) * 65 + n_l]; o[3] = tile[(rl + 3) * 65 + n_l];
      *(bf16x4*)&aux3[(long long)(blockIdx.y * 64 + n_l) * NN + blockIdx.x * 128 + rl] = o;
    }
  } else if constexpr (EP == EP_BRELU) {
    bf16_t* Cb = (bf16_t*)Cv;
    float bj[2];
#pragma unroll
    for (int n = 0; n < 2; ++n) bj[n] = aux1[c0 + n * 16];
#pragma unroll
    for (int m = 0; m < 4; ++m)
#pragma unroll
      for (int n = 0; n < 2; ++n)
#pragma unroll
        for (int j = 0; j < 4; ++j)
          Cb[(long long)(r0 + m * 16 + j) * N + c0 + n * 16] =
              (bf16_t)fmaxf(acc[m][n][j] + bj[n], 0.f);
  } else { // EP_BF32
    float* Cb = (float*)Cv;
    float bj[2];
#pragma unroll
    for (int n = 0; n < 2; ++n) bj[n] = aux1[c0 + n * 16];
#pragma unroll
    for (int m = 0; m < 4; ++m)
#pragma unroll
      for (int n = 0; n < 2; ++n)
#pragma unroll
        for (int j = 0; j < 4; ++j)
          Cb[(long long)(r0 + m * 16 + j) * N + c0 + n * 16] = acc[m][n][j] + bj[n];
  }
}

// ---------------- GCN epilogue: out = relu(cscal*(Z - Mdiag*dis*XW) + dis^2*XW + b) ----------------

__global__ void k_gcn_epi2(const float* __restrict__ Z, const float* __restrict__ XW,
                           const float* __restrict__ gcn_b, const float* __restrict__ cscal,
                           const float* __restrict__ disv, const float* __restrict__ Mdiag,
                           bf16_t* __restrict__ Xcat) {
  long long idx4 = ((long long)blockIdx.x * 256 + threadIdx.x) * 4;
  int c = (int)(idx4 >> 19);
  int rem = (int)(idx4 & ((1 << 19) - 1));
  int n = rem >> 8, fcol = rem & 255;
  float4 z  = *(const float4*)(Z + (long long)c * NN * WOUT + rem);
  float4 xw = *(const float4*)(XW + rem);
  float4 b  = *(const float4*)(gcn_b + fcol);
  float cs = cscal[c * NN + n], dn = disv[c * NN + n], md = Mdiag[c * NN + n];
  float d2 = dn * dn, mdd = md * dn;
  bf16x4 o;
  o[0] = (bf16_t)fmaxf(cs * (z.x - mdd * xw.x) + d2 * xw.x + b.x, 0.f);
  o[1] = (bf16_t)fmaxf(cs * (z.y - mdd * xw.y) + d2 * xw.y + b.y, 0.f);
  o[2] = (bf16_t)fmaxf(cs * (z.z - mdd * xw.z) + d2 * xw.z + b.z, 0.f);
  o[3] = (bf16_t)fmaxf(cs * (z.w - mdd * xw.w) + d2 * xw.w + b.w, 0.f);
  *(bf16x4*)&Xcat[(long long)n * (CC * WOUT) + c * WOUT + fcol] = o;
}

// ---------------- launch ----------------

extern "C" void kernel_launch(void* const* d_in, const int* in_sizes, int n_in,
                              void* d_out, int out_size, void* d_ws, size_t ws_size,
                              hipStream_t stream) {
  const float* A    = (const float*)d_in[0];
  const float* X    = (const float*)d_in[1];
  const float* w0a  = (const float*)d_in[2];
  const float* w0b  = (const float*)d_in[3];
  const float* w1   = (const float*)d_in[4];
  const float* gcnw = (const float*)d_in[5];
  const float* gcnb = (const float*)d_in[6];
  const float* l1w  = (const float*)d_in[7];
  const float* l1b  = (const float*)d_in[8];
  const float* l2w  = (const float*)d_in[9];
  const float* l2b  = (const float*)d_in[10];
  float* out = (float*)d_out;

  char* p = (char*)d_ws;
  auto carve = [&](size_t bytes) -> char* {
    char* r = p; p += (bytes + 255) & ~(size_t)255; return r;
  };
  float*  svec  = (float*)carve((size_t)CC * NN * 4);
  float*  dinv1 = (float*)carve((size_t)CC * NN * 4);
  float*  m1    = (float*)carve((size_t)CC * NN * 4);
  float*  cscal = (float*)carve((size_t)CC * NN * 4);
  float*  disv  = (float*)carve((size_t)CC * NN * 4);
  float*  Mdiag = (float*)carve((size_t)CC * NN * 4);
  float*  part  = (float*)carve((size_t)CC * 32 * NN * 4);
  bf16_t* S1    = (bf16_t*)carve((size_t)CC * N2 * 2); // Ha -> {XWdT, Yt, Z}
  bf16_t* HbT   = (bf16_t*)carve((size_t)CC * N2 * 2);
  bf16_t* Hb2T  = (bf16_t*)carve((size_t)CC * N2 * 2);
  bf16_t* Hn    = (bf16_t*)carve((size_t)CC * N2 * 2);
  bf16_t* HnT   = (bf16_t*)carve((size_t)CC * N2 * 2);
  bf16_t* Xb    = (bf16_t*)carve((size_t)NN * WIN * 2);
  bf16_t* gwT   = (bf16_t*)carve((size_t)WOUT * WIN * 2);
  bf16_t* l1wb  = (bf16_t*)carve((size_t)WOUT * CC * WOUT * 2);
  bf16_t* l2wb  = (bf16_t*)carve((size_t)WOUT * WOUT * 2);
  float*  XW    = (float*)carve((size_t)NN * WOUT * 4);
  bf16_t* XWT   = (bf16_t*)carve((size_t)WOUT * NN * 2);
  bf16_t* Xcat  = (bf16_t*)carve((size_t)NN * CC * WOUT * 2);
  bf16_t* hb    = (bf16_t*)carve((size_t)NN * WOUT * 2);

  bf16_t* Ha = S1;
  bf16_t* XWdT = (bf16_t*)((char*)S1);
  bf16_t* Yt   = (bf16_t*)((char*)S1 + (2LL << 20));
  float*  Z    = (float*) ((char*)S1 + (6LL << 20));

  // prep
  k_prep<<<640, 256, 0, stream>>>(X, l1w, l2w, gcnw, Xb, l1wb, l2wb, gwT);
  k_combine<<<dim3(32, 32), 256, 0, stream>>>(A, w0a, w0b, w1, Ha, HbT, Hb2T, part);
  k_s_finish<<<16, 256, 0, stream>>>(part, svec);

  // layer 0: analytic degrees; GEMM1 with fused normalize, writes Hn AND HnT
  k_deg<false><<<dim3(512, 2), 256, 0, stream>>>(svec, Ha, HbT, dinv1, m1, nullptr);
  k_gemm<EP_NORM1T><<<dim3(16, 32, 2), 256, 0, stream>>>(
      Ha, HbT, Hn, dinv1, nullptr, HnT, NN, NN, NN, NN, N2, N2, N2);

  // layer 1 scalars: deg2 (-> cscal, disv) and Mdiag from one row-dot pass
  k_deg<true><<<dim3(512, 2), 256, 0, stream>>>(m1, Hn, Hb2T, cscal, disv, Mdiag);

  // GCN via associativity
  k_gemm<EP_XWT><<<dim3(16, 4, 1), 256, 0, stream>>>(
      Xb, gwT, XW, nullptr, nullptr, XWT, WOUT, WIN, WIN, WIN, 0, 0, 0);
  k_scale_xwd<<<512, 256, 0, stream>>>(XWT, disv, XWdT);
  k_gemm<EP_BF16O><<<dim3(2, 32, 2), 256, 0, stream>>>(
      XWdT, HnT, Yt, nullptr, nullptr, nullptr, NN, NN, NN, NN,
      (long long)WOUT * NN, N2, (long long)WOUT * NN);
  k_gemm<EP_F32><<<dim3(16, 4, 2), 256, 0, stream>>>(
      Hb2T, Yt, Z, nullptr, nullptr, nullptr, WOUT, NN, NN, NN,
      N2, (long long)WOUT * NN, (long long)NN * WOUT);
  k_gcn_epi2<<<1024, 256, 0, stream>>>(Z, XW, gcnb, cscal, disv, Mdiag, Xcat);

  // MLP with fused bias(+relu)
  k_gemm<EP_BRELU><<<dim3(16, 4, 1), 256, 0, stream>>>(
      Xcat, l1wb, hb, l1b, nullptr, nullptr, WOUT, CC * WOUT, CC * WOUT, CC * WOUT, 0, 0, 0);
  k_gemm<EP_BF32><<<dim3(16, 4, 1), 256, 0, stream>>>(
      hb, l2wb, out, l2b, nullptr, nullptr, WOUT, WOUT, WOUT, WOUT, 0, 0, 0);
}

// Round 7
// 152.765 us; speedup vs baseline: 1.9265x; 1.0809x over previous
//
#include <hip/hip_runtime.h>
#include <cstdint>
#include <cstddef>

#define NN   2048
#define N2   (2048LL*2048LL)
#define CC   2
#define EE   5
#define WIN  512
#define WOUT 256

typedef __bf16 bf16_t;
typedef __attribute__((ext_vector_type(8))) __bf16 bf16x8;
typedef __attribute__((ext_vector_type(4))) __bf16 bf16x4;
typedef __attribute__((ext_vector_type(4))) float  f32x4;

// ---------------- prep: bf16 casts + gcn_w transpose-cast, one launch ----------------
__global__ void k_prep(const float* __restrict__ X, const float* __restrict__ l1w,
                       const float* __restrict__ l2w, const float* __restrict__ gcnw,
                       bf16_t* __restrict__ Xb, bf16_t* __restrict__ l1wb,
                       bf16_t* __restrict__ l2wb, bf16_t* __restrict__ gwT) {
  __shared__ bf16_t tile[64][65];
  int bid = blockIdx.x;
  if (bid < 608) {
    int i = bid * 256 + threadIdx.x;
    const float* src; bf16_t* dst; int off;
    if (i < 131072)      { src = X;   dst = Xb;   off = i; }
    else if (i < 147456) { src = l1w; dst = l1wb; off = i - 131072; }
    else if (i < 155648) { src = l2w; dst = l2wb; off = i - 147456; }
    else return;
    float4 a = ((const float4*)src)[off * 2];
    float4 b = ((const float4*)src)[off * 2 + 1];
    bf16x8 o;
    o[0] = (bf16_t)a.x; o[1] = (bf16_t)a.y; o[2] = (bf16_t)a.z; o[3] = (bf16_t)a.w;
    o[4] = (bf16_t)b.x; o[5] = (bf16_t)b.y; o[6] = (bf16_t)b.z; o[7] = (bf16_t)b.w;
    ((bf16x8*)dst)[off] = o;
  } else {
    int b2 = bid - 608;              // 0..31
    int m0 = (b2 & 7) * 64, n0 = (b2 >> 3) * 64;
    int t = threadIdx.x, tr = t >> 4, tc = (t & 15) << 2;
#pragma unroll
    for (int v = 0; v < 4; ++v) {
      int r = tr + v * 16;
      float4 d = *(const float4*)&gcnw[(long long)(m0 + r) * WOUT + n0 + tc];
      tile[r][tc + 0] = (bf16_t)d.x; tile[r][tc + 1] = (bf16_t)d.y;
      tile[r][tc + 2] = (bf16_t)d.z; tile[r][tc + 3] = (bf16_t)d.w;
    }
    __syncthreads();
#pragma unroll
    for (int v = 0; v < 4; ++v) {
      int r = tr + v * 16;
      bf16x4 o;
      o[0] = tile[tc + 0][r]; o[1] = tile[tc + 1][r];
      o[2] = tile[tc + 2][r]; o[3] = tile[tc + 3][r];
      *(bf16x4*)&gwT[(long long)(n0 + r) * WIN + m0 + tc] = o;
    }
  }
}

// ---------------- combine: single A pass; Hb via LDS, Hb2 carried in registers ----------------

__global__ void k_combine(const float* __restrict__ A,
                          const float* __restrict__ w0a, const float* __restrict__ w0b,
                          const float* __restrict__ w1,
                          bf16_t* __restrict__ Ha, bf16_t* __restrict__ HbT,
                          bf16_t* __restrict__ Hb2T, float* __restrict__ part) {
  __shared__ bf16_t tl[2][64][65];
  __shared__ float cs[2][16][64];
  float f[3][2][5];
  {
    const float* wp[3] = {w0a, w0b, w1};
#pragma unroll
    for (int w = 0; w < 3; ++w)
#pragma unroll
      for (int c = 0; c < 2; ++c) {
        float x[5], m = -1e30f, s = 0.f;
#pragma unroll
        for (int e = 0; e < 5; ++e) { x[e] = wp[w][c * 5 + e]; m = fmaxf(m, x[e]); }
#pragma unroll
        for (int e = 0; e < 5; ++e) { x[e] = expf(x[e] - m); s += x[e]; }
#pragma unroll
        for (int e = 0; e < 5; ++e) f[w][c][e] = x[e] / s;
      }
  }
  int i0 = blockIdx.x * 64, j0 = blockIdx.y * 64;
  int t = threadIdx.x, tr = t >> 4, tc = (t & 15) << 2;
  float cs0[4] = {0, 0, 0, 0}, cs1[4] = {0, 0, 0, 0};
  bf16x4 hb2a[4], hb2b[4];

#pragma unroll
  for (int v = 0; v < 4; ++v) {
    int lr = tr + v * 16;
    long long gi = i0 + lr;
    const float* base = A + gi * (long long)NN + j0 + tc;
    float av[5][4];
#pragma unroll
    for (int e = 0; e < 5; ++e) {
      float4 q = *(const float4*)(base + (long long)e * N2);
      av[e][0] = q.x; av[e][1] = q.y; av[e][2] = q.z; av[e][3] = q.w;
    }
    bf16x4 ha0, ha1;
#pragma unroll
    for (int x = 0; x < 4; ++x) {
      float s0 = 0.f, s1 = 0.f, s2 = 0.f, s3 = 0.f, s4 = 0.f, s5 = 0.f;
#pragma unroll
      for (int e = 0; e < 5; ++e) {
        float u = av[e][x];
        s0 += f[0][0][e] * u; s1 += f[0][1][e] * u;
        s2 += f[1][0][e] * u; s3 += f[1][1][e] * u;
        s4 += f[2][0][e] * u; s5 += f[2][1][e] * u;
      }
      ha0[x] = (bf16_t)s0; cs0[x] += (float)ha0[x];
      ha1[x] = (bf16_t)s1; cs1[x] += (float)ha1[x];
      tl[0][lr][tc + x] = (bf16_t)s2; tl[1][lr][tc + x] = (bf16_t)s3;
      hb2a[v][x] = (bf16_t)s4; hb2b[v][x] = (bf16_t)s5;
    }
    *(bf16x4*)&Ha[0 * N2 + gi * NN + j0 + tc] = ha0;
    *(bf16x4*)&Ha[1 * N2 + gi * NN + j0 + tc] = ha1;
  }
#pragma unroll
  for (int x = 0; x < 4; ++x) { cs[0][tr][tc + x] = cs0[x]; cs[1][tr][tc + x] = cs1[x]; }
  __syncthreads();

#pragma unroll
  for (int v = 0; v < 4; ++v) {
    int lr = tr + v * 16;
#pragma unroll
    for (int ch = 0; ch < 2; ++ch) {
      bf16x4 o;
      o[0] = tl[ch][tc + 0][lr]; o[1] = tl[ch][tc + 1][lr];
      o[2] = tl[ch][tc + 2][lr]; o[3] = tl[ch][tc + 3][lr];
      *(bf16x4*)&HbT[(long long)ch * N2 + (long long)(j0 + lr) * NN + i0 + tc] = o;
    }
  }
  if (t < 128) {
    int ch = t >> 6, col = t & 63;
    float s = 0.f;
#pragma unroll
    for (int r = 0; r < 16; ++r) s += cs[ch][r][col];
    part[((long long)ch * 32 + blockIdx.x) * NN + j0 + col] = s;
  }
  __syncthreads();

#pragma unroll
  for (int v = 0; v < 4; ++v) {
    int lr = tr + v * 16;
#pragma unroll
    for (int x = 0; x < 4; ++x) {
      tl[0][lr][tc + x] = hb2a[v][x];
      tl[1][lr][tc + x] = hb2b[v][x];
    }
  }
  __syncthreads();

#pragma unroll
  for (int v = 0; v < 4; ++v) {
    int lr = tr + v * 16;
#pragma unroll
    for (int ch = 0; ch < 2; ++ch) {
      bf16x4 o;
      o[0] = tl[ch][tc + 0][lr]; o[1] = tl[ch][tc + 1][lr];
      o[2] = tl[ch][tc + 2][lr]; o[3] = tl[ch][tc + 3][lr];
      *(bf16x4*)&Hb2T[(long long)ch * N2 + (long long)(j0 + lr) * NN + i0 + tc] = o;
    }
  }
}

__global__ void k_s_finish(const float* __restrict__ part, float* __restrict__ s) {
  int idx = blockIdx.x * 256 + threadIdx.x;
  int c = idx >> 11, k = idx & 2047;
  float acc = 0.f;
#pragma unroll
  for (int ib = 0; ib < 32; ++ib) acc += part[((long long)c * 32 + ib) * NN + k];
  s[idx] = acc;
}

// deg[c][j] = sum_k (svec[k] - A[j,k])*BT[j,k];  Mdiag[c][j] = sum_k A[j,k]*BT[j,k]
template<bool EMIT_DIS>
__global__ void k_deg(const float* __restrict__ svec, const bf16_t* __restrict__ Arows,
                      const bf16_t* __restrict__ BT,
                      float* __restrict__ out1, float* __restrict__ out2,
                      float* __restrict__ out3) {
  int c = blockIdx.y;
  int j = blockIdx.x * 4 + (threadIdx.x >> 6);
  int lane = threadIdx.x & 63;
  const bf16_t* a = Arows + (long long)c * N2 + (long long)j * NN;
  const bf16_t* b = BT + (long long)c * N2 + (long long)j * NN;
  const float* s = svec + c * NN;
  float acc_s = 0.f, acc_a = 0.f;
#pragma unroll
  for (int it = 0; it < 4; ++it) {
    int k0 = (lane + it * 64) * 8;
    bf16x8 av = *(const bf16x8*)(a + k0);
    bf16x8 bv = *(const bf16x8*)(b + k0);
    float4 s0 = *(const float4*)(s + k0);
    float4 s1 = *(const float4*)(s + k0 + 4);
    float sv[8] = {s0.x, s0.y, s0.z, s0.w, s1.x, s1.y, s1.z, s1.w};
#pragma unroll
    for (int x = 0; x < 8; ++x) {
      float bx = (float)bv[x];
      acc_s += sv[x] * bx;
      acc_a += (float)av[x] * bx;
    }
  }
#pragma unroll
  for (int o = 32; o > 0; o >>= 1) {
    acc_s += __shfl_xor(acc_s, o, 64);
    acc_a += __shfl_xor(acc_a, o, 64);
  }
  if (lane == 0) {
    float deg = acc_s - acc_a;
    bool nz = (deg != 0.f);
    if (!EMIT_DIS) {
      out1[c * NN + j] = nz ? 1.f / deg : 0.f;
      out2[c * NN + j] = nz ? 1.f : 0.f;
    } else {
      float dis = nz ? 0.70710678118654752f : 1.f;
      out1[c * NN + j] = nz ? dis / deg : 0.f;     // cscal = dis/deg2
      out2[c * NN + j] = dis;                      // disv
      out3[c * NN + j] = acc_a;                    // Mdiag = diag(Hn@Hb2)
    }
  }
}

// XWdT[c][f][i] = XWT[f][i] * disv[c][i]
__global__ void k_scale_xwd(const bf16_t* __restrict__ XWT, const float* __restrict__ disv,
                            bf16_t* __restrict__ XWdT) {
  int i = blockIdx.x * 256 + threadIdx.x;
  int c = i >> 16, rem = i & 65535;
  bf16x8 v = ((const bf16x8*)XWT)[rem];
  int col0 = (rem & 255) * 8;
  float4 d0 = *(const float4*)(disv + c * NN + col0);
  float4 d1 = *(const float4*)(disv + c * NN + col0 + 4);
  bf16x8 o;
  o[0] = (bf16_t)((float)v[0] * d0.x); o[1] = (bf16_t)((float)v[1] * d0.y);
  o[2] = (bf16_t)((float)v[2] * d0.z); o[3] = (bf16_t)((float)v[3] * d0.w);
  o[4] = (bf16_t)((float)v[4] * d1.x); o[5] = (bf16_t)((float)v[5] * d1.y);
  o[6] = (bf16_t)((float)v[6] * d1.z); o[7] = (bf16_t)((float)v[7] * d1.w);
  ((bf16x8*)XWdT)[i] = o;
}

// ---------------- GEMM1 kernel: 128x128 tile, ring-3, counted vmcnt, swizzle, setprio ----------------
// C = A[2048,2048] @ B[2048,2048]^T per channel; epilogue: Hn (normalized bf16) + HnT (transposed).

__global__ __launch_bounds__(256)
void k_gemmL(const bf16_t* __restrict__ A, const bf16_t* __restrict__ B,
             bf16_t* __restrict__ Hn, bf16_t* __restrict__ HnT,
             const float* __restrict__ dinv) {
  // ring: As 3 x 8KB at 0, Bs 3 x 8KB at 24576; epilogue tile 128x130 bf16 (33.3KB) reuses base.
  __shared__ __align__(16) char smem[49152];
  bf16_t* As = (bf16_t*)smem;
  bf16_t* Bs = (bf16_t*)(smem + 24576);
  bf16_t* tile = (bf16_t*)smem;

  int cz = blockIdx.z;
  const bf16_t* Ab = A + cz * N2 + (long long)blockIdx.x * 128 * NN;
  const bf16_t* Bb = B + cz * N2 + (long long)blockIdx.y * 128 * NN;

  int t = threadIdx.x, wid = t >> 6, lane = t & 63;
  int wr = wid >> 1, wc = wid & 1;
  f32x4 acc[4][4] = {};
  int frow = lane & 15;
  int fk_sw = (((lane >> 4) ^ ((frow >> 1) & 3)) << 3);
  int srow = t >> 2;
  int scol_sw = (((t & 3) ^ ((t >> 3) & 3)) << 3);

  auto STAGE = [&](int TT, int BUF) {
    long long kko = (long long)TT * 32 + scol_sw;
    const bf16_t* ga0 = Ab + (long long)srow * NN + kko;
    const bf16_t* gb0 = Bb + (long long)srow * NN + kko;
    char* la = smem + BUF * 8192 + wid * 1024;
    char* lb = smem + 24576 + BUF * 8192 + wid * 1024;
    __builtin_amdgcn_global_load_lds((__attribute__((address_space(1))) void*)ga0,
        (__attribute__((address_space(3))) void*)la, 16, 0, 0);
    __builtin_amdgcn_global_load_lds((__attribute__((address_space(1))) void*)(ga0 + 64LL * NN),
        (__attribute__((address_space(3))) void*)(la + 4096), 16, 0, 0);
    __builtin_amdgcn_global_load_lds((__attribute__((address_space(1))) void*)gb0,
        (__attribute__((address_space(3))) void*)lb, 16, 0, 0);
    __builtin_amdgcn_global_load_lds((__attribute__((address_space(1))) void*)(gb0 + 64LL * NN),
        (__attribute__((address_space(3))) void*)(lb + 4096), 16, 0, 0);
  };
  auto COMPUTE = [&](int BUF) {
    bf16x8 af[4], bfr[4];
#pragma unroll
    for (int m = 0; m < 4; ++m)
      af[m] = *(const bf16x8*)&As[BUF * 4096 + (wr * 64 + m * 16 + frow) * 32 + fk_sw];
#pragma unroll
    for (int n = 0; n < 4; ++n)
      bfr[n] = *(const bf16x8*)&Bs[BUF * 4096 + (wc * 64 + n * 16 + frow) * 32 + fk_sw];
    __builtin_amdgcn_s_setprio(1);
#pragma unroll
    for (int m = 0; m < 4; ++m)
#pragma unroll
      for (int n = 0; n < 4; ++n)
        acc[m][n] = __builtin_amdgcn_mfma_f32_16x16x32_bf16(af[m], bfr[n], acc[m][n], 0, 0, 0);
    __builtin_amdgcn_s_setprio(0);
  };

  const int nt = 64;
  STAGE(0, 0); STAGE(1, 1); STAGE(2, 2);
  int slot = 0;
  for (int tt = 0; tt < nt; ++tt) {
    int rem = nt - 1 - tt;
    if (rem >= 2)      asm volatile("s_waitcnt vmcnt(8)" ::: "memory");
    else if (rem == 1) asm volatile("s_waitcnt vmcnt(4)" ::: "memory");
    else               asm volatile("s_waitcnt vmcnt(0)" ::: "memory");
    __builtin_amdgcn_s_barrier();
    __builtin_amdgcn_sched_barrier(0);
    COMPUTE(slot);
    __builtin_amdgcn_s_barrier();
    if (tt + 3 < nt) STAGE(tt + 3, slot);
    slot = (slot == 2) ? 0 : slot + 1;
  }
  __builtin_amdgcn_sched_barrier(0);

  int rl0 = wr * 64 + ((lane >> 4) << 2);
  int cl0 = wc * 64 + (lane & 15);
  int r0 = blockIdx.x * 128 + rl0;
  int c0 = blockIdx.y * 128 + cl0;

  bf16_t* Cb = Hn + cz * N2;
  bf16_t* Ct = HnT + cz * N2;
  float dj[4];
#pragma unroll
  for (int n = 0; n < 4; ++n) dj[n] = dinv[cz * NN + c0 + n * 16];
#pragma unroll
  for (int m = 0; m < 4; ++m)
#pragma unroll
    for (int n = 0; n < 4; ++n)
#pragma unroll
      for (int j = 0; j < 4; ++j) {
        int r = r0 + m * 16 + j, col = c0 + n * 16;
        float v = (r == col) ? 0.f : acc[m][n][j] * dj[n];
        Cb[(long long)r * NN + col] = (bf16_t)v;
        tile[(rl0 + m * 16 + j) * 130 + cl0 + n * 16] = (bf16_t)v;
      }
  __syncthreads();
  int nl = t >> 5, rl = (t & 31) * 4;
#pragma unroll
  for (int vv = 0; vv < 16; ++vv) {
    int n_l = nl + vv * 8;
    bf16x4 o;
    o[0] = tile[(rl + 0) * 130 + n_l]; o[1] = tile[(rl + 1) * 130 + n_l];
    o[2] = tile[(rl + 2) * 130 + n_l]; o[3] = tile[(rl + 3) * 130 + n_l];
    *(bf16x4*)&Ct[(long long)(blockIdx.y * 128 + n_l) * NN + blockIdx.x * 128 + rl] = o;
  }
}

// ---------------- bf16 GEMM, 128x64 tile, ring-3, counted vmcnt, swizzle, fused epilogues ----------------

enum { EP_F32 = 0, EP_BRELU = 3, EP_BF32 = 4, EP_XWT = 5, EP_BF16O = 7 };

template<int EP>
__global__ __launch_bounds__(256)
void k_gemm(const bf16_t* __restrict__ A, const bf16_t* __restrict__ B,
            void* __restrict__ Cv,
            const float* __restrict__ aux1, const float* __restrict__ aux2,
            bf16_t* __restrict__ aux3,
            int N, int K, int lda, int ldb,
            long long zA, long long zB, long long zC) {
  __shared__ __align__(16) char smem[36864];
  bf16_t* As = (bf16_t*)smem;
  bf16_t* Bs = (bf16_t*)(smem + 24576);
  bf16_t* tile = (bf16_t*)smem;

  int cz = blockIdx.z;
  const bf16_t* Ab = A + cz * zA + (long long)blockIdx.x * 128 * lda;
  const bf16_t* Bb = B + cz * zB + (long long)blockIdx.y * 64 * ldb;

  int t = threadIdx.x, wid = t >> 6, lane = t & 63;
  int wr = wid >> 1, wc = wid & 1;
  f32x4 acc[4][2] = {};
  int frow = lane & 15;
  int fk_sw = (((lane >> 4) ^ ((frow >> 1) & 3)) << 3);
  int srow = t >> 2;
  int scol_sw = (((t & 3) ^ ((t >> 3) & 3)) << 3);
  int nt = K >> 5;

  auto STAGE = [&](int TT, int BUF) {
    long long kko = (long long)TT * 32 + scol_sw;
    const bf16_t* ga0 = Ab + (long long)srow * lda + kko;
    const bf16_t* ga1 = Ab + (long long)(64 + srow) * lda + kko;
    const bf16_t* gb0 = Bb + (long long)srow * ldb + kko;
    char* la = smem + BUF * 8192 + wid * 1024;
    char* lb = smem + 24576 + BUF * 4096 + wid * 1024;
    __builtin_amdgcn_global_load_lds((__attribute__((address_space(1))) void*)ga0,
        (__attribute__((address_space(3))) void*)la, 16, 0, 0);
    __builtin_amdgcn_global_load_lds((__attribute__((address_space(1))) void*)ga1,
        (__attribute__((address_space(3))) void*)(la + 4096), 16, 0, 0);
    __builtin_amdgcn_global_load_lds((__attribute__((address_space(1))) void*)gb0,
        (__attribute__((address_space(3))) void*)lb, 16, 0, 0);
  };
  auto COMPUTE = [&](int BUF) {
    bf16x8 af[4], bfr[2];
#pragma unroll
    for (int m = 0; m < 4; ++m)
      af[m] = *(const bf16x8*)&As[BUF * 4096 + (wr * 64 + m * 16 + frow) * 32 + fk_sw];
#pragma unroll
    for (int n = 0; n < 2; ++n)
      bfr[n] = *(const bf16x8*)&Bs[BUF * 2048 + (wc * 32 + n * 16 + frow) * 32 + fk_sw];
#pragma unroll
    for (int m = 0; m < 4; ++m)
#pragma unroll
      for (int n = 0; n < 2; ++n)
        acc[m][n] = __builtin_amdgcn_mfma_f32_16x16x32_bf16(af[m], bfr[n], acc[m][n], 0, 0, 0);
  };

  STAGE(0, 0); STAGE(1, 1); STAGE(2, 2);
  int slot = 0;
  for (int tt = 0; tt < nt; ++tt) {
    int rem = nt - 1 - tt;
    if (rem >= 2)      asm volatile("s_waitcnt vmcnt(6)" ::: "memory");
    else if (rem == 1) asm volatile("s_waitcnt vmcnt(3)" ::: "memory");
    else               asm volatile("s_waitcnt vmcnt(0)" ::: "memory");
    __builtin_amdgcn_s_barrier();
    __builtin_amdgcn_sched_barrier(0);
    COMPUTE(slot);
    __builtin_amdgcn_s_barrier();
    if (tt + 3 < nt) STAGE(tt + 3, slot);
    slot = (slot == 2) ? 0 : slot + 1;
  }
  __builtin_amdgcn_sched_barrier(0);

  int rl0 = wr * 64 + ((lane >> 4) << 2);
  int cl0 = wc * 32 + (lane & 15);
  int r0 = blockIdx.x * 128 + rl0;
  int c0 = blockIdx.y * 64 + cl0;

  if constexpr (EP == EP_F32) {
    float* Cb = (float*)Cv + cz * zC;
#pragma unroll
    for (int m = 0; m < 4; ++m)
#pragma unroll
      for (int n = 0; n < 2; ++n)
#pragma unroll
        for (int j = 0; j < 4; ++j)
          Cb[(long long)(r0 + m * 16 + j) * N + c0 + n * 16] = acc[m][n][j];
  } else if constexpr (EP == EP_BF16O) {
    bf16_t* Cb = (bf16_t*)Cv + cz * zC;
#pragma unroll
    for (int m = 0; m < 4; ++m)
#pragma unroll
      for (int n = 0; n < 2; ++n)
#pragma unroll
        for (int j = 0; j < 4; ++j)
          Cb[(long long)(r0 + m * 16 + j) * N + c0 + n * 16] = (bf16_t)acc[m][n][j];
  } else if constexpr (EP == EP_XWT) {
    float* Cb = (float*)Cv;
#pragma unroll
    for (int m = 0; m < 4; ++m)
#pragma unroll
      for (int n = 0; n < 2; ++n)
#pragma unroll
        for (int j = 0; j < 4; ++j) {
          float v = acc[m][n][j];
          Cb[(long long)(r0 + m * 16 + j) * N + c0 + n * 16] = v;
          tile[(rl0 + m * 16 + j) * 65 + cl0 + n * 16] = (bf16_t)v;
        }
    __syncthreads();
    int nl = t >> 5, rl = (t & 31) * 4;
#pragma unroll
    for (int vv = 0; vv < 8; ++vv) {
      int n_l = nl + vv * 8;
      bf16x4 o;
      o[0] = tile[(rl + 0) * 65 + n_l]; o[1] = tile[(rl + 1) * 65 + n_l];
      o[2] = tile[(rl + 2) * 65 + n_l]; o[3] = tile[(rl + 3) * 65 + n_l];
      *(bf16x4*)&aux3[(long long)(blockIdx.y * 64 + n_l) * NN + blockIdx.x * 128 + rl] = o;
    }
  } else if constexpr (EP == EP_BRELU) {
    bf16_t* Cb = (bf16_t*)Cv;
    float bj[2];
#pragma unroll
    for (int n = 0; n < 2; ++n) bj[n] = aux1[c0 + n * 16];
#pragma unroll
    for (int m = 0; m < 4; ++m)
#pragma unroll
      for (int n = 0; n < 2; ++n)
#pragma unroll
        for (int j = 0; j < 4; ++j)
          Cb[(long long)(r0 + m * 16 + j) * N + c0 + n * 16] =
              (bf16_t)fmaxf(acc[m][n][j] + bj[n], 0.f);
  } else { // EP_BF32
    float* Cb = (float*)Cv;
    float bj[2];
#pragma unroll
    for (int n = 0; n < 2; ++n) bj[n] = aux1[c0 + n * 16];
#pragma unroll
    for (int m = 0; m < 4; ++m)
#pragma unroll
      for (int n = 0; n < 2; ++n)
#pragma unroll
        for (int j = 0; j < 4; ++j)
          Cb[(long long)(r0 + m * 16 + j) * N + c0 + n * 16] = acc[m][n][j] + bj[n];
  }
}

// ---------------- GCN epilogue: out = relu(cscal*(Z - Mdiag*dis*XW) + dis^2*XW + b) ----------------

__global__ void k_gcn_epi2(const float* __restrict__ Z, const float* __restrict__ XW,
                           const float* __restrict__ gcn_b, const float* __restrict__ cscal,
                           const float* __restrict__ disv, const float* __restrict__ Mdiag,
                           bf16_t* __restrict__ Xcat) {
  long long idx4 = ((long long)blockIdx.x * 256 + threadIdx.x) * 4;
  int c = (int)(idx4 >> 19);
  int rem = (int)(idx4 & ((1 << 19) - 1));
  int n = rem >> 8, fcol = rem & 255;
  float4 z  = *(const float4*)(Z + (long long)c * NN * WOUT + rem);
  float4 xw = *(const float4*)(XW + rem);
  float4 b  = *(const float4*)(gcn_b + fcol);
  float cs = cscal[c * NN + n], dn = disv[c * NN + n], md = Mdiag[c * NN + n];
  float d2 = dn * dn, mdd = md * dn;
  bf16x4 o;
  o[0] = (bf16_t)fmaxf(cs * (z.x - mdd * xw.x) + d2 * xw.x + b.x, 0.f);
  o[1] = (bf16_t)fmaxf(cs * (z.y - mdd * xw.y) + d2 * xw.y + b.y, 0.f);
  o[2] = (bf16_t)fmaxf(cs * (z.z - mdd * xw.z) + d2 * xw.z + b.z, 0.f);
  o[3] = (bf16_t)fmaxf(cs * (z.w - mdd * xw.w) + d2 * xw.w + b.w, 0.f);
  *(bf16x4*)&Xcat[(long long)n * (CC * WOUT) + c * WOUT + fcol] = o;
}

// ---------------- launch ----------------

extern "C" void kernel_launch(void* const* d_in, const int* in_sizes, int n_in,
                              void* d_out, int out_size, void* d_ws, size_t ws_size,
                              hipStream_t stream) {
  const float* A    = (const float*)d_in[0];
  const float* X    = (const float*)d_in[1];
  const float* w0a  = (const float*)d_in[2];
  const float* w0b  = (const float*)d_in[3];
  const float* w1   = (const float*)d_in[4];
  const float* gcnw = (const float*)d_in[5];
  const float* gcnb = (const float*)d_in[6];
  const float* l1w  = (const float*)d_in[7];
  const float* l1b  = (const float*)d_in[8];
  const float* l2w  = (const float*)d_in[9];
  const float* l2b  = (const float*)d_in[10];
  float* out = (float*)d_out;

  char* p = (char*)d_ws;
  auto carve = [&](size_t bytes) -> char* {
    char* r = p; p += (bytes + 255) & ~(size_t)255; return r;
  };
  float*  svec  = (float*)carve((size_t)CC * NN * 4);
  float*  dinv1 = (float*)carve((size_t)CC * NN * 4);
  float*  m1    = (float*)carve((size_t)CC * NN * 4);
  float*  cscal = (float*)carve((size_t)CC * NN * 4);
  float*  disv  = (float*)carve((size_t)CC * NN * 4);
  float*  Mdiag = (float*)carve((size_t)CC * NN * 4);
  float*  part  = (float*)carve((size_t)CC * 32 * NN * 4);
  bf16_t* S1    = (bf16_t*)carve((size_t)CC * N2 * 2); // Ha -> {XWdT, Yt, Z}
  bf16_t* HbT   = (bf16_t*)carve((size_t)CC * N2 * 2);
  bf16_t* Hb2T  = (bf16_t*)carve((size_t)CC * N2 * 2);
  bf16_t* Hn    = (bf16_t*)carve((size_t)CC * N2 * 2);
  bf16_t* HnT   = (bf16_t*)carve((size_t)CC * N2 * 2);
  bf16_t* Xb    = (bf16_t*)carve((size_t)NN * WIN * 2);
  bf16_t* gwT   = (bf16_t*)carve((size_t)WOUT * WIN * 2);
  bf16_t* l1wb  = (bf16_t*)carve((size_t)WOUT * CC * WOUT * 2);
  bf16_t* l2wb  = (bf16_t*)carve((size_t)WOUT * WOUT * 2);
  float*  XW    = (float*)carve((size_t)NN * WOUT * 4);
  bf16_t* XWT   = (bf16_t*)carve((size_t)WOUT * NN * 2);
  bf16_t* Xcat  = (bf16_t*)carve((size_t)NN * CC * WOUT * 2);
  bf16_t* hb    = (bf16_t*)carve((size_t)NN * WOUT * 2);

  bf16_t* Ha = S1;
  bf16_t* XWdT = (bf16_t*)((char*)S1);
  bf16_t* Yt   = (bf16_t*)((char*)S1 + (2LL << 20));
  float*  Z    = (float*) ((char*)S1 + (6LL << 20));

  // prep
  k_prep<<<640, 256, 0, stream>>>(X, l1w, l2w, gcnw, Xb, l1wb, l2wb, gwT);
  k_combine<<<dim3(32, 32), 256, 0, stream>>>(A, w0a, w0b, w1, Ha, HbT, Hb2T, part);
  k_s_finish<<<16, 256, 0, stream>>>(part, svec);

  // layer 0: analytic degrees; GEMM1 (128^2 tile) with fused normalize, writes Hn AND HnT
  k_deg<false><<<dim3(512, 2), 256, 0, stream>>>(svec, Ha, HbT, dinv1, m1, nullptr);
  k_gemmL<<<dim3(16, 16, 2), 256, 0, stream>>>(Ha, HbT, Hn, HnT, dinv1);

  // layer 1 scalars: deg2 (-> cscal, disv) and Mdiag from one row-dot pass
  k_deg<true><<<dim3(512, 2), 256, 0, stream>>>(m1, Hn, Hb2T, cscal, disv, Mdiag);

  // GCN via associativity
  k_gemm<EP_XWT><<<dim3(16, 4, 1), 256, 0, stream>>>(
      Xb, gwT, XW, nullptr, nullptr, XWT, WOUT, WIN, WIN, WIN, 0, 0, 0);
  k_scale_xwd<<<512, 256, 0, stream>>>(XWT, disv, XWdT);
  k_gemm<EP_BF16O><<<dim3(2, 32, 2), 256, 0, stream>>>(
      XWdT, HnT, Yt, nullptr, nullptr, nullptr, NN, NN, NN, NN,
      (long long)WOUT * NN, N2, (long long)WOUT * NN);
  k_gemm<EP_F32><<<dim3(16, 4, 2), 256, 0, stream>>>(
      Hb2T, Yt, Z, nullptr, nullptr, nullptr, WOUT, NN, NN, NN,
      N2, (long long)WOUT * NN, (long long)NN * WOUT);
  k_gcn_epi2<<<1024, 256, 0, stream>>>(Z, XW, gcnb, cscal, disv, Mdiag, Xcat);

  // MLP with fused bias(+relu)
  k_gemm<EP_BRELU><<<dim3(16, 4, 1), 256, 0, stream>>>(
      Xcat, l1wb, hb, l1b, nullptr, nullptr, WOUT, CC * WOUT, CC * WOUT, CC * WOUT, 0, 0, 0);
  k_gemm<EP_BF32><<<dim3(16, 4, 1), 256, 0, stream>>>(
      hb, l2wb, out, l2b, nullptr, nullptr, WOUT, WOUT, WOUT, WOUT, 0, 0, 0);
}

// Round 8
// 149.900 us; speedup vs baseline: 1.9633x; 1.0191x over previous
//
#include <hip/hip_runtime.h>
#include <cstdint>
#include <cstddef>

#define NN   2048
#define N2   (2048LL*2048LL)
#define CC   2
#define EE   5
#define WIN  512
#define WOUT 256

typedef __bf16 bf16_t;
typedef __attribute__((ext_vector_type(8))) __bf16 bf16x8;
typedef __attribute__((ext_vector_type(4))) __bf16 bf16x4;
typedef __attribute__((ext_vector_type(4))) float  f32x4;

// ---------------- prep: bf16 casts + gcn_w transpose-cast, one launch ----------------
__global__ void k_prep(const float* __restrict__ X, const float* __restrict__ l1w,
                       const float* __restrict__ l2w, const float* __restrict__ gcnw,
                       bf16_t* __restrict__ Xb, bf16_t* __restrict__ l1wb,
                       bf16_t* __restrict__ l2wb, bf16_t* __restrict__ gwT) {
  __shared__ bf16_t tile[64][65];
  int bid = blockIdx.x;
  if (bid < 608) {
    int i = bid * 256 + threadIdx.x;
    const float* src; bf16_t* dst; int off;
    if (i < 131072)      { src = X;   dst = Xb;   off = i; }
    else if (i < 147456) { src = l1w; dst = l1wb; off = i - 131072; }
    else if (i < 155648) { src = l2w; dst = l2wb; off = i - 147456; }
    else return;
    float4 a = ((const float4*)src)[off * 2];
    float4 b = ((const float4*)src)[off * 2 + 1];
    bf16x8 o;
    o[0] = (bf16_t)a.x; o[1] = (bf16_t)a.y; o[2] = (bf16_t)a.z; o[3] = (bf16_t)a.w;
    o[4] = (bf16_t)b.x; o[5] = (bf16_t)b.y; o[6] = (bf16_t)b.z; o[7] = (bf16_t)b.w;
    ((bf16x8*)dst)[off] = o;
  } else {
    int b2 = bid - 608;              // 0..31
    int m0 = (b2 & 7) * 64, n0 = (b2 >> 3) * 64;
    int t = threadIdx.x, tr = t >> 4, tc = (t & 15) << 2;
#pragma unroll
    for (int v = 0; v < 4; ++v) {
      int r = tr + v * 16;
      float4 d = *(const float4*)&gcnw[(long long)(m0 + r) * WOUT + n0 + tc];
      tile[r][tc + 0] = (bf16_t)d.x; tile[r][tc + 1] = (bf16_t)d.y;
      tile[r][tc + 2] = (bf16_t)d.z; tile[r][tc + 3] = (bf16_t)d.w;
    }
    __syncthreads();
#pragma unroll
    for (int v = 0; v < 4; ++v) {
      int r = tr + v * 16;
      bf16x4 o;
      o[0] = tile[tc + 0][r]; o[1] = tile[tc + 1][r];
      o[2] = tile[tc + 2][r]; o[3] = tile[tc + 3][r];
      *(bf16x4*)&gwT[(long long)(n0 + r) * WIN + m0 + tc] = o;
    }
  }
}

// ---------------- combine: single A pass; Hb via LDS, Hb2 carried in registers ----------------

__global__ void k_combine(const float* __restrict__ A,
                          const float* __restrict__ w0a, const float* __restrict__ w0b,
                          const float* __restrict__ w1,
                          bf16_t* __restrict__ Ha, bf16_t* __restrict__ HbT,
                          bf16_t* __restrict__ Hb2T, float* __restrict__ part) {
  __shared__ bf16_t tl[2][64][65];
  __shared__ float cs[2][16][64];
  float f[3][2][5];
  {
    const float* wp[3] = {w0a, w0b, w1};
#pragma unroll
    for (int w = 0; w < 3; ++w)
#pragma unroll
      for (int c = 0; c < 2; ++c) {
        float x[5], m = -1e30f, s = 0.f;
#pragma unroll
        for (int e = 0; e < 5; ++e) { x[e] = wp[w][c * 5 + e]; m = fmaxf(m, x[e]); }
#pragma unroll
        for (int e = 0; e < 5; ++e) { x[e] = expf(x[e] - m); s += x[e]; }
#pragma unroll
        for (int e = 0; e < 5; ++e) f[w][c][e] = x[e] / s;
      }
  }
  int i0 = blockIdx.x * 64, j0 = blockIdx.y * 64;
  int t = threadIdx.x, tr = t >> 4, tc = (t & 15) << 2;
  float cs0[4] = {0, 0, 0, 0}, cs1[4] = {0, 0, 0, 0};
  bf16x4 hb2a[4], hb2b[4];

#pragma unroll
  for (int v = 0; v < 4; ++v) {
    int lr = tr + v * 16;
    long long gi = i0 + lr;
    const float* base = A + gi * (long long)NN + j0 + tc;
    float av[5][4];
#pragma unroll
    for (int e = 0; e < 5; ++e) {
      float4 q = *(const float4*)(base + (long long)e * N2);
      av[e][0] = q.x; av[e][1] = q.y; av[e][2] = q.z; av[e][3] = q.w;
    }
    bf16x4 ha0, ha1;
#pragma unroll
    for (int x = 0; x < 4; ++x) {
      float s0 = 0.f, s1 = 0.f, s2 = 0.f, s3 = 0.f, s4 = 0.f, s5 = 0.f;
#pragma unroll
      for (int e = 0; e < 5; ++e) {
        float u = av[e][x];
        s0 += f[0][0][e] * u; s1 += f[0][1][e] * u;
        s2 += f[1][0][e] * u; s3 += f[1][1][e] * u;
        s4 += f[2][0][e] * u; s5 += f[2][1][e] * u;
      }
      ha0[x] = (bf16_t)s0; cs0[x] += (float)ha0[x];
      ha1[x] = (bf16_t)s1; cs1[x] += (float)ha1[x];
      tl[0][lr][tc + x] = (bf16_t)s2; tl[1][lr][tc + x] = (bf16_t)s3;
      hb2a[v][x] = (bf16_t)s4; hb2b[v][x] = (bf16_t)s5;
    }
    *(bf16x4*)&Ha[0 * N2 + gi * NN + j0 + tc] = ha0;
    *(bf16x4*)&Ha[1 * N2 + gi * NN + j0 + tc] = ha1;
  }
#pragma unroll
  for (int x = 0; x < 4; ++x) { cs[0][tr][tc + x] = cs0[x]; cs[1][tr][tc + x] = cs1[x]; }
  __syncthreads();

#pragma unroll
  for (int v = 0; v < 4; ++v) {
    int lr = tr + v * 16;
#pragma unroll
    for (int ch = 0; ch < 2; ++ch) {
      bf16x4 o;
      o[0] = tl[ch][tc + 0][lr]; o[1] = tl[ch][tc + 1][lr];
      o[2] = tl[ch][tc + 2][lr]; o[3] = tl[ch][tc + 3][lr];
      *(bf16x4*)&HbT[(long long)ch * N2 + (long long)(j0 + lr) * NN + i0 + tc] = o;
    }
  }
  if (t < 128) {
    int ch = t >> 6, col = t & 63;
    float s = 0.f;
#pragma unroll
    for (int r = 0; r < 16; ++r) s += cs[ch][r][col];
    part[((long long)ch * 32 + blockIdx.x) * NN + j0 + col] = s;
  }
  __syncthreads();

#pragma unroll
  for (int v = 0; v < 4; ++v) {
    int lr = tr + v * 16;
#pragma unroll
    for (int x = 0; x < 4; ++x) {
      tl[0][lr][tc + x] = hb2a[v][x];
      tl[1][lr][tc + x] = hb2b[v][x];
    }
  }
  __syncthreads();

#pragma unroll
  for (int v = 0; v < 4; ++v) {
    int lr = tr + v * 16;
#pragma unroll
    for (int ch = 0; ch < 2; ++ch) {
      bf16x4 o;
      o[0] = tl[ch][tc + 0][lr]; o[1] = tl[ch][tc + 1][lr];
      o[2] = tl[ch][tc + 2][lr]; o[3] = tl[ch][tc + 3][lr];
      *(bf16x4*)&Hb2T[(long long)ch * N2 + (long long)(j0 + lr) * NN + i0 + tc] = o;
    }
  }
}

__global__ void k_s_finish(const float* __restrict__ part, float* __restrict__ s) {
  int idx = blockIdx.x * 256 + threadIdx.x;
  int c = idx >> 11, k = idx & 2047;
  float acc = 0.f;
#pragma unroll
  for (int ib = 0; ib < 32; ++ib) acc += part[((long long)c * 32 + ib) * NN + k];
  s[idx] = acc;
}

// deg[c][j] = sum_k (svec[k] - A[j,k])*BT[j,k];  Mdiag[c][j] = sum_k A[j,k]*BT[j,k]
template<bool EMIT_DIS>
__global__ void k_deg(const float* __restrict__ svec, const bf16_t* __restrict__ Arows,
                      const bf16_t* __restrict__ BT,
                      float* __restrict__ out1, float* __restrict__ out2,
                      float* __restrict__ out3) {
  int c = blockIdx.y;
  int j = blockIdx.x * 4 + (threadIdx.x >> 6);
  int lane = threadIdx.x & 63;
  const bf16_t* a = Arows + (long long)c * N2 + (long long)j * NN;
  const bf16_t* b = BT + (long long)c * N2 + (long long)j * NN;
  const float* s = svec + c * NN;
  float acc_s = 0.f, acc_a = 0.f;
#pragma unroll
  for (int it = 0; it < 4; ++it) {
    int k0 = (lane + it * 64) * 8;
    bf16x8 av = *(const bf16x8*)(a + k0);
    bf16x8 bv = *(const bf16x8*)(b + k0);
    float4 s0 = *(const float4*)(s + k0);
    float4 s1 = *(const float4*)(s + k0 + 4);
    float sv[8] = {s0.x, s0.y, s0.z, s0.w, s1.x, s1.y, s1.z, s1.w};
#pragma unroll
    for (int x = 0; x < 8; ++x) {
      float bx = (float)bv[x];
      acc_s += sv[x] * bx;
      acc_a += (float)av[x] * bx;
    }
  }
#pragma unroll
  for (int o = 32; o > 0; o >>= 1) {
    acc_s += __shfl_xor(acc_s, o, 64);
    acc_a += __shfl_xor(acc_a, o, 64);
  }
  if (lane == 0) {
    float deg = acc_s - acc_a;
    bool nz = (deg != 0.f);
    if (!EMIT_DIS) {
      out1[c * NN + j] = nz ? 1.f / deg : 0.f;
      out2[c * NN + j] = nz ? 1.f : 0.f;
    } else {
      float dis = nz ? 0.70710678118654752f : 1.f;
      out1[c * NN + j] = nz ? dis / deg : 0.f;     // cscal = dis/deg2
      out2[c * NN + j] = dis;                      // disv
      out3[c * NN + j] = acc_a;                    // Mdiag = diag(Hn@Hb2)
    }
  }
}

// XWdT[c][f][i] = XWT[f][i] * disv[c][i]
__global__ void k_scale_xwd(const bf16_t* __restrict__ XWT, const float* __restrict__ disv,
                            bf16_t* __restrict__ XWdT) {
  int i = blockIdx.x * 256 + threadIdx.x;
  int c = i >> 16, rem = i & 65535;
  bf16x8 v = ((const bf16x8*)XWT)[rem];
  int col0 = (rem & 255) * 8;
  float4 d0 = *(const float4*)(disv + c * NN + col0);
  float4 d1 = *(const float4*)(disv + c * NN + col0 + 4);
  bf16x8 o;
  o[0] = (bf16_t)((float)v[0] * d0.x); o[1] = (bf16_t)((float)v[1] * d0.y);
  o[2] = (bf16_t)((float)v[2] * d0.z); o[3] = (bf16_t)((float)v[3] * d0.w);
  o[4] = (bf16_t)((float)v[4] * d1.x); o[5] = (bf16_t)((float)v[5] * d1.y);
  o[6] = (bf16_t)((float)v[6] * d1.z); o[7] = (bf16_t)((float)v[7] * d1.w);
  ((bf16x8*)XWdT)[i] = o;
}

// ---------------- GEMM1: 128x128 tile, BK=64 slots (2x BK32 sub-tiles), ring-2 ----------------
// 32 MFMA per barrier pair, counted vmcnt, chunk-XOR swizzle, setprio.

__global__ __launch_bounds__(256)
void k_gemmL(const bf16_t* __restrict__ A, const bf16_t* __restrict__ B,
             bf16_t* __restrict__ Hn, bf16_t* __restrict__ HnT,
             const float* __restrict__ dinv) {
  // As: 2 slots x 16KB at 0; Bs: 2 slots x 16KB at 32768. Slot = 2 BK32 sub-tiles (8KB each).
  // Epilogue transpose tile (128x130 bf16 = 33.3KB) reuses base after final barrier.
  __shared__ __align__(16) char smem[65536];
  bf16_t* As = (bf16_t*)smem;
  bf16_t* Bs = (bf16_t*)(smem + 32768);
  bf16_t* tile = (bf16_t*)smem;

  int cz = blockIdx.z;
  const bf16_t* Ab = A + cz * N2 + (long long)blockIdx.x * 128 * NN;
  const bf16_t* Bb = B + cz * N2 + (long long)blockIdx.y * 128 * NN;

  int t = threadIdx.x, wid = t >> 6, lane = t & 63;
  int wr = wid >> 1, wc = wid & 1;
  f32x4 acc[4][4] = {};
  int frow = lane & 15;
  int fk_sw = (((lane >> 4) ^ ((frow >> 1) & 3)) << 3);
  int srow = t >> 2;
  int scol_sw = (((t & 3) ^ ((t >> 3) & 3)) << 3);

  auto STAGE = [&](int TT, int BUF) {
#pragma unroll
    for (int s = 0; s < 2; ++s) {
      long long kko = (long long)TT * 64 + s * 32 + scol_sw;
      const bf16_t* ga0 = Ab + (long long)srow * NN + kko;
      const bf16_t* gb0 = Bb + (long long)srow * NN + kko;
      char* la = smem + BUF * 16384 + s * 8192 + wid * 1024;
      char* lb = smem + 32768 + BUF * 16384 + s * 8192 + wid * 1024;
      __builtin_amdgcn_global_load_lds((__attribute__((address_space(1))) void*)ga0,
          (__attribute__((address_space(3))) void*)la, 16, 0, 0);
      __builtin_amdgcn_global_load_lds((__attribute__((address_space(1))) void*)(ga0 + 64LL * NN),
          (__attribute__((address_space(3))) void*)(la + 4096), 16, 0, 0);
      __builtin_amdgcn_global_load_lds((__attribute__((address_space(1))) void*)gb0,
          (__attribute__((address_space(3))) void*)lb, 16, 0, 0);
      __builtin_amdgcn_global_load_lds((__attribute__((address_space(1))) void*)(gb0 + 64LL * NN),
          (__attribute__((address_space(3))) void*)(lb + 4096), 16, 0, 0);
    }
  };
  auto COMPUTE = [&](int BUF) {
#pragma unroll
    for (int ks = 0; ks < 2; ++ks) {
      bf16x8 af[4], bfr[4];
#pragma unroll
      for (int m = 0; m < 4; ++m)
        af[m] = *(const bf16x8*)&As[BUF * 8192 + ks * 4096 + (wr * 64 + m * 16 + frow) * 32 + fk_sw];
#pragma unroll
      for (int n = 0; n < 4; ++n)
        bfr[n] = *(const bf16x8*)&Bs[BUF * 8192 + ks * 4096 + (wc * 64 + n * 16 + frow) * 32 + fk_sw];
      __builtin_amdgcn_s_setprio(1);
#pragma unroll
      for (int m = 0; m < 4; ++m)
#pragma unroll
        for (int n = 0; n < 4; ++n)
          acc[m][n] = __builtin_amdgcn_mfma_f32_16x16x32_bf16(af[m], bfr[n], acc[m][n], 0, 0, 0);
      __builtin_amdgcn_s_setprio(0);
    }
  };

  const int nt = 32;  // K/64
  STAGE(0, 0); STAGE(1, 1);
  for (int tt = 0; tt < nt; ++tt) {
    if (tt < nt - 1) asm volatile("s_waitcnt vmcnt(8)" ::: "memory");
    else             asm volatile("s_waitcnt vmcnt(0)" ::: "memory");
    __builtin_amdgcn_s_barrier();
    __builtin_amdgcn_sched_barrier(0);
    COMPUTE(tt & 1);
    __builtin_amdgcn_s_barrier();
    if (tt + 2 < nt) STAGE(tt + 2, tt & 1);
  }
  __builtin_amdgcn_sched_barrier(0);

  int rl0 = wr * 64 + ((lane >> 4) << 2);
  int cl0 = wc * 64 + (lane & 15);
  int r0 = blockIdx.x * 128 + rl0;
  int c0 = blockIdx.y * 128 + cl0;

  bf16_t* Cb = Hn + cz * N2;
  bf16_t* Ct = HnT + cz * N2;
  float dj[4];
#pragma unroll
  for (int n = 0; n < 4; ++n) dj[n] = dinv[cz * NN + c0 + n * 16];
#pragma unroll
  for (int m = 0; m < 4; ++m)
#pragma unroll
    for (int n = 0; n < 4; ++n)
#pragma unroll
      for (int j = 0; j < 4; ++j) {
        int r = r0 + m * 16 + j, col = c0 + n * 16;
        float v = (r == col) ? 0.f : acc[m][n][j] * dj[n];
        Cb[(long long)r * NN + col] = (bf16_t)v;
        tile[(rl0 + m * 16 + j) * 130 + cl0 + n * 16] = (bf16_t)v;
      }
  __syncthreads();
  int nl = t >> 5, rl = (t & 31) * 4;
#pragma unroll
  for (int vv = 0; vv < 16; ++vv) {
    int n_l = nl + vv * 8;
    bf16x4 o;
    o[0] = tile[(rl + 0) * 130 + n_l]; o[1] = tile[(rl + 1) * 130 + n_l];
    o[2] = tile[(rl + 2) * 130 + n_l]; o[3] = tile[(rl + 3) * 130 + n_l];
    *(bf16x4*)&Ct[(long long)(blockIdx.y * 128 + n_l) * NN + blockIdx.x * 128 + rl] = o;
  }
}

// ---------------- bf16 GEMM, 128x64 tile, ring-3, counted vmcnt, swizzle, fused epilogues ----------------

enum { EP_F32 = 0, EP_BRELU = 3, EP_BF32 = 4, EP_XWT = 5, EP_BF16O = 7 };

template<int EP>
__global__ __launch_bounds__(256)
void k_gemm(const bf16_t* __restrict__ A, const bf16_t* __restrict__ B,
            void* __restrict__ Cv,
            const float* __restrict__ aux1, const float* __restrict__ aux2,
            bf16_t* __restrict__ aux3,
            int N, int K, int lda, int ldb,
            long long zA, long long zB, long long zC) {
  __shared__ __align__(16) char smem[36864];
  bf16_t* As = (bf16_t*)smem;
  bf16_t* Bs = (bf16_t*)(smem + 24576);
  bf16_t* tile = (bf16_t*)smem;

  int cz = blockIdx.z;
  const bf16_t* Ab = A + cz * zA + (long long)blockIdx.x * 128 * lda;
  const bf16_t* Bb = B + cz * zB + (long long)blockIdx.y * 64 * ldb;

  int t = threadIdx.x, wid = t >> 6, lane = t & 63;
  int wr = wid >> 1, wc = wid & 1;
  f32x4 acc[4][2] = {};
  int frow = lane & 15;
  int fk_sw = (((lane >> 4) ^ ((frow >> 1) & 3)) << 3);
  int srow = t >> 2;
  int scol_sw = (((t & 3) ^ ((t >> 3) & 3)) << 3);
  int nt = K >> 5;

  auto STAGE = [&](int TT, int BUF) {
    long long kko = (long long)TT * 32 + scol_sw;
    const bf16_t* ga0 = Ab + (long long)srow * lda + kko;
    const bf16_t* ga1 = Ab + (long long)(64 + srow) * lda + kko;
    const bf16_t* gb0 = Bb + (long long)srow * ldb + kko;
    char* la = smem + BUF * 8192 + wid * 1024;
    char* lb = smem + 24576 + BUF * 4096 + wid * 1024;
    __builtin_amdgcn_global_load_lds((__attribute__((address_space(1))) void*)ga0,
        (__attribute__((address_space(3))) void*)la, 16, 0, 0);
    __builtin_amdgcn_global_load_lds((__attribute__((address_space(1))) void*)ga1,
        (__attribute__((address_space(3))) void*)(la + 4096), 16, 0, 0);
    __builtin_amdgcn_global_load_lds((__attribute__((address_space(1))) void*)gb0,
        (__attribute__((address_space(3))) void*)lb, 16, 0, 0);
  };
  auto COMPUTE = [&](int BUF) {
    bf16x8 af[4], bfr[2];
#pragma unroll
    for (int m = 0; m < 4; ++m)
      af[m] = *(const bf16x8*)&As[BUF * 4096 + (wr * 64 + m * 16 + frow) * 32 + fk_sw];
#pragma unroll
    for (int n = 0; n < 2; ++n)
      bfr[n] = *(const bf16x8*)&Bs[BUF * 2048 + (wc * 32 + n * 16 + frow) * 32 + fk_sw];
#pragma unroll
    for (int m = 0; m < 4; ++m)
#pragma unroll
      for (int n = 0; n < 2; ++n)
        acc[m][n] = __builtin_amdgcn_mfma_f32_16x16x32_bf16(af[m], bfr[n], acc[m][n], 0, 0, 0);
  };

  STAGE(0, 0); STAGE(1, 1); STAGE(2, 2);
  int slot = 0;
  for (int tt = 0; tt < nt; ++tt) {
    int rem = nt - 1 - tt;
    if (rem >= 2)      asm volatile("s_waitcnt vmcnt(6)" ::: "memory");
    else if (rem == 1) asm volatile("s_waitcnt vmcnt(3)" ::: "memory");
    else               asm volatile("s_waitcnt vmcnt(0)" ::: "memory");
    __builtin_amdgcn_s_barrier();
    __builtin_amdgcn_sched_barrier(0);
    COMPUTE(slot);
    __builtin_amdgcn_s_barrier();
    if (tt + 3 < nt) STAGE(tt + 3, slot);
    slot = (slot == 2) ? 0 : slot + 1;
  }
  __builtin_amdgcn_sched_barrier(0);

  int rl0 = wr * 64 + ((lane >> 4) << 2);
  int cl0 = wc * 32 + (lane & 15);
  int r0 = blockIdx.x * 128 + rl0;
  int c0 = blockIdx.y * 64 + cl0;

  if constexpr (EP == EP_F32) {
    float* Cb = (float*)Cv + cz * zC;
#pragma unroll
    for (int m = 0; m < 4; ++m)
#pragma unroll
      for (int n = 0; n < 2; ++n)
#pragma unroll
        for (int j = 0; j < 4; ++j)
          Cb[(long long)(r0 + m * 16 + j) * N + c0 + n * 16] = acc[m][n][j];
  } else if constexpr (EP == EP_BF16O) {
    bf16_t* Cb = (bf16_t*)Cv + cz * zC;
#pragma unroll
    for (int m = 0; m < 4; ++m)
#pragma unroll
      for (int n = 0; n < 2; ++n)
#pragma unroll
        for (int j = 0; j < 4; ++j)
          Cb[(long long)(r0 + m * 16 + j) * N + c0 + n * 16] = (bf16_t)acc[m][n][j];
  } else if constexpr (EP == EP_XWT) {
    float* Cb = (float*)Cv;
#pragma unroll
    for (int m = 0; m < 4; ++m)
#pragma unroll
      for (int n = 0; n < 2; ++n)
#pragma unroll
        for (int j = 0; j < 4; ++j) {
          float v = acc[m][n][j];
          Cb[(long long)(r0 + m * 16 + j) * N + c0 + n * 16] = v;
          tile[(rl0 + m * 16 + j) * 65 + cl0 + n * 16] = (bf16_t)v;
        }
    __syncthreads();
    int nl = t >> 5, rl = (t & 31) * 4;
#pragma unroll
    for (int vv = 0; vv < 8; ++vv) {
      int n_l = nl + vv * 8;
      bf16x4 o;
      o[0] = tile[(rl + 0) * 65 + n_l]; o[1] = tile[(rl + 1) * 65 + n_l];
      o[2] = tile[(rl + 2) * 65 + n_l]; o[3] = tile[(rl + 3) * 65 + n_l];
      *(bf16x4*)&aux3[(long long)(blockIdx.y * 64 + n_l) * NN + blockIdx.x * 128 + rl] = o;
    }
  } else if constexpr (EP == EP_BRELU) {
    bf16_t* Cb = (bf16_t*)Cv;
    float bj[2];
#pragma unroll
    for (int n = 0; n < 2; ++n) bj[n] = aux1[c0 + n * 16];
#pragma unroll
    for (int m = 0; m < 4; ++m)
#pragma unroll
      for (int n = 0; n < 2; ++n)
#pragma unroll
        for (int j = 0; j < 4; ++j)
          Cb[(long long)(r0 + m * 16 + j) * N + c0 + n * 16] =
              (bf16_t)fmaxf(acc[m][n][j] + bj[n], 0.f);
  } else { // EP_BF32
    float* Cb = (float*)Cv;
    float bj[2];
#pragma unroll
    for (int n = 0; n < 2; ++n) bj[n] = aux1[c0 + n * 16];
#pragma unroll
    for (int m = 0; m < 4; ++m)
#pragma unroll
      for (int n = 0; n < 2; ++n)
#pragma unroll
        for (int j = 0; j < 4; ++j)
          Cb[(long long)(r0 + m * 16 + j) * N + c0 + n * 16] = acc[m][n][j] + bj[n];
  }
}

// ---------------- GCN epilogue: out = relu(cscal*(Z - Mdiag*dis*XW) + dis^2*XW + b) ----------------

__global__ void k_gcn_epi2(const float* __restrict__ Z, const float* __restrict__ XW,
                           const float* __restrict__ gcn_b, const float* __restrict__ cscal,
                           const float* __restrict__ disv, const float* __restrict__ Mdiag,
                           bf16_t* __restrict__ Xcat) {
  long long idx4 = ((long long)blockIdx.x * 256 + threadIdx.x) * 4;
  int c = (int)(idx4 >> 19);
  int rem = (int)(idx4 & ((1 << 19) - 1));
  int n = rem >> 8, fcol = rem & 255;
  float4 z  = *(const float4*)(Z + (long long)c * NN * WOUT + rem);
  float4 xw = *(const float4*)(XW + rem);
  float4 b  = *(const float4*)(gcn_b + fcol);
  float cs = cscal[c * NN + n], dn = disv[c * NN + n], md = Mdiag[c * NN + n];
  float d2 = dn * dn, mdd = md * dn;
  bf16x4 o;
  o[0] = (bf16_t)fmaxf(cs * (z.x - mdd * xw.x) + d2 * xw.x + b.x, 0.f);
  o[1] = (bf16_t)fmaxf(cs * (z.y - mdd * xw.y) + d2 * xw.y + b.y, 0.f);
  o[2] = (bf16_t)fmaxf(cs * (z.z - mdd * xw.z) + d2 * xw.z + b.z, 0.f);
  o[3] = (bf16_t)fmaxf(cs * (z.w - mdd * xw.w) + d2 * xw.w + b.w, 0.f);
  *(bf16x4*)&Xcat[(long long)n * (CC * WOUT) + c * WOUT + fcol] = o;
}

// ---------------- launch ----------------

extern "C" void kernel_launch(void* const* d_in, const int* in_sizes, int n_in,
                              void* d_out, int out_size, void* d_ws, size_t ws_size,
                              hipStream_t stream) {
  const float* A    = (const float*)d_in[0];
  const float* X    = (const float*)d_in[1];
  const float* w0a  = (const float*)d_in[2];
  const float* w0b  = (const float*)d_in[3];
  const float* w1   = (const float*)d_in[4];
  const float* gcnw = (const float*)d_in[5];
  const float* gcnb = (const float*)d_in[6];
  const float* l1w  = (const float*)d_in[7];
  const float* l1b  = (const float*)d_in[8];
  const float* l2w  = (const float*)d_in[9];
  const float* l2b  = (const float*)d_in[10];
  float* out = (float*)d_out;

  char* p = (char*)d_ws;
  auto carve = [&](size_t bytes) -> char* {
    char* r = p; p += (bytes + 255) & ~(size_t)255; return r;
  };
  float*  svec  = (float*)carve((size_t)CC * NN * 4);
  float*  dinv1 = (float*)carve((size_t)CC * NN * 4);
  float*  m1    = (float*)carve((size_t)CC * NN * 4);
  float*  cscal = (float*)carve((size_t)CC * NN * 4);
  float*  disv  = (float*)carve((size_t)CC * NN * 4);
  float*  Mdiag = (float*)carve((size_t)CC * NN * 4);
  float*  part  = (float*)carve((size_t)CC * 32 * NN * 4);
  bf16_t* S1    = (bf16_t*)carve((size_t)CC * N2 * 2); // Ha -> {XWdT, Yt, Z}
  bf16_t* HbT   = (bf16_t*)carve((size_t)CC * N2 * 2);
  bf16_t* Hb2T  = (bf16_t*)carve((size_t)CC * N2 * 2);
  bf16_t* Hn    = (bf16_t*)carve((size_t)CC * N2 * 2);
  bf16_t* HnT   = (bf16_t*)carve((size_t)CC * N2 * 2);
  bf16_t* Xb    = (bf16_t*)carve((size_t)NN * WIN * 2);
  bf16_t* gwT   = (bf16_t*)carve((size_t)WOUT * WIN * 2);
  bf16_t* l1wb  = (bf16_t*)carve((size_t)WOUT * CC * WOUT * 2);
  bf16_t* l2wb  = (bf16_t*)carve((size_t)WOUT * WOUT * 2);
  float*  XW    = (float*)carve((size_t)NN * WOUT * 4);
  bf16_t* XWT   = (bf16_t*)carve((size_t)WOUT * NN * 2);
  bf16_t* Xcat  = (bf16_t*)carve((size_t)NN * CC * WOUT * 2);
  bf16_t* hb    = (bf16_t*)carve((size_t)NN * WOUT * 2);

  bf16_t* Ha = S1;
  bf16_t* XWdT = (bf16_t*)((char*)S1);
  bf16_t* Yt   = (bf16_t*)((char*)S1 + (2LL << 20));
  float*  Z    = (float*) ((char*)S1 + (6LL << 20));

  // prep
  k_prep<<<640, 256, 0, stream>>>(X, l1w, l2w, gcnw, Xb, l1wb, l2wb, gwT);
  k_combine<<<dim3(32, 32), 256, 0, stream>>>(A, w0a, w0b, w1, Ha, HbT, Hb2T, part);
  k_s_finish<<<16, 256, 0, stream>>>(part, svec);

  // layer 0: analytic degrees; GEMM1 (128^2 tile, BK=64 ring-2) fused normalize -> Hn + HnT
  k_deg<false><<<dim3(512, 2), 256, 0, stream>>>(svec, Ha, HbT, dinv1, m1, nullptr);
  k_gemmL<<<dim3(16, 16, 2), 256, 0, stream>>>(Ha, HbT, Hn, HnT, dinv1);

  // layer 1 scalars: deg2 (-> cscal, disv) and Mdiag from one row-dot pass
  k_deg<true><<<dim3(512, 2), 256, 0, stream>>>(m1, Hn, Hb2T, cscal, disv, Mdiag);

  // GCN via associativity
  k_gemm<EP_XWT><<<dim3(16, 4, 1), 256, 0, stream>>>(
      Xb, gwT, XW, nullptr, nullptr, XWT, WOUT, WIN, WIN, WIN, 0, 0, 0);
  k_scale_xwd<<<512, 256, 0, stream>>>(XWT, disv, XWdT);
  k_gemm<EP_BF16O><<<dim3(2, 32, 2), 256, 0, stream>>>(
      XWdT, HnT, Yt, nullptr, nullptr, nullptr, NN, NN, NN, NN,
      (long long)WOUT * NN, N2, (long long)WOUT * NN);
  k_gemm<EP_F32><<<dim3(16, 4, 2), 256, 0, stream>>>(
      Hb2T, Yt, Z, nullptr, nullptr, nullptr, WOUT, NN, NN, NN,
      N2, (long long)WOUT * NN, (long long)NN * WOUT);
  k_gcn_epi2<<<1024, 256, 0, stream>>>(Z, XW, gcnb, cscal, disv, Mdiag, Xcat);

  // MLP with fused bias(+relu)
  k_gemm<EP_BRELU><<<dim3(16, 4, 1), 256, 0, stream>>>(
      Xcat, l1wb, hb, l1b, nullptr, nullptr, WOUT, CC * WOUT, CC * WOUT, CC * WOUT, 0, 0, 0);
  k_gemm<EP_BF32><<<dim3(16, 4, 1), 256, 0, stream>>>(
      hb, l2wb, out, l2b, nullptr, nullptr, WOUT, WOUT, WOUT, WOUT, 0, 0, 0);
}